// Round 6
// baseline (2224.138 us; speedup 1.0000x reference)
//
#include <hip/hip_runtime.h>
#include <hip/hip_bf16.h>
#include <math.h>

#define NN     8000
#define MPAD   8064    /* NN padded to 128 */
#define BATCH  4
#define SEQ    2000
#define DTR    64
#define NHTR   4
#define DHD    16
#define FFD    2048
#define TOUTD  16
#define HIDD   512
#define NHEADS 6
#define HCD    512
#define GIND   514
#define GOUT   3072
#define NEDGE  32000
#define ELOOP  40000   /* NEDGE + NN */

#define K1     576     /* GIND padded to 64-multiple */
#define K2     1152    /* hi + lo halves */

#define KSPLIT 8
#define KCH    250     /* SEQ / KSPLIT */

#define CDIV(a,b) (((a)+(b)-1)/(b))

using bf16x8 = __attribute__((__ext_vector_type__(8))) __bf16;
using f32x4  = __attribute__((__ext_vector_type__(4))) float;

__device__ __forceinline__ float selu_f(float x){
  const float a = 1.6732632423543772848f;
  const float s = 1.0507009873554805f;
  return x > 0.f ? s * x : s * a * (__expf(x) - 1.f);
}

__device__ __forceinline__ unsigned short f2bf_rn(float x){
  unsigned u = __float_as_uint(x);
  unsigned r = (u + 0x7fffu + ((u >> 16) & 1u)) >> 16;
  return (unsigned short)r;
}
__device__ __forceinline__ float bf2f(unsigned short h){
  return __uint_as_float((unsigned)h << 16);
}

// ---------------------------------------------------------------------------
// Generic C[M,N] = act(A[M,K] @ W[N,K]^T + bias). fp32, 64x64 tile, BK=16.
// ---------------------------------------------------------------------------
template<int ACT>  // 0=none 1=relu 2=selu
__global__ __launch_bounds__(256) void k_gemm(const float* __restrict__ A,
    const float* __restrict__ W, const float* __restrict__ bias,
    float* __restrict__ C, int M, int N, int K)
{
  __shared__ float As[16][68];
  __shared__ float Ws[16][68];
  const int tid = threadIdx.x;
  const int bm = blockIdx.y * 64, bn = blockIdx.x * 64;
  const int tx = tid & 15, ty = tid >> 4;
  float acc[4][4] = {};
  for (int k0 = 0; k0 < K; k0 += 16){
    #pragma unroll
    for (int i = 0; i < 4; ++i){
      int el = tid + (i << 8);
      int kk = el & 15, r = el >> 4;
      int gk = k0 + kk;
      int gm = bm + r;
      As[kk][r] = (gm < M && gk < K) ? A[(size_t)gm * K + gk] : 0.f;
      int gn = bn + r;
      Ws[kk][r] = (gn < N && gk < K) ? W[(size_t)gn * K + gk] : 0.f;
    }
    __syncthreads();
    #pragma unroll
    for (int kk = 0; kk < 16; ++kk){
      float av[4], wv[4];
      #pragma unroll
      for (int i = 0; i < 4; ++i) av[i] = As[kk][ty*4+i];
      #pragma unroll
      for (int j = 0; j < 4; ++j) wv[j] = Ws[kk][tx*4+j];
      #pragma unroll
      for (int i = 0; i < 4; ++i)
        #pragma unroll
        for (int j = 0; j < 4; ++j) acc[i][j] = fmaf(av[i], wv[j], acc[i][j]);
    }
    __syncthreads();
  }
  #pragma unroll
  for (int i = 0; i < 4; ++i){
    int gm = bm + ty*4 + i;
    if (gm >= M) continue;
    #pragma unroll
    for (int j = 0; j < 4; ++j){
      int gn = bn + tx*4 + j;
      if (gn >= N) continue;
      float v = acc[i][j] + bias[gn];
      if (ACT == 1) v = fmaxf(v, 0.f);
      if (ACT == 2) v = selu_f(v);
      C[(size_t)gm * N + gn] = v;
    }
  }
}

// ---------------------------------------------------------------------------
// Split-K GEMM: partial[z][M][N] = A[:, z*kchunk:(z+1)*kchunk] @ W^T slice.
// grid (CDIV(N,64), CDIV(M,64), KS)
// ---------------------------------------------------------------------------
__global__ __launch_bounds__(256) void k_gemm_sk(const float* __restrict__ A,
    const float* __restrict__ W, float* __restrict__ part,
    int M, int N, int K, int kchunk)
{
  __shared__ float As[16][68];
  __shared__ float Ws[16][68];
  const int tid = threadIdx.x;
  const int bm = blockIdx.y * 64, bn = blockIdx.x * 64;
  const int kbeg = blockIdx.z * kchunk;
  const int tx = tid & 15, ty = tid >> 4;
  float acc[4][4] = {};
  for (int k0 = kbeg; k0 < kbeg + kchunk; k0 += 16){
    #pragma unroll
    for (int i = 0; i < 4; ++i){
      int el = tid + (i << 8);
      int kk = el & 15, r = el >> 4;
      int gk = k0 + kk;
      int gm = bm + r;
      As[kk][r] = (gm < M && gk < K) ? A[(size_t)gm * K + gk] : 0.f;
      int gn = bn + r;
      Ws[kk][r] = (gn < N && gk < K) ? W[(size_t)gn * K + gk] : 0.f;
    }
    __syncthreads();
    #pragma unroll
    for (int kk = 0; kk < 16; ++kk){
      float av[4], wv[4];
      #pragma unroll
      for (int i = 0; i < 4; ++i) av[i] = As[kk][ty*4+i];
      #pragma unroll
      for (int j = 0; j < 4; ++j) wv[j] = Ws[kk][tx*4+j];
      #pragma unroll
      for (int i = 0; i < 4; ++i)
        #pragma unroll
        for (int j = 0; j < 4; ++j) acc[i][j] = fmaf(av[i], wv[j], acc[i][j]);
    }
    __syncthreads();
  }
  float* pz = part + (size_t)blockIdx.z * M * N;
  #pragma unroll
  for (int i = 0; i < 4; ++i){
    int gm = bm + ty*4 + i;
    if (gm >= M) continue;
    #pragma unroll
    for (int j = 0; j < 4; ++j){
      int gn = bn + tx*4 + j;
      if (gn >= N) continue;
      pz[(size_t)gm * N + gn] = acc[i][j];
    }
  }
}

// combine KS partials + bias + activation
template<int ACT>
__global__ void k_comb(const float* __restrict__ part, const float* __restrict__ bias,
                       float* __restrict__ C, int M, int N, int KS)
{
  int i = blockIdx.x * blockDim.x + threadIdx.x;
  if (i >= M * N) return;
  int n = i - N * (i / N);
  float v = bias[n];
  for (int z = 0; z < KS; ++z) v += part[(size_t)z * M * N + i];
  if (ACT == 1) v = fmaxf(v, 0.f);
  if (ACT == 2) v = selu_f(v);
  C[i] = v;
}

// ---------------------------------------------------------------------------
// weight fp32 [3072][514] -> bf16 split [3072][K2] = [hi(576) | lo(576)]
// ---------------------------------------------------------------------------
__global__ void k_cvt_w(const float* __restrict__ W, short* __restrict__ Wbf)
{
  int i = blockIdx.x * blockDim.x + threadIdx.x;
  if (i >= GOUT * K1) return;
  int n = i / K1, k = i - K1 * n;
  float v = (k < GIND) ? W[(size_t)n * GIND + k] : 0.f;
  unsigned short h = f2bf_rn(v);
  unsigned short l = f2bf_rn(v - bf2f(h));
  Wbf[(size_t)n * K2 + k]      = (short)h;
  Wbf[(size_t)n * K2 + K1 + k] = (short)l;
}

// A = [coord | hidden] fp32 -> bf16 split [MPAD][K2] = [hi(576) | lo(576)]
__global__ void k_cvt_a(const float* __restrict__ coord,
                        const float* __restrict__ hidden,
                        short* __restrict__ Abf)
{
  int i = blockIdx.x * blockDim.x + threadIdx.x;
  if (i >= MPAD * K1) return;
  int n = i / K1, k = i - K1 * n;
  float v = 0.f;
  if (n < NN && k < GIND)
    v = (k < 2) ? coord[(size_t)n*2 + k] : hidden[(size_t)n*HIDD + k - 2];
  unsigned short h = f2bf_rn(v);
  unsigned short l = f2bf_rn(v - bf2f(h));
  Abf[(size_t)n * K2 + k]      = (short)h;
  Abf[(size_t)n * K2 + K1 + k] = (short)l;
}

// ---------------------------------------------------------------------------
// Fused GAT GEMM pair via MFMA bf16, 3-pass hi/lo split (27 K-tiles of 64):
//  tiles 0-8: a_hi*b_hi ; 9-17: a_lo*b_hi ; 18-26: a_hi*b_lo
// One A-tile staged per K-step serves BOTH Wl and Wr B-tiles (2 C outputs).
// 128x128 tile, 4 waves, global_load_lds(16B), XCD-swizzled block mapping.
// ---------------------------------------------------------------------------
__global__ __launch_bounds__(256) void k_gat2(
    const short* __restrict__ Abf, const short* __restrict__ Wlb,
    const short* __restrict__ Wrb, const float* __restrict__ bl,
    const float* __restrict__ br, float* __restrict__ Cl, float* __restrict__ Cr)
{
  __shared__ short As [128 * 64];
  __shared__ short Bls[128 * 64];
  __shared__ short Brs[128 * 64];
  const int tid  = threadIdx.x;
  // bijective XCD swizzle: nwg = 24*63 = 1512 = 8 * 189
  int lin = blockIdx.y * 24 + blockIdx.x;
  int wg  = (lin & 7) * 189 + (lin >> 3);
  const int bm = (wg / 24) * 128, bn = (wg % 24) * 128;
  const int w    = tid >> 6, lane = tid & 63;
  const int wr   = w >> 1, wc = w & 1;
  const int lrow = lane & 15, lk = (lane >> 4) * 8;

  f32x4 accl[4][4], accr[4][4];
  #pragma unroll
  for (int i = 0; i < 4; ++i)
    #pragma unroll
    for (int j = 0; j < 4; ++j){
      accl[i][j] = (f32x4){0.f, 0.f, 0.f, 0.f};
      accr[i][j] = (f32x4){0.f, 0.f, 0.f, 0.f};
    }

  for (int kt = 0; kt < 27; ++kt){
    int aoff, boff;
    if (kt < 9)       { aoff = kt * 64;             boff = kt * 64; }
    else if (kt < 18) { aoff = K1 + (kt - 9) * 64;  boff = (kt - 9) * 64; }
    else              { aoff = (kt - 18) * 64;      boff = K1 + (kt - 18) * 64; }
    __syncthreads();                 // previous tile fully consumed
    #pragma unroll
    for (int i = 0; i < 4; ++i){
      int l  = i * 256 + tid;        // 16B-chunk index 0..1023
      int r  = l >> 3, c = (l & 7) * 8;
      const short* ga = Abf + (size_t)(bm + r) * K2 + aoff + c;
      const short* gl = Wlb + (size_t)(bn + r) * K2 + boff + c;
      const short* gr = Wrb + (size_t)(bn + r) * K2 + boff + c;
      short* la  = As  + ((i * 256 + w * 64) << 3);   // wave-uniform base
      short* lbl = Bls + ((i * 256 + w * 64) << 3);
      short* lbr = Brs + ((i * 256 + w * 64) << 3);
      __builtin_amdgcn_global_load_lds(
          (const __attribute__((address_space(1))) unsigned*)ga,
          (__attribute__((address_space(3))) unsigned*)la, 16, 0, 0);
      __builtin_amdgcn_global_load_lds(
          (const __attribute__((address_space(1))) unsigned*)gl,
          (__attribute__((address_space(3))) unsigned*)lbl, 16, 0, 0);
      __builtin_amdgcn_global_load_lds(
          (const __attribute__((address_space(1))) unsigned*)gr,
          (__attribute__((address_space(3))) unsigned*)lbr, 16, 0, 0);
    }
    __syncthreads();                 // drains vmcnt, tile ready
    #pragma unroll
    for (int ks = 0; ks < 2; ++ks){
      bf16x8 fa[4], fl[4], fr[4];
      #pragma unroll
      for (int mi = 0; mi < 4; ++mi)
        fa[mi] = *(const bf16x8*)&As[(wr*64 + mi*16 + lrow) * 64 + ks*32 + lk];
      #pragma unroll
      for (int ni = 0; ni < 4; ++ni){
        fl[ni] = *(const bf16x8*)&Bls[(wc*64 + ni*16 + lrow) * 64 + ks*32 + lk];
        fr[ni] = *(const bf16x8*)&Brs[(wc*64 + ni*16 + lrow) * 64 + ks*32 + lk];
      }
      #pragma unroll
      for (int mi = 0; mi < 4; ++mi)
        #pragma unroll
        for (int ni = 0; ni < 4; ++ni){
          accl[mi][ni] = __builtin_amdgcn_mfma_f32_16x16x32_bf16(
              fa[mi], fl[ni], accl[mi][ni], 0, 0, 0);
          accr[mi][ni] = __builtin_amdgcn_mfma_f32_16x16x32_bf16(
              fa[mi], fr[ni], accr[mi][ni], 0, 0, 0);
        }
    }
  }
  // epilogue: col = lane&15 (+n offsets), row = (lane>>4)*4 + j (+m offsets)
  #pragma unroll
  for (int mi = 0; mi < 4; ++mi){
    #pragma unroll
    for (int ni = 0; ni < 4; ++ni){
      int gn = bn + wc*64 + ni*16 + lrow;
      float bvl = bl[gn], bvr = br[gn];
      #pragma unroll
      for (int j = 0; j < 4; ++j){
        int gm = bm + wr*64 + mi*16 + (lane >> 4) * 4 + j;
        if (gm < NN){
          Cl[(size_t)gm * GOUT + gn] = accl[mi][ni][j] + bvl;
          Cr[(size_t)gm * GOUT + gn] = accr[mi][ni][j] + bvr;
        }
      }
    }
  }
}

// ---------------------------------------------------------------------------
// h[n,d] = mesh[n,0:4] . embed_w[d,0:4] + embed_b[d]
// ---------------------------------------------------------------------------
__global__ void k_embed(const float* __restrict__ mesh,
                        const float* __restrict__ w, const float* __restrict__ b,
                        float* __restrict__ h)
{
  int i = blockIdx.x * blockDim.x + threadIdx.x;
  if (i >= NN * DTR) return;
  int n = i >> 6, d = i & 63;
  const float* mr = mesh + n * 4;
  const float* wr = w + d * 4;
  h[i] = fmaf(mr[0], wr[0], fmaf(mr[1], wr[1], fmaf(mr[2], wr[2], mr[3]*wr[3]))) + b[d];
}

// ---------------------------------------------------------------------------
// split-K flash attention, stage 1: partials per (query, ksplit)
// qkv row layout (192 floats): [Q 0..63 | K 64..127 | V 128..191], head h at h*16
// ---------------------------------------------------------------------------
__global__ __launch_bounds__(128) void k_attn_part(const float* __restrict__ qkv,
    float* __restrict__ Pm, float* __restrict__ Pl, float* __restrict__ Pacc)
{
  __shared__ float Ks[128][DHD];
  __shared__ float Vs[128][DHD];
  const int q  = blockIdx.x * 128 + threadIdx.x;
  const int bh = blockIdx.y;
  const int b  = bh >> 2, h = bh & 3;
  const int ks = blockIdx.z;
  const bool valid = q < SEQ;
  float qv[DHD];
  if (valid){
    const float4* qr = (const float4*)(qkv + ((size_t)(b*SEQ + q))*192 + h*DHD);
    #pragma unroll
    for (int j = 0; j < 4; ++j){
      float4 t = qr[j];
      qv[j*4+0] = t.x; qv[j*4+1] = t.y; qv[j*4+2] = t.z; qv[j*4+3] = t.w;
    }
  }
  float m = -1e30f, l = 0.f, acc[DHD] = {};
  const int kbeg = ks * KCH, kend = kbeg + KCH;
  for (int kt = kbeg; kt < kend; kt += 128){
    int cnt = min(128, kend - kt);
    __syncthreads();
    for (int el = threadIdx.x; el < cnt * 4; el += 128){
      int r = el >> 2, d4 = el & 3;
      const float4* base = (const float4*)(qkv + ((size_t)(b*SEQ + kt + r))*192 + h*DHD);
      ((float4*)Ks[r])[d4] = base[16 + d4];      // +64 floats  = K block
      ((float4*)Vs[r])[d4] = base[32 + d4];      // +128 floats = V block
    }
    __syncthreads();
    if (valid){
      for (int r = 0; r < cnt; ++r){
        float s = 0.f;
        #pragma unroll
        for (int d = 0; d < DHD; ++d) s = fmaf(qv[d], Ks[r][d], s);
        s *= 0.25f;
        float mn = fmaxf(m, s);
        float cc = __expf(m - mn), p = __expf(s - mn);
        l = l * cc + p;
        #pragma unroll
        for (int d = 0; d < DHD; ++d) acc[d] = fmaf(acc[d], cc, p * Vs[r][d]);
        m = mn;
      }
    }
  }
  if (valid){
    size_t qi = ((size_t)bh * SEQ + q) * KSPLIT + ks;
    Pm[qi] = m; Pl[qi] = l;
    #pragma unroll
    for (int d = 0; d < DHD; ++d) Pacc[qi*DHD + d] = acc[d];
  }
}

// stage 2: merge KSPLIT partials per query -> o[N][64]
__global__ void k_attn_comb(const float* __restrict__ Pm, const float* __restrict__ Pl,
                            const float* __restrict__ Pacc, float* __restrict__ o)
{
  int qi = blockIdx.x * blockDim.x + threadIdx.x;
  if (qi >= BATCH * NHTR * SEQ) return;
  float m = -1e30f;
  #pragma unroll
  for (int ks = 0; ks < KSPLIT; ++ks) m = fmaxf(m, Pm[(size_t)qi*KSPLIT + ks]);
  float l = 0.f, acc[DHD] = {};
  #pragma unroll
  for (int ks = 0; ks < KSPLIT; ++ks){
    size_t p = (size_t)qi*KSPLIT + ks;
    float sc = __expf(Pm[p] - m);
    l += Pl[p] * sc;
    #pragma unroll
    for (int d = 0; d < DHD; ++d) acc[d] = fmaf(Pacc[p*DHD + d], sc, acc[d]);
  }
  int bh = qi / SEQ, q = qi - bh * SEQ;
  int b = bh >> 2, h = bh & 3;
  float inv = 1.f / l;
  #pragma unroll
  for (int d = 0; d < DHD; ++d)
    o[((size_t)(b*SEQ + q))*64 + h*DHD + d] = acc[d] * inv;
}

// ---------------------------------------------------------------------------
__global__ __launch_bounds__(256) void k_addln(const float* __restrict__ x,
    const float* __restrict__ y, const float* __restrict__ g,
    const float* __restrict__ b, float* __restrict__ out)
{
  int row = blockIdx.x * 4 + (threadIdx.x >> 6);
  int lane = threadIdx.x & 63;
  if (row >= NN) return;
  float v = x[(size_t)row*64 + lane] + y[(size_t)row*64 + lane];
  float s1 = v, s2 = v * v;
  #pragma unroll
  for (int o = 32; o; o >>= 1){ s1 += __shfl_xor(s1, o); s2 += __shfl_xor(s2, o); }
  float mean = s1 * (1.f/64.f);
  float var  = s2 * (1.f/64.f) - mean * mean;
  float r = rsqrtf(var + 1e-5f);
  out[(size_t)row*64 + lane] = (v - mean) * r * g[lane] + b[lane];
}

__global__ void k_concat_feats(const float* __restrict__ x,
                               const float* __restrict__ tout,
                               float* __restrict__ feats)
{
  int i = blockIdx.x * blockDim.x + threadIdx.x;
  if (i >= NN * 21) return;
  int n = i / 21, c = i - 21*n;
  feats[i] = (c < 5) ? x[(size_t)n*7 + 2 + c] : tout[(size_t)n*16 + c - 5];
}

__global__ void k_initcoord(const float* __restrict__ x, float* __restrict__ coord)
{
  int i = blockIdx.x * blockDim.x + threadIdx.x;
  if (i >= NN * 2) return;
  coord[i] = x[(size_t)(i >> 1)*7 + (i & 1)];
}

// ---------------------------------------------------------------------------
// CSR build (by dst). dst for e>=NEDGE is the self-loop e-NEDGE.
// ---------------------------------------------------------------------------
__global__ void k_count(const int* __restrict__ dst, int* __restrict__ cnt)
{
  int e = blockIdx.x * blockDim.x + threadIdx.x;
  if (e >= ELOOP) return;
  int d = (e < NEDGE) ? dst[e] : e - NEDGE;
  atomicAdd(&cnt[d], 1);
}

__global__ __launch_bounds__(1024) void k_scan(const int* __restrict__ cnt,
                                               int* __restrict__ ptr)
{
  __shared__ int part[1024];
  int tid = threadIdx.x;
  const int per = 8;
  int loc[per]; int s = 0;
  int base = tid * per;
  #pragma unroll
  for (int i = 0; i < per; ++i){
    int v = (base + i < NN) ? cnt[base + i] : 0;
    loc[i] = s; s += v;
  }
  part[tid] = s;
  __syncthreads();
  for (int off = 1; off < 1024; off <<= 1){
    int v = 0;
    if (tid >= off) v = part[tid - off];
    __syncthreads();
    if (tid >= off) part[tid] += v;
    __syncthreads();
  }
  int pre = tid ? part[tid - 1] : 0;
  #pragma unroll
  for (int i = 0; i < per; ++i)
    if (base + i < NN) ptr[base + i] = pre + loc[i];
  if (tid == 1023) ptr[NN] = part[1023];
}

__global__ void k_fill(const int* __restrict__ dst, const int* __restrict__ ptr,
                       int* __restrict__ fil, int* __restrict__ eid)
{
  int e = blockIdx.x * blockDim.x + threadIdx.x;
  if (e >= ELOOP) return;
  int d = (e < NEDGE) ? dst[e] : e - NEDGE;
  int pos = ptr[d] + atomicAdd(&fil[d], 1);
  eid[pos] = e;
}

// ---------------------------------------------------------------------------
// logits[e,h] = sum_c lrelu(xl[src,h,c]+xr[dst,h,c]) * att[h,c]; wave/(e,h)
// ---------------------------------------------------------------------------
__global__ __launch_bounds__(256) void k_logits(const float* __restrict__ xl,
    const float* __restrict__ xr, const int* __restrict__ src_a,
    const int* __restrict__ dst_a, const float* __restrict__ att,
    float* __restrict__ logits)
{
  int wid = blockIdx.x * 4 + (threadIdx.x >> 6);
  if (wid >= ELOOP * NHEADS) return;
  int e = wid / NHEADS, h = wid - NHEADS * e;
  int lane = threadIdx.x & 63;
  int s = (e < NEDGE) ? src_a[e] : e - NEDGE;
  int d = (e < NEDGE) ? dst_a[e] : e - NEDGE;
  const float4* pl = (const float4*)(xl + (size_t)s * GOUT + h * HCD);
  const float4* pr = (const float4*)(xr + (size_t)d * GOUT + h * HCD);
  const float4* pa = (const float4*)(att + h * HCD);
  float acc = 0.f;
  #pragma unroll
  for (int j = 0; j < 2; ++j){
    int c = j * 64 + lane;
    float4 a = pl[c], r = pr[c], w = pa[c];
    float v;
    v = a.x + r.x; v = v > 0.f ? v : 0.2f * v; acc = fmaf(v, w.x, acc);
    v = a.y + r.y; v = v > 0.f ? v : 0.2f * v; acc = fmaf(v, w.y, acc);
    v = a.z + r.z; v = v > 0.f ? v : 0.2f * v; acc = fmaf(v, w.z, acc);
    v = a.w + r.w; v = v > 0.f ? v : 0.2f * v; acc = fmaf(v, w.w, acc);
  }
  #pragma unroll
  for (int o = 32; o; o >>= 1) acc += __shfl_xor(acc, o);
  if (lane == 0) logits[wid] = acc;
}

__global__ void k_stats(const float* __restrict__ logits, const int* __restrict__ ptr,
                        const int* __restrict__ eid, float* __restrict__ mx,
                        float* __restrict__ inv)
{
  int i = blockIdx.x * blockDim.x + threadIdx.x;
  if (i >= NN * NHEADS) return;
  int n = i / NHEADS, h = i - NHEADS * n;
  int s0 = ptr[n], s1 = ptr[n + 1];
  float m = -1e30f;
  for (int t = s0; t < s1; ++t) m = fmaxf(m, logits[eid[t]*NHEADS + h]);
  float s = 0.f;
  for (int t = s0; t < s1; ++t) s += __expf(logits[eid[t]*NHEADS + h] - m);
  mx[i] = m; inv[i] = 1.f / s;
}

// ---------------------------------------------------------------------------
// hidden[n,c] = selu(mean_h sum_{e in(n)} a[e,h]*xl[src,h,c] + gbias[c])
// ---------------------------------------------------------------------------
__global__ __launch_bounds__(256) void k_agg(const float* __restrict__ xl,
    const float* __restrict__ logits, const float* __restrict__ mx,
    const float* __restrict__ inv, const int* __restrict__ ptr,
    const int* __restrict__ eid, const int* __restrict__ src_a,
    const float* __restrict__ gbias, float* __restrict__ hidden)
{
  const int n = blockIdx.x;
  const int tid = threadIdx.x;
  __shared__ float a_sh[64 * NHEADS];
  __shared__ int src_sh[64];
  const int s0 = ptr[n];
  const int deg = ptr[n + 1] - s0;
  float acc[12] = {};
  for (int base = 0; base < deg; base += 64){
    int cnt = min(64, deg - base);
    __syncthreads();
    for (int t = tid; t < cnt * NHEADS; t += 256){
      int ei = t / NHEADS, h = t - NHEADS * ei;
      int e = eid[s0 + base + ei];
      a_sh[t] = __expf(logits[e*NHEADS + h] - mx[n*NHEADS + h]) * inv[n*NHEADS + h];
      if (h == 0) src_sh[ei] = (e < NEDGE) ? src_a[e] : e - NEDGE;
    }
    __syncthreads();
    for (int i2 = 0; i2 < cnt; ++i2){
      const float* row = xl + (size_t)src_sh[i2] * GOUT;
      #pragma unroll
      for (int k = 0; k < 12; ++k){
        int slot = tid + (k << 8);
        acc[k] = fmaf(row[slot], a_sh[i2*NHEADS + (slot >> 9)], acc[k]);
      }
    }
  }
  float m1 = (acc[0]+acc[2]+acc[4]+acc[6]+acc[8]+acc[10]) * (1.f/6.f);
  float m2 = (acc[1]+acc[3]+acc[5]+acc[7]+acc[9]+acc[11]) * (1.f/6.f);
  hidden[(size_t)n*HIDD + tid]       = selu_f(m1 + gbias[tid]);
  hidden[(size_t)n*HIDD + 256 + tid] = selu_f(m2 + gbias[256 + tid]);
}

// ---------------------------------------------------------------------------
extern "C" void kernel_launch(void* const* d_in, const int* in_sizes, int n_in,
                              void* d_out, int out_size, void* d_ws, size_t ws_size,
                              hipStream_t stream)
{
  const float* mesh     = (const float*)d_in[1];
  const float* xin      = (const float*)d_in[2];
  const int*   ei       = (const int*)d_in[3];
  const float* embed_w  = (const float*)d_in[4];
  const float* embed_b  = (const float*)d_in[5];
  const float* in_proj_w= (const float*)d_in[6];
  const float* in_proj_b= (const float*)d_in[7];
  const float* out_proj_w=(const float*)d_in[8];
  const float* out_proj_b=(const float*)d_in[9];
  const float* ln1_g    = (const float*)d_in[10];
  const float* ln1_b    = (const float*)d_in[11];
  const float* ln2_g    = (const float*)d_in[12];
  const float* ln2_b    = (const float*)d_in[13];
  const float* ff1_w    = (const float*)d_in[14];
  const float* ff1_b    = (const float*)d_in[15];
  const float* ff2_w    = (const float*)d_in[16];
  const float* ff2_b    = (const float*)d_in[17];
  const float* tout_w   = (const float*)d_in[18];
  const float* tout_b   = (const float*)d_in[19];
  const float* lin_w    = (const float*)d_in[20];
  const float* lin_b    = (const float*)d_in[21];
  const float* gat_wl   = (const float*)d_in[22];
  const float* gat_bl   = (const float*)d_in[23];
  const float* gat_wr   = (const float*)d_in[24];
  const float* gat_br   = (const float*)d_in[25];
  const float* gat_att  = (const float*)d_in[26];
  const float* gat_bias = (const float*)d_in[27];
  const float* coord1_w = (const float*)d_in[28];
  const float* coord1_b = (const float*)d_in[29];
  const float* coord2_w = (const float*)d_in[30];
  const float* coord2_b = (const float*)d_in[31];

  const int* esrc = ei;
  const int* edst = ei + NEDGE;

  char* ws = (char*)d_ws;
  size_t off = 0;
  auto alloc = [&](size_t nbytes){
    size_t o = off; off += (nbytes + 255) & ~(size_t)255; return o;
  };
  float* hidden = (float*)(ws + alloc((size_t)NN * HIDD * 4));
  float* coord  = (float*)(ws + alloc((size_t)NN * 2 * 4));
  float* xl     = (float*)(ws + alloc((size_t)NN * GOUT * 4));
  float* xr     = (float*)(ws + alloc((size_t)NN * GOUT * 4));
  float* logits = (float*)(ws + alloc((size_t)ELOOP * NHEADS * 4));
  float* mxb    = (float*)(ws + alloc((size_t)NN * NHEADS * 4));
  float* invb   = (float*)(ws + alloc((size_t)NN * NHEADS * 4));
  float* c1     = (float*)(ws + alloc((size_t)NN * 256 * 4));
  int*   ptr    = (int*)(ws + alloc((size_t)(NN + 1) * 4));
  int*   eid    = (int*)(ws + alloc((size_t)ELOOP * 4));
  int*   cnt    = (int*)(ws + alloc((size_t)NN * 4));
  int*   fil    = (int*)(ws + alloc((size_t)NN * 4));
  short* abf    = (short*)(ws + alloc((size_t)MPAD * K2 * 2));
  short* wlbf   = (short*)(ws + alloc((size_t)GOUT * K2 * 2));
  short* wrbf   = (short*)(ws + alloc((size_t)GOUT * K2 * 2));

  // phase-A temporaries aliased inside xl / xr (free before GAT loop)
  float* h     = (float*)((char*)xl + 0);
  float* qkv   = (float*)((char*)xl + (4u << 20));
  float* o     = (float*)((char*)xl + (12u << 20));
  float* tmp   = (float*)((char*)xl + (16u << 20));
  float* feats = (float*)((char*)xl + (20u << 20));
  float* toutb = (float*)((char*)xl + (24u << 20));
  float* part  = (float*)((char*)xl + (28u << 20));  // split-K partials (<=32MB, xl is 98MB)
  float* ffmid = xr;
  float* Pm    = (float*)((char*)xr + (70u << 20));
  float* Pl    = (float*)((char*)xr + (72u << 20));
  float* Pacc  = (float*)((char*)xr + (74u << 20));

  // ---- transformer ----
  k_embed<<<CDIV(NN*DTR, 256), 256, 0, stream>>>(mesh, embed_w, embed_b, h);
  k_gemm<0><<<dim3(CDIV(192,64), CDIV(NN,64)), 256, 0, stream>>>(h, in_proj_w, in_proj_b, qkv, NN, 192, DTR);
  k_attn_part<<<dim3(CDIV(SEQ,128), BATCH*NHTR, KSPLIT), 128, 0, stream>>>(qkv, Pm, Pl, Pacc);
  k_attn_comb<<<CDIV(BATCH*NHTR*SEQ, 256), 256, 0, stream>>>(Pm, Pl, Pacc, o);
  k_gemm<0><<<dim3(1, CDIV(NN,64)), 256, 0, stream>>>(o, out_proj_w, out_proj_b, tmp, NN, DTR, DTR);
  k_addln<<<CDIV(NN,4), 256, 0, stream>>>(h, tmp, ln1_g, ln1_b, h);
  k_gemm<1><<<dim3(CDIV(FFD,64), CDIV(NN,64)), 256, 0, stream>>>(h, ff1_w, ff1_b, ffmid, NN, FFD, DTR);
  // ff2 via split-K (K=2048 -> 8 x 256)
  k_gemm_sk<<<dim3(1, CDIV(NN,64), 8), 256, 0, stream>>>(ffmid, ff2_w, part, NN, DTR, FFD, 256);
  k_comb<0><<<CDIV(NN*DTR, 256), 256, 0, stream>>>(part, ff2_b, tmp, NN, DTR, 8);
  k_addln<<<CDIV(NN,4), 256, 0, stream>>>(h, tmp, ln2_g, ln2_b, h);
  k_gemm<0><<<dim3(1, CDIV(NN,64)), 256, 0, stream>>>(h, tout_w, tout_b, toutb, NN, TOUTD, DTR);
  k_concat_feats<<<CDIV(NN*21, 256), 256, 0, stream>>>(xin, toutb, feats);
  k_gemm<2><<<dim3(CDIV(HIDD,64), CDIV(NN,64)), 256, 0, stream>>>(feats, lin_w, lin_b, hidden, NN, HIDD, 21);
  k_initcoord<<<CDIV(NN*2, 256), 256, 0, stream>>>(xin, coord);

  // ---- CSR by dst + weight conversion (once) ----
  hipMemsetAsync(cnt, 0, (size_t)NN * 4, stream);
  hipMemsetAsync(fil, 0, (size_t)NN * 4, stream);
  k_count<<<CDIV(ELOOP, 256), 256, 0, stream>>>(edst, cnt);
  k_scan<<<1, 1024, 0, stream>>>(cnt, ptr);
  k_fill<<<CDIV(ELOOP, 256), 256, 0, stream>>>(edst, ptr, fil, eid);
  k_cvt_w<<<CDIV(GOUT*K1, 256), 256, 0, stream>>>(gat_wl, wlbf);
  k_cvt_w<<<CDIV(GOUT*K1, 256), 256, 0, stream>>>(gat_wr, wrbf);

  // ---- GAT loops ----
  for (int it = 0; it < 3; ++it){
    k_cvt_a<<<CDIV(MPAD*K1, 256), 256, 0, stream>>>(coord, hidden, abf);
    k_gat2<<<dim3(GOUT/128, MPAD/128), 256, 0, stream>>>(abf, wlbf, wrbf, gat_bl, gat_br, xl, xr);
    k_logits<<<CDIV(ELOOP*NHEADS, 4), 256, 0, stream>>>(xl, xr, esrc, edst, gat_att, logits);
    k_stats<<<CDIV(NN*NHEADS, 256), 256, 0, stream>>>(logits, ptr, eid, mxb, invb);
    k_agg<<<NN, 256, 0, stream>>>(xl, logits, mxb, invb, ptr, eid, esrc, gat_bias, hidden);
    // coord1 via split-K (K=512 -> 4 x 128), selu in combine
    k_gemm_sk<<<dim3(CDIV(256,64), CDIV(NN,64), 4), 256, 0, stream>>>(hidden, coord1_w, part, NN, 256, HIDD, 128);
    k_comb<2><<<CDIV(NN*256, 256), 256, 0, stream>>>(part, coord1_b, c1, NN, 256, 4);
    float* cdst = (it == 2) ? (float*)d_out : coord;
    k_gemm<0><<<dim3(1, CDIV(NN,64)), 256, 0, stream>>>(c1, coord2_w, coord2_b, cdst, NN, 2, 256);
  }
}

// Round 7
// 1818.774 us; speedup vs baseline: 1.2229x; 1.2229x over previous
//
#include <hip/hip_runtime.h>
#include <hip/hip_bf16.h>
#include <math.h>

#define NN     8000
#define MPAD   8064    /* NN padded to 128 */
#define BATCH  4
#define SEQ    2000
#define DTR    64
#define NHTR   4
#define DHD    16
#define FFD    2048
#define TOUTD  16
#define HIDD   512
#define NHEADS 6
#define HCD    512
#define GIND   514
#define GOUT   3072
#define NEDGE  32000
#define ELOOP  40000   /* NEDGE + NN */

#define K1     576     /* GIND padded to 64-multiple */
#define K2     1152    /* hi + lo halves */

#define KSPLIT 8
#define KCH    250     /* SEQ / KSPLIT */

#define CDIV(a,b) (((a)+(b)-1)/(b))

using bf16x8 = __attribute__((__ext_vector_type__(8))) __bf16;
using f32x4  = __attribute__((__ext_vector_type__(4))) float;

__device__ __forceinline__ float selu_f(float x){
  const float a = 1.6732632423543772848f;
  const float s = 1.0507009873554805f;
  return x > 0.f ? s * x : s * a * (__expf(x) - 1.f);
}

__device__ __forceinline__ unsigned short f2bf_rn(float x){
  unsigned u = __float_as_uint(x);
  unsigned r = (u + 0x7fffu + ((u >> 16) & 1u)) >> 16;
  return (unsigned short)r;
}
__device__ __forceinline__ float bf2f(unsigned short h){
  return __uint_as_float((unsigned)h << 16);
}

// ---------------------------------------------------------------------------
// Generic C[M,N] = act(A[M,K] @ W[N,K]^T + bias). fp32, 64x64 tile, BK=16.
// ---------------------------------------------------------------------------
template<int ACT>  // 0=none 1=relu 2=selu
__global__ __launch_bounds__(256) void k_gemm(const float* __restrict__ A,
    const float* __restrict__ W, const float* __restrict__ bias,
    float* __restrict__ C, int M, int N, int K)
{
  __shared__ float As[16][68];
  __shared__ float Ws[16][68];
  const int tid = threadIdx.x;
  const int bm = blockIdx.y * 64, bn = blockIdx.x * 64;
  const int tx = tid & 15, ty = tid >> 4;
  float acc[4][4] = {};
  for (int k0 = 0; k0 < K; k0 += 16){
    #pragma unroll
    for (int i = 0; i < 4; ++i){
      int el = tid + (i << 8);
      int kk = el & 15, r = el >> 4;
      int gk = k0 + kk;
      int gm = bm + r;
      As[kk][r] = (gm < M && gk < K) ? A[(size_t)gm * K + gk] : 0.f;
      int gn = bn + r;
      Ws[kk][r] = (gn < N && gk < K) ? W[(size_t)gn * K + gk] : 0.f;
    }
    __syncthreads();
    #pragma unroll
    for (int kk = 0; kk < 16; ++kk){
      float av[4], wv[4];
      #pragma unroll
      for (int i = 0; i < 4; ++i) av[i] = As[kk][ty*4+i];
      #pragma unroll
      for (int j = 0; j < 4; ++j) wv[j] = Ws[kk][tx*4+j];
      #pragma unroll
      for (int i = 0; i < 4; ++i)
        #pragma unroll
        for (int j = 0; j < 4; ++j) acc[i][j] = fmaf(av[i], wv[j], acc[i][j]);
    }
    __syncthreads();
  }
  #pragma unroll
  for (int i = 0; i < 4; ++i){
    int gm = bm + ty*4 + i;
    if (gm >= M) continue;
    #pragma unroll
    for (int j = 0; j < 4; ++j){
      int gn = bn + tx*4 + j;
      if (gn >= N) continue;
      float v = acc[i][j] + bias[gn];
      if (ACT == 1) v = fmaxf(v, 0.f);
      if (ACT == 2) v = selu_f(v);
      C[(size_t)gm * N + gn] = v;
    }
  }
}

// ---------------------------------------------------------------------------
// Split-K GEMM: partial[z][M][N] = A[:, z*kchunk:(z+1)*kchunk] @ W^T slice.
// ---------------------------------------------------------------------------
__global__ __launch_bounds__(256) void k_gemm_sk(const float* __restrict__ A,
    const float* __restrict__ W, float* __restrict__ part,
    int M, int N, int K, int kchunk)
{
  __shared__ float As[16][68];
  __shared__ float Ws[16][68];
  const int tid = threadIdx.x;
  const int bm = blockIdx.y * 64, bn = blockIdx.x * 64;
  const int kbeg = blockIdx.z * kchunk;
  const int tx = tid & 15, ty = tid >> 4;
  float acc[4][4] = {};
  for (int k0 = kbeg; k0 < kbeg + kchunk; k0 += 16){
    #pragma unroll
    for (int i = 0; i < 4; ++i){
      int el = tid + (i << 8);
      int kk = el & 15, r = el >> 4;
      int gk = k0 + kk;
      int gm = bm + r;
      As[kk][r] = (gm < M && gk < K) ? A[(size_t)gm * K + gk] : 0.f;
      int gn = bn + r;
      Ws[kk][r] = (gn < N && gk < K) ? W[(size_t)gn * K + gk] : 0.f;
    }
    __syncthreads();
    #pragma unroll
    for (int kk = 0; kk < 16; ++kk){
      float av[4], wv[4];
      #pragma unroll
      for (int i = 0; i < 4; ++i) av[i] = As[kk][ty*4+i];
      #pragma unroll
      for (int j = 0; j < 4; ++j) wv[j] = Ws[kk][tx*4+j];
      #pragma unroll
      for (int i = 0; i < 4; ++i)
        #pragma unroll
        for (int j = 0; j < 4; ++j) acc[i][j] = fmaf(av[i], wv[j], acc[i][j]);
    }
    __syncthreads();
  }
  float* pz = part + (size_t)blockIdx.z * M * N;
  #pragma unroll
  for (int i = 0; i < 4; ++i){
    int gm = bm + ty*4 + i;
    if (gm >= M) continue;
    #pragma unroll
    for (int j = 0; j < 4; ++j){
      int gn = bn + tx*4 + j;
      if (gn >= N) continue;
      pz[(size_t)gm * N + gn] = acc[i][j];
    }
  }
}

// combine KS partials + bias + activation
template<int ACT>
__global__ void k_comb(const float* __restrict__ part, const float* __restrict__ bias,
                       float* __restrict__ C, int M, int N, int KS)
{
  int i = blockIdx.x * blockDim.x + threadIdx.x;
  if (i >= M * N) return;
  int n = i - N * (i / N);
  float v = bias[n];
  for (int z = 0; z < KS; ++z) v += part[(size_t)z * M * N + i];
  if (ACT == 1) v = fmaxf(v, 0.f);
  if (ACT == 2) v = selu_f(v);
  C[i] = v;
}

// ---------------------------------------------------------------------------
// weight fp32 [3072][514] -> bf16 split [3072][K2] = [hi(576) | lo(576)]
// ---------------------------------------------------------------------------
__global__ void k_cvt_w(const float* __restrict__ W, short* __restrict__ Wbf)
{
  int i = blockIdx.x * blockDim.x + threadIdx.x;
  if (i >= GOUT * K1) return;
  int n = i / K1, k = i - K1 * n;
  float v = (k < GIND) ? W[(size_t)n * GIND + k] : 0.f;
  unsigned short h = f2bf_rn(v);
  unsigned short l = f2bf_rn(v - bf2f(h));
  Wbf[(size_t)n * K2 + k]      = (short)h;
  Wbf[(size_t)n * K2 + K1 + k] = (short)l;
}

// A = [coord | hidden] fp32 -> bf16 split [MPAD][K2] = [hi(576) | lo(576)]
__global__ void k_cvt_a(const float* __restrict__ coord,
                        const float* __restrict__ hidden,
                        short* __restrict__ Abf)
{
  int i = blockIdx.x * blockDim.x + threadIdx.x;
  if (i >= MPAD * K1) return;
  int n = i / K1, k = i - K1 * n;
  float v = 0.f;
  if (n < NN && k < GIND)
    v = (k < 2) ? coord[(size_t)n*2 + k] : hidden[(size_t)n*HIDD + k - 2];
  unsigned short h = f2bf_rn(v);
  unsigned short l = f2bf_rn(v - bf2f(h));
  Abf[(size_t)n * K2 + k]      = (short)h;
  Abf[(size_t)n * K2 + K1 + k] = (short)l;
}

// ---------------------------------------------------------------------------
// GAT GEMM via MFMA bf16, 3-pass hi/lo split (27 K-tiles of 64):
//  tiles 0-8: a_hi*b_hi ; 9-17: a_lo*b_hi ; 18-26: a_hi*b_lo
// 128x128 tile, 4 waves, global_load_lds(16B), 2-barrier loop.
// LDS bank-conflict fix: 16B-chunk XOR swizzle (j ^= r&7) applied on the
// GLOBAL source address (gload_lds writes linearly) and on the ds_read addr.
// XCD-aware bijective block swizzle (1512 = 8 * 189).
// ---------------------------------------------------------------------------
__global__ __launch_bounds__(256) void k_gat_mfma(
    const short* __restrict__ Abf, const short* __restrict__ Wbf,
    const float* __restrict__ bias, float* __restrict__ C)
{
  __shared__ short As[128 * 64];
  __shared__ short Bs[128 * 64];
  const int tid  = threadIdx.x;
  int lin = blockIdx.y * 24 + blockIdx.x;          // 24*63 = 1512 = 8*189
  int wg  = (lin & 7) * 189 + (lin >> 3);          // bijective XCD chunking
  const int bm = (wg / 24) * 128, bn = (wg % 24) * 128;
  const int w    = tid >> 6, lane = tid & 63;
  const int wr   = w >> 1, wc = w & 1;
  const int lrow = lane & 15;

  f32x4 acc[4][4];
  #pragma unroll
  for (int i = 0; i < 4; ++i)
    #pragma unroll
    for (int j = 0; j < 4; ++j) acc[i][j] = (f32x4){0.f, 0.f, 0.f, 0.f};

  for (int kt = 0; kt < 27; ++kt){
    int aoff, boff;
    if (kt < 9)       { aoff = kt * 64;             boff = kt * 64; }
    else if (kt < 18) { aoff = K1 + (kt - 9) * 64;  boff = (kt - 9) * 64; }
    else              { aoff = (kt - 18) * 64;      boff = K1 + (kt - 18) * 64; }
    __syncthreads();                 // previous tile fully consumed
    #pragma unroll
    for (int i = 0; i < 4; ++i){
      int l  = i * 256 + tid;        // 16B-chunk index 0..1023
      int r  = l >> 3, j = l & 7;
      int js = j ^ (r & 7);          // source pre-swizzle (write side)
      const short* ga = Abf + (size_t)(bm + r) * K2 + aoff + js * 8;
      const short* gb = Wbf + (size_t)(bn + r) * K2 + boff + js * 8;
      short* la = As + ((i * 256 + w * 64) << 3);   // wave-uniform base
      short* lb = Bs + ((i * 256 + w * 64) << 3);
      __builtin_amdgcn_global_load_lds(
          (const __attribute__((address_space(1))) unsigned*)ga,
          (__attribute__((address_space(3))) unsigned*)la, 16, 0, 0);
      __builtin_amdgcn_global_load_lds(
          (const __attribute__((address_space(1))) unsigned*)gb,
          (__attribute__((address_space(3))) unsigned*)lb, 16, 0, 0);
    }
    __syncthreads();                 // drains vmcnt, tile ready
    #pragma unroll
    for (int ks = 0; ks < 2; ++ks){
      // read-side swizzle: chunk c = ks*4 + (lane>>4), row&7 == lrow&7
      const int co = ((ks * 4 + (lane >> 4)) ^ (lrow & 7)) * 8;
      bf16x8 fa[4], fb[4];
      #pragma unroll
      for (int mi = 0; mi < 4; ++mi)
        fa[mi] = *(const bf16x8*)&As[(wr*64 + mi*16 + lrow) * 64 + co];
      #pragma unroll
      for (int ni = 0; ni < 4; ++ni)
        fb[ni] = *(const bf16x8*)&Bs[(wc*64 + ni*16 + lrow) * 64 + co];
      #pragma unroll
      for (int mi = 0; mi < 4; ++mi)
        #pragma unroll
        for (int ni = 0; ni < 4; ++ni)
          acc[mi][ni] = __builtin_amdgcn_mfma_f32_16x16x32_bf16(
              fa[mi], fb[ni], acc[mi][ni], 0, 0, 0);
    }
  }
  // epilogue: col = lane&15 (+n offsets), row = (lane>>4)*4 + j (+m offsets)
  #pragma unroll
  for (int mi = 0; mi < 4; ++mi){
    #pragma unroll
    for (int ni = 0; ni < 4; ++ni){
      int gn = bn + wc*64 + ni*16 + lrow;
      float bv = bias[gn];
      #pragma unroll
      for (int j = 0; j < 4; ++j){
        int gm = bm + wr*64 + mi*16 + (lane >> 4) * 4 + j;
        if (gm < NN)
          C[(size_t)gm * GOUT + gn] = acc[mi][ni][j] + bv;
      }
    }
  }
}

// ---------------------------------------------------------------------------
// h[n,d] = mesh[n,0:4] . embed_w[d,0:4] + embed_b[d]
// ---------------------------------------------------------------------------
__global__ void k_embed(const float* __restrict__ mesh,
                        const float* __restrict__ w, const float* __restrict__ b,
                        float* __restrict__ h)
{
  int i = blockIdx.x * blockDim.x + threadIdx.x;
  if (i >= NN * DTR) return;
  int n = i >> 6, d = i & 63;
  const float* mr = mesh + n * 4;
  const float* wr = w + d * 4;
  h[i] = fmaf(mr[0], wr[0], fmaf(mr[1], wr[1], fmaf(mr[2], wr[2], mr[3]*wr[3]))) + b[d];
}

// ---------------------------------------------------------------------------
// split-K flash attention, stage 1: partials per (query, ksplit)
// qkv row layout (192 floats): [Q 0..63 | K 64..127 | V 128..191], head h at h*16
// ---------------------------------------------------------------------------
__global__ __launch_bounds__(128) void k_attn_part(const float* __restrict__ qkv,
    float* __restrict__ Pm, float* __restrict__ Pl, float* __restrict__ Pacc)
{
  __shared__ float Ks[128][DHD];
  __shared__ float Vs[128][DHD];
  const int q  = blockIdx.x * 128 + threadIdx.x;
  const int bh = blockIdx.y;
  const int b  = bh >> 2, h = bh & 3;
  const int ks = blockIdx.z;
  const bool valid = q < SEQ;
  float qv[DHD];
  if (valid){
    const float4* qr = (const float4*)(qkv + ((size_t)(b*SEQ + q))*192 + h*DHD);
    #pragma unroll
    for (int j = 0; j < 4; ++j){
      float4 t = qr[j];
      qv[j*4+0] = t.x; qv[j*4+1] = t.y; qv[j*4+2] = t.z; qv[j*4+3] = t.w;
    }
  }
  float m = -1e30f, l = 0.f, acc[DHD] = {};
  const int kbeg = ks * KCH, kend = kbeg + KCH;
  for (int kt = kbeg; kt < kend; kt += 128){
    int cnt = min(128, kend - kt);
    __syncthreads();
    for (int el = threadIdx.x; el < cnt * 4; el += 128){
      int r = el >> 2, d4 = el & 3;
      const float4* base = (const float4*)(qkv + ((size_t)(b*SEQ + kt + r))*192 + h*DHD);
      ((float4*)Ks[r])[d4] = base[16 + d4];      // +64 floats  = K block
      ((float4*)Vs[r])[d4] = base[32 + d4];      // +128 floats = V block
    }
    __syncthreads();
    if (valid){
      for (int r = 0; r < cnt; ++r){
        float s = 0.f;
        #pragma unroll
        for (int d = 0; d < DHD; ++d) s = fmaf(qv[d], Ks[r][d], s);
        s *= 0.25f;
        float mn = fmaxf(m, s);
        float cc = __expf(m - mn), p = __expf(s - mn);
        l = l * cc + p;
        #pragma unroll
        for (int d = 0; d < DHD; ++d) acc[d] = fmaf(acc[d], cc, p * Vs[r][d]);
        m = mn;
      }
    }
  }
  if (valid){
    size_t qi = ((size_t)bh * SEQ + q) * KSPLIT + ks;
    Pm[qi] = m; Pl[qi] = l;
    #pragma unroll
    for (int d = 0; d < DHD; ++d) Pacc[qi*DHD + d] = acc[d];
  }
}

// stage 2: merge KSPLIT partials per query -> o[N][64]
__global__ void k_attn_comb(const float* __restrict__ Pm, const float* __restrict__ Pl,
                            const float* __restrict__ Pacc, float* __restrict__ o)
{
  int qi = blockIdx.x * blockDim.x + threadIdx.x;
  if (qi >= BATCH * NHTR * SEQ) return;
  float m = -1e30f;
  #pragma unroll
  for (int ks = 0; ks < KSPLIT; ++ks) m = fmaxf(m, Pm[(size_t)qi*KSPLIT + ks]);
  float l = 0.f, acc[DHD] = {};
  #pragma unroll
  for (int ks = 0; ks < KSPLIT; ++ks){
    size_t p = (size_t)qi*KSPLIT + ks;
    float sc = __expf(Pm[p] - m);
    l += Pl[p] * sc;
    #pragma unroll
    for (int d = 0; d < DHD; ++d) acc[d] = fmaf(Pacc[p*DHD + d], sc, acc[d]);
  }
  int bh = qi / SEQ, q = qi - bh * SEQ;
  int b = bh >> 2, h = bh & 3;
  float inv = 1.f / l;
  #pragma unroll
  for (int d = 0; d < DHD; ++d)
    o[((size_t)(b*SEQ + q))*64 + h*DHD + d] = acc[d] * inv;
}

// ---------------------------------------------------------------------------
__global__ __launch_bounds__(256) void k_addln(const float* __restrict__ x,
    const float* __restrict__ y, const float* __restrict__ g,
    const float* __restrict__ b, float* __restrict__ out)
{
  int row = blockIdx.x * 4 + (threadIdx.x >> 6);
  int lane = threadIdx.x & 63;
  if (row >= NN) return;
  float v = x[(size_t)row*64 + lane] + y[(size_t)row*64 + lane];
  float s1 = v, s2 = v * v;
  #pragma unroll
  for (int o = 32; o; o >>= 1){ s1 += __shfl_xor(s1, o); s2 += __shfl_xor(s2, o); }
  float mean = s1 * (1.f/64.f);
  float var  = s2 * (1.f/64.f) - mean * mean;
  float r = rsqrtf(var + 1e-5f);
  out[(size_t)row*64 + lane] = (v - mean) * r * g[lane] + b[lane];
}

__global__ void k_concat_feats(const float* __restrict__ x,
                               const float* __restrict__ tout,
                               float* __restrict__ feats)
{
  int i = blockIdx.x * blockDim.x + threadIdx.x;
  if (i >= NN * 21) return;
  int n = i / 21, c = i - 21*n;
  feats[i] = (c < 5) ? x[(size_t)n*7 + 2 + c] : tout[(size_t)n*16 + c - 5];
}

__global__ void k_initcoord(const float* __restrict__ x, float* __restrict__ coord)
{
  int i = blockIdx.x * blockDim.x + threadIdx.x;
  if (i >= NN * 2) return;
  coord[i] = x[(size_t)(i >> 1)*7 + (i & 1)];
}

// ---------------------------------------------------------------------------
// CSR build (by dst). dst for e>=NEDGE is the self-loop e-NEDGE.
// ---------------------------------------------------------------------------
__global__ void k_count(const int* __restrict__ dst, int* __restrict__ cnt)
{
  int e = blockIdx.x * blockDim.x + threadIdx.x;
  if (e >= ELOOP) return;
  int d = (e < NEDGE) ? dst[e] : e - NEDGE;
  atomicAdd(&cnt[d], 1);
}

__global__ __launch_bounds__(1024) void k_scan(const int* __restrict__ cnt,
                                               int* __restrict__ ptr)
{
  __shared__ int part[1024];
  int tid = threadIdx.x;
  const int per = 8;
  int loc[per]; int s = 0;
  int base = tid * per;
  #pragma unroll
  for (int i = 0; i < per; ++i){
    int v = (base + i < NN) ? cnt[base + i] : 0;
    loc[i] = s; s += v;
  }
  part[tid] = s;
  __syncthreads();
  for (int off = 1; off < 1024; off <<= 1){
    int v = 0;
    if (tid >= off) v = part[tid - off];
    __syncthreads();
    if (tid >= off) part[tid] += v;
    __syncthreads();
  }
  int pre = tid ? part[tid - 1] : 0;
  #pragma unroll
  for (int i = 0; i < per; ++i)
    if (base + i < NN) ptr[base + i] = pre + loc[i];
  if (tid == 1023) ptr[NN] = part[1023];
}

__global__ void k_fill(const int* __restrict__ dst, const int* __restrict__ ptr,
                       int* __restrict__ fil, int* __restrict__ eid)
{
  int e = blockIdx.x * blockDim.x + threadIdx.x;
  if (e >= ELOOP) return;
  int d = (e < NEDGE) ? dst[e] : e - NEDGE;
  int pos = ptr[d] + atomicAdd(&fil[d], 1);
  eid[pos] = e;
}

// ---------------------------------------------------------------------------
// logits[e,h] = sum_c lrelu(xl[src,h,c]+xr[dst,h,c]) * att[h,c]; wave/(e,h)
// ---------------------------------------------------------------------------
__global__ __launch_bounds__(256) void k_logits(const float* __restrict__ xl,
    const float* __restrict__ xr, const int* __restrict__ src_a,
    const int* __restrict__ dst_a, const float* __restrict__ att,
    float* __restrict__ logits)
{
  int wid = blockIdx.x * 4 + (threadIdx.x >> 6);
  if (wid >= ELOOP * NHEADS) return;
  int e = wid / NHEADS, h = wid - NHEADS * e;
  int lane = threadIdx.x & 63;
  int s = (e < NEDGE) ? src_a[e] : e - NEDGE;
  int d = (e < NEDGE) ? dst_a[e] : e - NEDGE;
  const float4* pl = (const float4*)(xl + (size_t)s * GOUT + h * HCD);
  const float4* pr = (const float4*)(xr + (size_t)d * GOUT + h * HCD);
  const float4* pa = (const float4*)(att + h * HCD);
  float acc = 0.f;
  #pragma unroll
  for (int j = 0; j < 2; ++j){
    int c = j * 64 + lane;
    float4 a = pl[c], r = pr[c], w = pa[c];
    float v;
    v = a.x + r.x; v = v > 0.f ? v : 0.2f * v; acc = fmaf(v, w.x, acc);
    v = a.y + r.y; v = v > 0.f ? v : 0.2f * v; acc = fmaf(v, w.y, acc);
    v = a.z + r.z; v = v > 0.f ? v : 0.2f * v; acc = fmaf(v, w.z, acc);
    v = a.w + r.w; v = v > 0.f ? v : 0.2f * v; acc = fmaf(v, w.w, acc);
  }
  #pragma unroll
  for (int o = 32; o; o >>= 1) acc += __shfl_xor(acc, o);
  if (lane == 0) logits[wid] = acc;
}

__global__ void k_stats(const float* __restrict__ logits, const int* __restrict__ ptr,
                        const int* __restrict__ eid, float* __restrict__ mx,
                        float* __restrict__ inv)
{
  int i = blockIdx.x * blockDim.x + threadIdx.x;
  if (i >= NN * NHEADS) return;
  int n = i / NHEADS, h = i - NHEADS * n;
  int s0 = ptr[n], s1 = ptr[n + 1];
  float m = -1e30f;
  for (int t = s0; t < s1; ++t) m = fmaxf(m, logits[eid[t]*NHEADS + h]);
  float s = 0.f;
  for (int t = s0; t < s1; ++t) s += __expf(logits[eid[t]*NHEADS + h] - m);
  mx[i] = m; inv[i] = 1.f / s;
}

// ---------------------------------------------------------------------------
// hidden[n,c] = selu(mean_h sum_{e in(n)} a[e,h]*xl[src,h,c] + gbias[c])
// ---------------------------------------------------------------------------
__global__ __launch_bounds__(256) void k_agg(const float* __restrict__ xl,
    const float* __restrict__ logits, const float* __restrict__ mx,
    const float* __restrict__ inv, const int* __restrict__ ptr,
    const int* __restrict__ eid, const int* __restrict__ src_a,
    const float* __restrict__ gbias, float* __restrict__ hidden)
{
  const int n = blockIdx.x;
  const int tid = threadIdx.x;
  __shared__ float a_sh[64 * NHEADS];
  __shared__ int src_sh[64];
  const int s0 = ptr[n];
  const int deg = ptr[n + 1] - s0;
  float acc[12] = {};
  for (int base = 0; base < deg; base += 64){
    int cnt = min(64, deg - base);
    __syncthreads();
    for (int t = tid; t < cnt * NHEADS; t += 256){
      int ei = t / NHEADS, h = t - NHEADS * ei;
      int e = eid[s0 + base + ei];
      a_sh[t] = __expf(logits[e*NHEADS + h] - mx[n*NHEADS + h]) * inv[n*NHEADS + h];
      if (h == 0) src_sh[ei] = (e < NEDGE) ? src_a[e] : e - NEDGE;
    }
    __syncthreads();
    for (int i2 = 0; i2 < cnt; ++i2){
      const float* row = xl + (size_t)src_sh[i2] * GOUT;
      #pragma unroll
      for (int k = 0; k < 12; ++k){
        int slot = tid + (k << 8);
        acc[k] = fmaf(row[slot], a_sh[i2*NHEADS + (slot >> 9)], acc[k]);
      }
    }
  }
  float m1 = (acc[0]+acc[2]+acc[4]+acc[6]+acc[8]+acc[10]) * (1.f/6.f);
  float m2 = (acc[1]+acc[3]+acc[5]+acc[7]+acc[9]+acc[11]) * (1.f/6.f);
  hidden[(size_t)n*HIDD + tid]       = selu_f(m1 + gbias[tid]);
  hidden[(size_t)n*HIDD + 256 + tid] = selu_f(m2 + gbias[256 + tid]);
}

// ---------------------------------------------------------------------------
extern "C" void kernel_launch(void* const* d_in, const int* in_sizes, int n_in,
                              void* d_out, int out_size, void* d_ws, size_t ws_size,
                              hipStream_t stream)
{
  const float* mesh     = (const float*)d_in[1];
  const float* xin      = (const float*)d_in[2];
  const int*   ei       = (const int*)d_in[3];
  const float* embed_w  = (const float*)d_in[4];
  const float* embed_b  = (const float*)d_in[5];
  const float* in_proj_w= (const float*)d_in[6];
  const float* in_proj_b= (const float*)d_in[7];
  const float* out_proj_w=(const float*)d_in[8];
  const float* out_proj_b=(const float*)d_in[9];
  const float* ln1_g    = (const float*)d_in[10];
  const float* ln1_b    = (const float*)d_in[11];
  const float* ln2_g    = (const float*)d_in[12];
  const float* ln2_b    = (const float*)d_in[13];
  const float* ff1_w    = (const float*)d_in[14];
  const float* ff1_b    = (const float*)d_in[15];
  const float* ff2_w    = (const float*)d_in[16];
  const float* ff2_b    = (const float*)d_in[17];
  const float* tout_w   = (const float*)d_in[18];
  const float* tout_b   = (const float*)d_in[19];
  const float* lin_w    = (const float*)d_in[20];
  const float* lin_b    = (const float*)d_in[21];
  const float* gat_wl   = (const float*)d_in[22];
  const float* gat_bl   = (const float*)d_in[23];
  const float* gat_wr   = (const float*)d_in[24];
  const float* gat_br   = (const float*)d_in[25];
  const float* gat_att  = (const float*)d_in[26];
  const float* gat_bias = (const float*)d_in[27];
  const float* coord1_w = (const float*)d_in[28];
  const float* coord1_b = (const float*)d_in[29];
  const float* coord2_w = (const float*)d_in[30];
  const float* coord2_b = (const float*)d_in[31];

  const int* esrc = ei;
  const int* edst = ei + NEDGE;

  char* ws = (char*)d_ws;
  size_t off = 0;
  auto alloc = [&](size_t nbytes){
    size_t o = off; off += (nbytes + 255) & ~(size_t)255; return o;
  };
  float* hidden = (float*)(ws + alloc((size_t)NN * HIDD * 4));
  float* coord  = (float*)(ws + alloc((size_t)NN * 2 * 4));
  float* xl     = (float*)(ws + alloc((size_t)NN * GOUT * 4));
  float* xr     = (float*)(ws + alloc((size_t)NN * GOUT * 4));
  float* logits = (float*)(ws + alloc((size_t)ELOOP * NHEADS * 4));
  float* mxb    = (float*)(ws + alloc((size_t)NN * NHEADS * 4));
  float* invb   = (float*)(ws + alloc((size_t)NN * NHEADS * 4));
  float* c1     = (float*)(ws + alloc((size_t)NN * 256 * 4));
  int*   ptr    = (int*)(ws + alloc((size_t)(NN + 1) * 4));
  int*   eid    = (int*)(ws + alloc((size_t)ELOOP * 4));
  int*   cnt    = (int*)(ws + alloc((size_t)NN * 4));
  int*   fil    = (int*)(ws + alloc((size_t)NN * 4));
  short* abf    = (short*)(ws + alloc((size_t)MPAD * K2 * 2));
  short* wlbf   = (short*)(ws + alloc((size_t)GOUT * K2 * 2));
  short* wrbf   = (short*)(ws + alloc((size_t)GOUT * K2 * 2));

  // phase-A temporaries aliased inside xl / xr (free before GAT loop)
  float* h     = (float*)((char*)xl + 0);
  float* qkv   = (float*)((char*)xl + (4u << 20));
  float* o     = (float*)((char*)xl + (12u << 20));
  float* tmp   = (float*)((char*)xl + (16u << 20));
  float* feats = (float*)((char*)xl + (20u << 20));
  float* toutb = (float*)((char*)xl + (24u << 20));
  float* part  = (float*)((char*)xl + (28u << 20));  // split-K partials (xl dead region)
  float* ffmid = xr;
  float* Pm    = (float*)((char*)xr + (70u << 20));
  float* Pl    = (float*)((char*)xr + (72u << 20));
  float* Pacc  = (float*)((char*)xr + (74u << 20));

  // ---- transformer ----
  k_embed<<<CDIV(NN*DTR, 256), 256, 0, stream>>>(mesh, embed_w, embed_b, h);
  k_gemm<0><<<dim3(CDIV(192,64), CDIV(NN,64)), 256, 0, stream>>>(h, in_proj_w, in_proj_b, qkv, NN, 192, DTR);
  k_attn_part<<<dim3(CDIV(SEQ,128), BATCH*NHTR, KSPLIT), 128, 0, stream>>>(qkv, Pm, Pl, Pacc);
  k_attn_comb<<<CDIV(BATCH*NHTR*SEQ, 256), 256, 0, stream>>>(Pm, Pl, Pacc, o);
  k_gemm<0><<<dim3(1, CDIV(NN,64)), 256, 0, stream>>>(o, out_proj_w, out_proj_b, tmp, NN, DTR, DTR);
  k_addln<<<CDIV(NN,4), 256, 0, stream>>>(h, tmp, ln1_g, ln1_b, h);
  k_gemm<1><<<dim3(CDIV(FFD,64), CDIV(NN,64)), 256, 0, stream>>>(h, ff1_w, ff1_b, ffmid, NN, FFD, DTR);
  // ff2 via split-K (K=2048 -> 8 x 256)
  k_gemm_sk<<<dim3(1, CDIV(NN,64), 8), 256, 0, stream>>>(ffmid, ff2_w, part, NN, DTR, FFD, 256);
  k_comb<0><<<CDIV(NN*DTR, 256), 256, 0, stream>>>(part, ff2_b, tmp, NN, DTR, 8);
  k_addln<<<CDIV(NN,4), 256, 0, stream>>>(h, tmp, ln2_g, ln2_b, h);
  k_gemm<0><<<dim3(1, CDIV(NN,64)), 256, 0, stream>>>(h, tout_w, tout_b, toutb, NN, TOUTD, DTR);
  k_concat_feats<<<CDIV(NN*21, 256), 256, 0, stream>>>(xin, toutb, feats);
  k_gemm<2><<<dim3(CDIV(HIDD,64), CDIV(NN,64)), 256, 0, stream>>>(feats, lin_w, lin_b, hidden, NN, HIDD, 21);
  k_initcoord<<<CDIV(NN*2, 256), 256, 0, stream>>>(xin, coord);

  // ---- CSR by dst + weight conversion (once) ----
  hipMemsetAsync(cnt, 0, (size_t)NN * 4, stream);
  hipMemsetAsync(fil, 0, (size_t)NN * 4, stream);
  k_count<<<CDIV(ELOOP, 256), 256, 0, stream>>>(edst, cnt);
  k_scan<<<1, 1024, 0, stream>>>(cnt, ptr);
  k_fill<<<CDIV(ELOOP, 256), 256, 0, stream>>>(edst, ptr, fil, eid);
  k_cvt_w<<<CDIV(GOUT*K1, 256), 256, 0, stream>>>(gat_wl, wlbf);
  k_cvt_w<<<CDIV(GOUT*K1, 256), 256, 0, stream>>>(gat_wr, wrbf);

  // ---- GAT loops ----
  for (int it = 0; it < 3; ++it){
    k_cvt_a<<<CDIV(MPAD*K1, 256), 256, 0, stream>>>(coord, hidden, abf);
    k_gat_mfma<<<dim3(GOUT/128, MPAD/128), 256, 0, stream>>>(abf, wlbf, gat_bl, xl);
    k_gat_mfma<<<dim3(GOUT/128, MPAD/128), 256, 0, stream>>>(abf, wrbf, gat_br, xr);
    k_logits<<<CDIV(ELOOP*NHEADS, 4), 256, 0, stream>>>(xl, xr, esrc, edst, gat_att, logits);
    k_stats<<<CDIV(NN*NHEADS, 256), 256, 0, stream>>>(logits, ptr, eid, mxb, invb);
    k_agg<<<NN, 256, 0, stream>>>(xl, logits, mxb, invb, ptr, eid, esrc, gat_bias, hidden);
    // coord1 via split-K (K=512 -> 4 x 128), selu in combine
    k_gemm_sk<<<dim3(CDIV(256,64), CDIV(NN,64), 4), 256, 0, stream>>>(hidden, coord1_w, part, NN, 256, HIDD, 128);
    k_comb<2><<<CDIV(NN*256, 256), 256, 0, stream>>>(part, coord1_b, c1, NN, 256, 4);
    float* cdst = (it == 2) ? (float*)d_out : coord;
    k_gemm<0><<<dim3(1, CDIV(NN,64)), 256, 0, stream>>>(c1, coord2_w, coord2_b, cdst, NN, 2, 256);
  }
}

// Round 9
// 1494.521 us; speedup vs baseline: 1.4882x; 1.2170x over previous
//
#include <hip/hip_runtime.h>
#include <hip/hip_bf16.h>
#include <math.h>

#define NN     8000
#define MPAD   8064    /* NN padded to 128 */
#define BATCH  4
#define SEQ    2000
#define DTR    64
#define NHTR   4
#define DHD    16
#define FFD    2048
#define TOUTD  16
#define HIDD   512
#define NHEADS 6
#define HCD    512
#define GIND   514
#define GOUT   3072
#define NEDGE  32000
#define ELOOP  40000   /* NEDGE + NN */

#define K1     576     /* GIND padded to 64-multiple */
#define K2     1152    /* hi + lo halves */

#define KSPLIT 8
#define KCH    250     /* SEQ / KSPLIT */

#define CDIV(a,b) (((a)+(b)-1)/(b))

using bf16x8 = __attribute__((__ext_vector_type__(8))) __bf16;
using f32x4  = __attribute__((__ext_vector_type__(4))) float;

__device__ __forceinline__ float selu_f(float x){
  const float a = 1.6732632423543772848f;
  const float s = 1.0507009873554805f;
  return x > 0.f ? s * x : s * a * (__expf(x) - 1.f);
}

__device__ __forceinline__ unsigned short f2bf_rn(float x){
  unsigned u = __float_as_uint(x);
  unsigned r = (u + 0x7fffu + ((u >> 16) & 1u)) >> 16;
  return (unsigned short)r;
}
__device__ __forceinline__ float bf2f(unsigned short h){
  return __uint_as_float((unsigned)h << 16);
}

// ---------------------------------------------------------------------------
// Generic C[M,N] = act(A[M,K] @ W[N,K]^T + bias). fp32, 64x64 tile, BK=16.
// ---------------------------------------------------------------------------
template<int ACT>  // 0=none 1=relu 2=selu
__global__ __launch_bounds__(256) void k_gemm(const float* __restrict__ A,
    const float* __restrict__ W, const float* __restrict__ bias,
    float* __restrict__ C, int M, int N, int K)
{
  __shared__ float As[16][68];
  __shared__ float Ws[16][68];
  const int tid = threadIdx.x;
  const int bm = blockIdx.y * 64, bn = blockIdx.x * 64;
  const int tx = tid & 15, ty = tid >> 4;
  float acc[4][4] = {};
  for (int k0 = 0; k0 < K; k0 += 16){
    #pragma unroll
    for (int i = 0; i < 4; ++i){
      int el = tid + (i << 8);
      int kk = el & 15, r = el >> 4;
      int gk = k0 + kk;
      int gm = bm + r;
      As[kk][r] = (gm < M && gk < K) ? A[(size_t)gm * K + gk] : 0.f;
      int gn = bn + r;
      Ws[kk][r] = (gn < N && gk < K) ? W[(size_t)gn * K + gk] : 0.f;
    }
    __syncthreads();
    #pragma unroll
    for (int kk = 0; kk < 16; ++kk){
      float av[4], wv[4];
      #pragma unroll
      for (int i = 0; i < 4; ++i) av[i] = As[kk][ty*4+i];
      #pragma unroll
      for (int j = 0; j < 4; ++j) wv[j] = Ws[kk][tx*4+j];
      #pragma unroll
      for (int i = 0; i < 4; ++i)
        #pragma unroll
        for (int j = 0; j < 4; ++j) acc[i][j] = fmaf(av[i], wv[j], acc[i][j]);
    }
    __syncthreads();
  }
  #pragma unroll
  for (int i = 0; i < 4; ++i){
    int gm = bm + ty*4 + i;
    if (gm >= M) continue;
    #pragma unroll
    for (int j = 0; j < 4; ++j){
      int gn = bn + tx*4 + j;
      if (gn >= N) continue;
      float v = acc[i][j] + bias[gn];
      if (ACT == 1) v = fmaxf(v, 0.f);
      if (ACT == 2) v = selu_f(v);
      C[(size_t)gm * N + gn] = v;
    }
  }
}

// ---------------------------------------------------------------------------
// Split-K GEMM: partial[z][M][N] = A[:, z*kchunk:(z+1)*kchunk] @ W^T slice.
// ---------------------------------------------------------------------------
__global__ __launch_bounds__(256) void k_gemm_sk(const float* __restrict__ A,
    const float* __restrict__ W, float* __restrict__ part,
    int M, int N, int K, int kchunk)
{
  __shared__ float As[16][68];
  __shared__ float Ws[16][68];
  const int tid = threadIdx.x;
  const int bm = blockIdx.y * 64, bn = blockIdx.x * 64;
  const int kbeg = blockIdx.z * kchunk;
  const int tx = tid & 15, ty = tid >> 4;
  float acc[4][4] = {};
  for (int k0 = kbeg; k0 < kbeg + kchunk; k0 += 16){
    #pragma unroll
    for (int i = 0; i < 4; ++i){
      int el = tid + (i << 8);
      int kk = el & 15, r = el >> 4;
      int gk = k0 + kk;
      int gm = bm + r;
      As[kk][r] = (gm < M && gk < K) ? A[(size_t)gm * K + gk] : 0.f;
      int gn = bn + r;
      Ws[kk][r] = (gn < N && gk < K) ? W[(size_t)gn * K + gk] : 0.f;
    }
    __syncthreads();
    #pragma unroll
    for (int kk = 0; kk < 16; ++kk){
      float av[4], wv[4];
      #pragma unroll
      for (int i = 0; i < 4; ++i) av[i] = As[kk][ty*4+i];
      #pragma unroll
      for (int j = 0; j < 4; ++j) wv[j] = Ws[kk][tx*4+j];
      #pragma unroll
      for (int i = 0; i < 4; ++i)
        #pragma unroll
        for (int j = 0; j < 4; ++j) acc[i][j] = fmaf(av[i], wv[j], acc[i][j]);
    }
    __syncthreads();
  }
  float* pz = part + (size_t)blockIdx.z * M * N;
  #pragma unroll
  for (int i = 0; i < 4; ++i){
    int gm = bm + ty*4 + i;
    if (gm >= M) continue;
    #pragma unroll
    for (int j = 0; j < 4; ++j){
      int gn = bn + tx*4 + j;
      if (gn >= N) continue;
      pz[(size_t)gm * N + gn] = acc[i][j];
    }
  }
}

// combine KS partials + bias + activation
template<int ACT>
__global__ void k_comb(const float* __restrict__ part, const float* __restrict__ bias,
                       float* __restrict__ C, int M, int N, int KS)
{
  int i = blockIdx.x * blockDim.x + threadIdx.x;
  if (i >= M * N) return;
  int n = i - N * (i / N);
  float v = bias[n];
  for (int z = 0; z < KS; ++z) v += part[(size_t)z * M * N + i];
  if (ACT == 1) v = fmaxf(v, 0.f);
  if (ACT == 2) v = selu_f(v);
  C[i] = v;
}

// ---------------------------------------------------------------------------
// weight fp32 [3072][514] -> bf16 split [3072][K2] = [hi(576) | lo(576)]
// ---------------------------------------------------------------------------
__global__ void k_cvt_w(const float* __restrict__ W, short* __restrict__ Wbf)
{
  int i = blockIdx.x * blockDim.x + threadIdx.x;
  if (i >= GOUT * K1) return;
  int n = i / K1, k = i - K1 * n;
  float v = (k < GIND) ? W[(size_t)n * GIND + k] : 0.f;
  unsigned short h = f2bf_rn(v);
  unsigned short l = f2bf_rn(v - bf2f(h));
  Wbf[(size_t)n * K2 + k]      = (short)h;
  Wbf[(size_t)n * K2 + K1 + k] = (short)l;
}

// A = [coord | hidden] fp32 -> bf16 split [MPAD][K2] = [hi(576) | lo(576)]
__global__ void k_cvt_a(const float* __restrict__ coord,
                        const float* __restrict__ hidden,
                        short* __restrict__ Abf)
{
  int i = blockIdx.x * blockDim.x + threadIdx.x;
  if (i >= MPAD * K1) return;
  int n = i / K1, k = i - K1 * n;
  float v = 0.f;
  if (n < NN && k < GIND)
    v = (k < 2) ? coord[(size_t)n*2 + k] : hidden[(size_t)n*HIDD + k - 2];
  unsigned short h = f2bf_rn(v);
  unsigned short l = f2bf_rn(v - bf2f(h));
  Abf[(size_t)n * K2 + k]      = (short)h;
  Abf[(size_t)n * K2 + K1 + k] = (short)l;
}

// ---------------------------------------------------------------------------
// GAT GEMM via MFMA bf16, 3-pass hi/lo split (27 K-tiles of 64).
// Output written as BF16 (edge phase reads bf16 -> halves traffic, L3-fits).
// LDS XOR swizzle both-sides; XCD-aware bijective block swizzle (1512=8*189).
// ---------------------------------------------------------------------------
__global__ __launch_bounds__(256) void k_gat_mfma(
    const short* __restrict__ Abf, const short* __restrict__ Wbf,
    const float* __restrict__ bias, unsigned short* __restrict__ Cb)
{
  __shared__ short As[128 * 64];
  __shared__ short Bs[128 * 64];
  const int tid  = threadIdx.x;
  int lin = blockIdx.y * 24 + blockIdx.x;          // 24*63 = 1512 = 8*189
  int wg  = (lin & 7) * 189 + (lin >> 3);          // bijective XCD chunking
  const int bm = (wg / 24) * 128, bn = (wg % 24) * 128;
  const int w    = tid >> 6, lane = tid & 63;
  const int wr   = w >> 1, wc = w & 1;
  const int lrow = lane & 15;

  f32x4 acc[4][4];
  #pragma unroll
  for (int i = 0; i < 4; ++i)
    #pragma unroll
    for (int j = 0; j < 4; ++j) acc[i][j] = (f32x4){0.f, 0.f, 0.f, 0.f};

  for (int kt = 0; kt < 27; ++kt){
    int aoff, boff;
    if (kt < 9)       { aoff = kt * 64;             boff = kt * 64; }
    else if (kt < 18) { aoff = K1 + (kt - 9) * 64;  boff = (kt - 9) * 64; }
    else              { aoff = (kt - 18) * 64;      boff = K1 + (kt - 18) * 64; }
    __syncthreads();                 // previous tile fully consumed
    #pragma unroll
    for (int i = 0; i < 4; ++i){
      int l  = i * 256 + tid;        // 16B-chunk index 0..1023
      int r  = l >> 3, j = l & 7;
      int js = j ^ (r & 7);          // source pre-swizzle (write side)
      const short* ga = Abf + (size_t)(bm + r) * K2 + aoff + js * 8;
      const short* gb = Wbf + (size_t)(bn + r) * K2 + boff + js * 8;
      short* la = As + ((i * 256 + w * 64) << 3);   // wave-uniform base
      short* lb = Bs + ((i * 256 + w * 64) << 3);
      __builtin_amdgcn_global_load_lds(
          (const __attribute__((address_space(1))) unsigned*)ga,
          (__attribute__((address_space(3))) unsigned*)la, 16, 0, 0);
      __builtin_amdgcn_global_load_lds(
          (const __attribute__((address_space(1))) unsigned*)gb,
          (__attribute__((address_space(3))) unsigned*)lb, 16, 0, 0);
    }
    __syncthreads();                 // drains vmcnt, tile ready
    #pragma unroll
    for (int ks = 0; ks < 2; ++ks){
      // read-side swizzle: chunk c = ks*4 + (lane>>4), row&7 == lrow&7
      const int co = ((ks * 4 + (lane >> 4)) ^ (lrow & 7)) * 8;
      bf16x8 fa[4], fb[4];
      #pragma unroll
      for (int mi = 0; mi < 4; ++mi)
        fa[mi] = *(const bf16x8*)&As[(wr*64 + mi*16 + lrow) * 64 + co];
      #pragma unroll
      for (int ni = 0; ni < 4; ++ni)
        fb[ni] = *(const bf16x8*)&Bs[(wc*64 + ni*16 + lrow) * 64 + co];
      #pragma unroll
      for (int mi = 0; mi < 4; ++mi)
        #pragma unroll
        for (int ni = 0; ni < 4; ++ni)
          acc[mi][ni] = __builtin_amdgcn_mfma_f32_16x16x32_bf16(
              fa[mi], fb[ni], acc[mi][ni], 0, 0, 0);
    }
  }
  // epilogue: bf16 output. col = lane&15, row = (lane>>4)*4 + j
  #pragma unroll
  for (int mi = 0; mi < 4; ++mi){
    #pragma unroll
    for (int ni = 0; ni < 4; ++ni){
      int gn = bn + wc*64 + ni*16 + lrow;
      float bv = bias[gn];
      #pragma unroll
      for (int j = 0; j < 4; ++j){
        int gm = bm + wr*64 + mi*16 + (lane >> 4) * 4 + j;
        if (gm < NN)
          Cb[(size_t)gm * GOUT + gn] = f2bf_rn(acc[mi][ni][j] + bv);
      }
    }
  }
}

// ---------------------------------------------------------------------------
__global__ void k_embed(const float* __restrict__ mesh,
                        const float* __restrict__ w, const float* __restrict__ b,
                        float* __restrict__ h)
{
  int i = blockIdx.x * blockDim.x + threadIdx.x;
  if (i >= NN * DTR) return;
  int n = i >> 6, d = i & 63;
  const float* mr = mesh + n * 4;
  const float* wr = w + d * 4;
  h[i] = fmaf(mr[0], wr[0], fmaf(mr[1], wr[1], fmaf(mr[2], wr[2], mr[3]*wr[3]))) + b[d];
}

// ---------------------------------------------------------------------------
// split-K flash attention, stage 1: partials per (query, ksplit)
// ---------------------------------------------------------------------------
__global__ __launch_bounds__(128) void k_attn_part(const float* __restrict__ qkv,
    float* __restrict__ Pm, float* __restrict__ Pl, float* __restrict__ Pacc)
{
  __shared__ float Ks[128][DHD];
  __shared__ float Vs[128][DHD];
  const int q  = blockIdx.x * 128 + threadIdx.x;
  const int bh = blockIdx.y;
  const int b  = bh >> 2, h = bh & 3;
  const int ks = blockIdx.z;
  const bool valid = q < SEQ;
  float qv[DHD];
  if (valid){
    const float4* qr = (const float4*)(qkv + ((size_t)(b*SEQ + q))*192 + h*DHD);
    #pragma unroll
    for (int j = 0; j < 4; ++j){
      float4 t = qr[j];
      qv[j*4+0] = t.x; qv[j*4+1] = t.y; qv[j*4+2] = t.z; qv[j*4+3] = t.w;
    }
  }
  float m = -1e30f, l = 0.f, acc[DHD] = {};
  const int kbeg = ks * KCH, kend = kbeg + KCH;
  for (int kt = kbeg; kt < kend; kt += 128){
    int cnt = min(128, kend - kt);
    __syncthreads();
    for (int el = threadIdx.x; el < cnt * 4; el += 128){
      int r = el >> 2, d4 = el & 3;
      const float4* base = (const float4*)(qkv + ((size_t)(b*SEQ + kt + r))*192 + h*DHD);
      ((float4*)Ks[r])[d4] = base[16 + d4];      // +64 floats  = K block
      ((float4*)Vs[r])[d4] = base[32 + d4];      // +128 floats = V block
    }
    __syncthreads();
    if (valid){
      for (int r = 0; r < cnt; ++r){
        float s = 0.f;
        #pragma unroll
        for (int d = 0; d < DHD; ++d) s = fmaf(qv[d], Ks[r][d], s);
        s *= 0.25f;
        float mn = fmaxf(m, s);
        float cc = __expf(m - mn), p = __expf(s - mn);
        l = l * cc + p;
        #pragma unroll
        for (int d = 0; d < DHD; ++d) acc[d] = fmaf(acc[d], cc, p * Vs[r][d]);
        m = mn;
      }
    }
  }
  if (valid){
    size_t qi = ((size_t)bh * SEQ + q) * KSPLIT + ks;
    Pm[qi] = m; Pl[qi] = l;
    #pragma unroll
    for (int d = 0; d < DHD; ++d) Pacc[qi*DHD + d] = acc[d];
  }
}

// stage 2: merge KSPLIT partials per query -> o[N][64]
__global__ void k_attn_comb(const float* __restrict__ Pm, const float* __restrict__ Pl,
                            const float* __restrict__ Pacc, float* __restrict__ o)
{
  int qi = blockIdx.x * blockDim.x + threadIdx.x;
  if (qi >= BATCH * NHTR * SEQ) return;
  float m = -1e30f;
  #pragma unroll
  for (int ks = 0; ks < KSPLIT; ++ks) m = fmaxf(m, Pm[(size_t)qi*KSPLIT + ks]);
  float l = 0.f, acc[DHD] = {};
  #pragma unroll
  for (int ks = 0; ks < KSPLIT; ++ks){
    size_t p = (size_t)qi*KSPLIT + ks;
    float sc = __expf(Pm[p] - m);
    l += Pl[p] * sc;
    #pragma unroll
    for (int d = 0; d < DHD; ++d) acc[d] = fmaf(Pacc[p*DHD + d], sc, acc[d]);
  }
  int bh = qi / SEQ, q = qi - bh * SEQ;
  int b = bh >> 2, h = bh & 3;
  float inv = 1.f / l;
  #pragma unroll
  for (int d = 0; d < DHD; ++d)
    o[((size_t)(b*SEQ + q))*64 + h*DHD + d] = acc[d] * inv;
}

// ---------------------------------------------------------------------------
__global__ __launch_bounds__(256) void k_addln(const float* __restrict__ x,
    const float* __restrict__ y, const float* __restrict__ g,
    const float* __restrict__ b, float* __restrict__ out)
{
  int row = blockIdx.x * 4 + (threadIdx.x >> 6);
  int lane = threadIdx.x & 63;
  if (row >= NN) return;
  float v = x[(size_t)row*64 + lane] + y[(size_t)row*64 + lane];
  float s1 = v, s2 = v * v;
  #pragma unroll
  for (int o = 32; o; o >>= 1){ s1 += __shfl_xor(s1, o); s2 += __shfl_xor(s2, o); }
  float mean = s1 * (1.f/64.f);
  float var  = s2 * (1.f/64.f) - mean * mean;
  float r = rsqrtf(var + 1e-5f);
  out[(size_t)row*64 + lane] = (v - mean) * r * g[lane] + b[lane];
}

__global__ void k_concat_feats(const float* __restrict__ x,
                               const float* __restrict__ tout,
                               float* __restrict__ feats)
{
  int i = blockIdx.x * blockDim.x + threadIdx.x;
  if (i >= NN * 21) return;
  int n = i / 21, c = i - 21*n;
  feats[i] = (c < 5) ? x[(size_t)n*7 + 2 + c] : tout[(size_t)n*16 + c - 5];
}

__global__ void k_initcoord(const float* __restrict__ x, float* __restrict__ coord)
{
  int i = blockIdx.x * blockDim.x + threadIdx.x;
  if (i >= NN * 2) return;
  coord[i] = x[(size_t)(i >> 1)*7 + (i & 1)];
}

// ---------------------------------------------------------------------------
// CSR build (by dst). dst for e>=NEDGE is the self-loop e-NEDGE.
// ---------------------------------------------------------------------------
__global__ void k_count(const int* __restrict__ dst, int* __restrict__ cnt)
{
  int e = blockIdx.x * blockDim.x + threadIdx.x;
  if (e >= ELOOP) return;
  int d = (e < NEDGE) ? dst[e] : e - NEDGE;
  atomicAdd(&cnt[d], 1);
}

__global__ __launch_bounds__(1024) void k_scan(const int* __restrict__ cnt,
                                               int* __restrict__ ptr)
{
  __shared__ int part[1024];
  int tid = threadIdx.x;
  const int per = 8;
  int loc[per]; int s = 0;
  int base = tid * per;
  #pragma unroll
  for (int i = 0; i < per; ++i){
    int v = (base + i < NN) ? cnt[base + i] : 0;
    loc[i] = s; s += v;
  }
  part[tid] = s;
  __syncthreads();
  for (int off = 1; off < 1024; off <<= 1){
    int v = 0;
    if (tid >= off) v = part[tid - off];
    __syncthreads();
    if (tid >= off) part[tid] += v;
    __syncthreads();
  }
  int pre = tid ? part[tid - 1] : 0;
  #pragma unroll
  for (int i = 0; i < per; ++i)
    if (base + i < NN) ptr[base + i] = pre + loc[i];
  if (tid == 1023) ptr[NN] = part[1023];
}

__global__ void k_fill(const int* __restrict__ dst, const int* __restrict__ ptr,
                       int* __restrict__ fil, int* __restrict__ eid)
{
  int e = blockIdx.x * blockDim.x + threadIdx.x;
  if (e >= ELOOP) return;
  int d = (e < NEDGE) ? dst[e] : e - NEDGE;
  int pos = ptr[d] + atomicAdd(&fil[d], 1);
  eid[pos] = e;
}

// ---------------------------------------------------------------------------
// logits2[pos*6+h] over CSR (dst-sorted) positions. bf16 xl/xr, uint4 loads.
// wave per (pos,h); XCD-chunked block swizzle (60000 blocks = 8 * 7500).
// ---------------------------------------------------------------------------
__global__ __launch_bounds__(256) void k_logits(const unsigned short* __restrict__ xlb,
    const unsigned short* __restrict__ xrb, const int* __restrict__ src_a,
    const int* __restrict__ dst_a, const int* __restrict__ eid,
    const float* __restrict__ att, float* __restrict__ logits2)
{
  int bid = blockIdx.x;                         // 60000 = 8 * 7500
  int wgs = (bid & 7) * 7500 + (bid >> 3);      // bijective XCD chunking
  int wid = wgs * 4 + (threadIdx.x >> 6);
  if (wid >= ELOOP * NHEADS) return;
  int pos = wid / NHEADS, h = wid - NHEADS * pos;
  int lane = threadIdx.x & 63;
  int e = eid[pos];
  int s = (e < NEDGE) ? src_a[e] : e - NEDGE;
  int d = (e < NEDGE) ? dst_a[e] : e - NEDGE;
  const uint4* pl = (const uint4*)(xlb + (size_t)s * GOUT + h * HCD);
  const uint4* pr = (const uint4*)(xrb + (size_t)d * GOUT + h * HCD);
  const float4* pa = (const float4*)(att + h * HCD);
  uint4 ua = pl[lane];
  uint4 ub = pr[lane];
  float4 w0 = pa[lane*2], w1 = pa[lane*2 + 1];
  float acc = 0.f;
  auto pair = [&](unsigned a, unsigned b, float wl, float wh){
    float vl = __uint_as_float(a << 16)        + __uint_as_float(b << 16);
    float vh = __uint_as_float(a & 0xffff0000u)+ __uint_as_float(b & 0xffff0000u);
    vl = vl > 0.f ? vl : 0.2f * vl;
    vh = vh > 0.f ? vh : 0.2f * vh;
    acc = fmaf(vl, wl, acc);
    acc = fmaf(vh, wh, acc);
  };
  pair(ua.x, ub.x, w0.x, w0.y);
  pair(ua.y, ub.y, w0.z, w0.w);
  pair(ua.z, ub.z, w1.x, w1.y);
  pair(ua.w, ub.w, w1.z, w1.w);
  #pragma unroll
  for (int o = 32; o; o >>= 1) acc += __shfl_xor(acc, o);
  if (lane == 0) logits2[wid] = acc;
}

// mx / inv(sum) per (node, head); logits2 is pos-ordered -> sequential reads
__global__ void k_stats(const float* __restrict__ logits2, const int* __restrict__ ptr,
                        float* __restrict__ mx, float* __restrict__ inv)
{
  int i = blockIdx.x * blockDim.x + threadIdx.x;
  if (i >= NN * NHEADS) return;
  int n = i / NHEADS, h = i - NHEADS * n;
  int s0 = ptr[n], s1 = ptr[n + 1];
  float m = -1e30f;
  for (int t = s0; t < s1; ++t) m = fmaxf(m, logits2[t*NHEADS + h]);
  float s = 0.f;
  for (int t = s0; t < s1; ++t) s += __expf(logits2[t*NHEADS + h] - m);
  mx[i] = m; inv[i] = 1.f / s;
}

// ---------------------------------------------------------------------------
// hidden[n,c] = selu(mean_h sum_{e in(n)} a[e,h]*xl[src,h,c] + gbias[c])
// bf16 xl; thread t owns channel pairs (512k + 2t, 512k + 2t+1), head = k.
// ---------------------------------------------------------------------------
__global__ __launch_bounds__(256) void k_agg(const unsigned short* __restrict__ xlb,
    const float* __restrict__ logits2, const float* __restrict__ mx,
    const float* __restrict__ inv, const int* __restrict__ ptr,
    const int* __restrict__ eid, const int* __restrict__ src_a,
    const float* __restrict__ gbias, float* __restrict__ hidden)
{
  const int n = blockIdx.x;
  const int tid = threadIdx.x;
  __shared__ float a_sh[64 * NHEADS];
  __shared__ int src_sh[64];
  const int s0 = ptr[n];
  const int deg = ptr[n + 1] - s0;
  float acc[12] = {};
  for (int base = 0; base < deg; base += 64){
    int cnt = min(64, deg - base);
    __syncthreads();
    for (int t = tid; t < cnt * NHEADS; t += 256){
      int ei = t / NHEADS, h = t - NHEADS * ei;
      a_sh[t] = __expf(logits2[(s0 + base + ei)*NHEADS + h] - mx[n*NHEADS + h])
                * inv[n*NHEADS + h];
      if (h == 0){
        int e = eid[s0 + base + ei];
        src_sh[ei] = (e < NEDGE) ? src_a[e] : e - NEDGE;
      }
    }
    __syncthreads();
    for (int i2 = 0; i2 < cnt; ++i2){
      const unsigned* row = (const unsigned*)(xlb + (size_t)src_sh[i2] * GOUT);
      #pragma unroll
      for (int k = 0; k < NHEADS; ++k){
        unsigned u = row[tid + (k << 8)];
        float wgt = a_sh[i2*NHEADS + k];
        acc[2*k]   = fmaf(__uint_as_float(u << 16),         wgt, acc[2*k]);
        acc[2*k+1] = fmaf(__uint_as_float(u & 0xffff0000u), wgt, acc[2*k+1]);
      }
    }
  }
  float m0 = (acc[0]+acc[2]+acc[4]+acc[6]+acc[8]+acc[10]) * (1.f/6.f);
  float m1 = (acc[1]+acc[3]+acc[5]+acc[7]+acc[9]+acc[11]) * (1.f/6.f);
  float2 out;
  out.x = selu_f(m0 + gbias[2*tid]);
  out.y = selu_f(m1 + gbias[2*tid + 1]);
  *(float2*)&hidden[(size_t)n*HIDD + 2*tid] = out;
}

// ---------------------------------------------------------------------------
extern "C" void kernel_launch(void* const* d_in, const int* in_sizes, int n_in,
                              void* d_out, int out_size, void* d_ws, size_t ws_size,
                              hipStream_t stream)
{
  const float* mesh     = (const float*)d_in[1];
  const float* xin      = (const float*)d_in[2];
  const int*   ei       = (const int*)d_in[3];
  const float* embed_w  = (const float*)d_in[4];
  const float* embed_b  = (const float*)d_in[5];
  const float* in_proj_w= (const float*)d_in[6];
  const float* in_proj_b= (const float*)d_in[7];
  const float* out_proj_w=(const float*)d_in[8];
  const float* out_proj_b=(const float*)d_in[9];
  const float* ln1_g    = (const float*)d_in[10];
  const float* ln1_b    = (const float*)d_in[11];
  const float* ln2_g    = (const float*)d_in[12];
  const float* ln2_b    = (const float*)d_in[13];
  const float* ff1_w    = (const float*)d_in[14];
  const float* ff1_b    = (const float*)d_in[15];
  const float* ff2_w    = (const float*)d_in[16];
  const float* ff2_b    = (const float*)d_in[17];
  const float* tout_w   = (const float*)d_in[18];
  const float* tout_b   = (const float*)d_in[19];
  const float* lin_w    = (const float*)d_in[20];
  const float* lin_b    = (const float*)d_in[21];
  const float* gat_wl   = (const float*)d_in[22];
  const float* gat_bl   = (const float*)d_in[23];
  const float* gat_wr   = (const float*)d_in[24];
  const float* gat_br   = (const float*)d_in[25];
  const float* gat_att  = (const float*)d_in[26];
  const float* gat_bias = (const float*)d_in[27];
  const float* coord1_w = (const float*)d_in[28];
  const float* coord1_b = (const float*)d_in[29];
  const float* coord2_w = (const float*)d_in[30];
  const float* coord2_b = (const float*)d_in[31];

  const int* esrc = ei;
  const int* edst = ei + NEDGE;

  char* ws = (char*)d_ws;
  size_t off = 0;
  auto alloc = [&](size_t nbytes){
    size_t o = off; off += (nbytes + 255) & ~(size_t)255; return o;
  };
  float* hidden = (float*)(ws + alloc((size_t)NN * HIDD * 4));
  float* coord  = (float*)(ws + alloc((size_t)NN * 2 * 4));
  unsigned short* xlb = (unsigned short*)(ws + alloc((size_t)NN * GOUT * 2));
  unsigned short* xrb = (unsigned short*)(ws + alloc((size_t)NN * GOUT * 2));
  float* logits = (float*)(ws + alloc((size_t)ELOOP * NHEADS * 4));
  float* mxb    = (float*)(ws + alloc((size_t)NN * NHEADS * 4));
  float* invb   = (float*)(ws + alloc((size_t)NN * NHEADS * 4));
  float* c1     = (float*)(ws + alloc((size_t)NN * 256 * 4));
  int*   ptr    = (int*)(ws + alloc((size_t)(NN + 1) * 4));
  int*   eid    = (int*)(ws + alloc((size_t)ELOOP * 4));
  int*   cnt    = (int*)(ws + alloc((size_t)NN * 4));
  int*   fil    = (int*)(ws + alloc((size_t)NN * 4));
  short* abf    = (short*)(ws + alloc((size_t)MPAD * K2 * 2));
  short* wlbf   = (short*)(ws + alloc((size_t)GOUT * K2 * 2));
  short* wrbf   = (short*)(ws + alloc((size_t)GOUT * K2 * 2));
  float* part_c1= (float*)(ws + alloc((size_t)4 * NN * 256 * 4));  // 31.25 MiB

  // Transformer-phase temporaries ALIASED inside xlb+xrb (93.75 MiB, all
  // dead before the first k_gat_mfma writes xlb). MiB offsets within region:
  char* arena = (char*)xlb;
  float* h       = (float*)(arena + ((size_t)0  << 20));  // 0-2   (live to ln2)
  float* o       = (float*)(arena + ((size_t)2  << 20));  // 2-4
  float* tmp     = (float*)(arena + ((size_t)4  << 20));  // 4-6
  float* feats   = (float*)(arena + ((size_t)6  << 20));  // 6-6.7
  float* toutb   = (float*)(arena + ((size_t)7  << 20));  // 7-7.6
  float* qkv     = (float*)(arena + ((size_t)8  << 20));  // 8-14.2  (dead after attn)
  float* Pm      = (float*)(arena + ((size_t)16 << 20));  // 16-17   (dead after comb)
  float* Pl      = (float*)(arena + ((size_t)17 << 20));  // 17-18
  float* Pacc    = (float*)(arena + ((size_t)18 << 20));  // 18-33.7 (dead after comb)
  float* part_f2 = (float*)(arena + ((size_t)8  << 20));  // 8-23.7  (after attn dead)
  float* ffmid   = (float*)(arena + ((size_t)28 << 20));  // 28-90.5 (< 93.75 OK)

  // ---- transformer ----
  k_embed<<<CDIV(NN*DTR, 256), 256, 0, stream>>>(mesh, embed_w, embed_b, h);
  k_gemm<0><<<dim3(CDIV(192,64), CDIV(NN,64)), 256, 0, stream>>>(h, in_proj_w, in_proj_b, qkv, NN, 192, DTR);
  k_attn_part<<<dim3(CDIV(SEQ,128), BATCH*NHTR, KSPLIT), 128, 0, stream>>>(qkv, Pm, Pl, Pacc);
  k_attn_comb<<<CDIV(BATCH*NHTR*SEQ, 256), 256, 0, stream>>>(Pm, Pl, Pacc, o);
  k_gemm<0><<<dim3(1, CDIV(NN,64)), 256, 0, stream>>>(o, out_proj_w, out_proj_b, tmp, NN, DTR, DTR);
  k_addln<<<CDIV(NN,4), 256, 0, stream>>>(h, tmp, ln1_g, ln1_b, h);
  k_gemm<1><<<dim3(CDIV(FFD,64), CDIV(NN,64)), 256, 0, stream>>>(h, ff1_w, ff1_b, ffmid, NN, FFD, DTR);
  k_gemm_sk<<<dim3(1, CDIV(NN,64), 8), 256, 0, stream>>>(ffmid, ff2_w, part_f2, NN, DTR, FFD, 256);
  k_comb<0><<<CDIV(NN*DTR, 256), 256, 0, stream>>>(part_f2, ff2_b, tmp, NN, DTR, 8);
  k_addln<<<CDIV(NN,4), 256, 0, stream>>>(h, tmp, ln2_g, ln2_b, h);
  k_gemm<0><<<dim3(1, CDIV(NN,64)), 256, 0, stream>>>(h, tout_w, tout_b, toutb, NN, TOUTD, DTR);
  k_concat_feats<<<CDIV(NN*21, 256), 256, 0, stream>>>(xin, toutb, feats);
  k_gemm<2><<<dim3(CDIV(HIDD,64), CDIV(NN,64)), 256, 0, stream>>>(feats, lin_w, lin_b, hidden, NN, HIDD, 21);
  k_initcoord<<<CDIV(NN*2, 256), 256, 0, stream>>>(xin, coord);

  // ---- CSR by dst + weight conversion (once) ----
  hipMemsetAsync(cnt, 0, (size_t)NN * 4, stream);
  hipMemsetAsync(fil, 0, (size_t)NN * 4, stream);
  k_count<<<CDIV(ELOOP, 256), 256, 0, stream>>>(edst, cnt);
  k_scan<<<1, 1024, 0, stream>>>(cnt, ptr);
  k_fill<<<CDIV(ELOOP, 256), 256, 0, stream>>>(edst, ptr, fil, eid);
  k_cvt_w<<<CDIV(GOUT*K1, 256), 256, 0, stream>>>(gat_wl, wlbf);
  k_cvt_w<<<CDIV(GOUT*K1, 256), 256, 0, stream>>>(gat_wr, wrbf);

  // ---- GAT loops ----
  for (int it = 0; it < 3; ++it){
    k_cvt_a<<<CDIV(MPAD*K1, 256), 256, 0, stream>>>(coord, hidden, abf);
    k_gat_mfma<<<dim3(GOUT/128, MPAD/128), 256, 0, stream>>>(abf, wlbf, gat_bl, xlb);
    k_gat_mfma<<<dim3(GOUT/128, MPAD/128), 256, 0, stream>>>(abf, wrbf, gat_br, xrb);
    k_logits<<<ELOOP*NHEADS/4, 256, 0, stream>>>(xlb, xrb, esrc, edst, eid, gat_att, logits);
    k_stats<<<CDIV(NN*NHEADS, 256), 256, 0, stream>>>(logits, ptr, mxb, invb);
    k_agg<<<NN, 256, 0, stream>>>(xlb, logits, mxb, invb, ptr, eid, esrc, gat_bias, hidden);
    k_gemm_sk<<<dim3(CDIV(256,64), CDIV(NN,64), 4), 256, 0, stream>>>(hidden, coord1_w, part_c1, NN, 256, HIDD, 128);
    k_comb<2><<<CDIV(NN*256, 256), 256, 0, stream>>>(part_c1, coord1_b, c1, NN, 256, 4);
    float* cdst = (it == 2) ? (float*)d_out : coord;
    k_gemm<0><<<dim3(1, CDIV(NN,64)), 256, 0, stream>>>(c1, coord2_w, coord2_b, cdst, NN, 2, 256);
  }
}

// Round 10
// 1354.782 us; speedup vs baseline: 1.6417x; 1.1031x over previous
//
#include <hip/hip_runtime.h>
#include <hip/hip_bf16.h>
#include <math.h>

#define NN     8000
#define MPAD   8064    /* NN padded to 128 */
#define BATCH  4
#define SEQ    2000
#define DTR    64
#define NHTR   4
#define DHD    16
#define FFD    2048
#define TOUTD  16
#define HIDD   512
#define NHEADS 6
#define HCD    512
#define GIND   514
#define GOUT   3072
#define NEDGE  32000
#define ELOOP  40000   /* NEDGE + NN */

#define K1     576     /* GIND padded to 64-multiple */
#define K2     1152    /* hi + lo halves (A only) */

#define KSPLIT 8
#define KCH    250     /* SEQ / KSPLIT */

#define CDIV(a,b) (((a)+(b)-1)/(b))

using bf16x8 = __attribute__((__ext_vector_type__(8))) __bf16;
using f32x4  = __attribute__((__ext_vector_type__(4))) float;

__device__ __forceinline__ float selu_f(float x){
  const float a = 1.6732632423543772848f;
  const float s = 1.0507009873554805f;
  return x > 0.f ? s * x : s * a * (__expf(x) - 1.f);
}

__device__ __forceinline__ unsigned short f2bf_rn(float x){
  unsigned u = __float_as_uint(x);
  unsigned r = (u + 0x7fffu + ((u >> 16) & 1u)) >> 16;
  return (unsigned short)r;
}
__device__ __forceinline__ float bf2f(unsigned short h){
  return __uint_as_float((unsigned)h << 16);
}

// ---------------------------------------------------------------------------
// Generic C[M,N] = act(A[M,K] @ W[N,K]^T + bias). fp32, 64x64 tile, BK=16.
// ---------------------------------------------------------------------------
template<int ACT>  // 0=none 1=relu 2=selu
__global__ __launch_bounds__(256) void k_gemm(const float* __restrict__ A,
    const float* __restrict__ W, const float* __restrict__ bias,
    float* __restrict__ C, int M, int N, int K)
{
  __shared__ float As[16][68];
  __shared__ float Ws[16][68];
  const int tid = threadIdx.x;
  const int bm = blockIdx.y * 64, bn = blockIdx.x * 64;
  const int tx = tid & 15, ty = tid >> 4;
  float acc[4][4] = {};
  for (int k0 = 0; k0 < K; k0 += 16){
    #pragma unroll
    for (int i = 0; i < 4; ++i){
      int el = tid + (i << 8);
      int kk = el & 15, r = el >> 4;
      int gk = k0 + kk;
      int gm = bm + r;
      As[kk][r] = (gm < M && gk < K) ? A[(size_t)gm * K + gk] : 0.f;
      int gn = bn + r;
      Ws[kk][r] = (gn < N && gk < K) ? W[(size_t)gn * K + gk] : 0.f;
    }
    __syncthreads();
    #pragma unroll
    for (int kk = 0; kk < 16; ++kk){
      float av[4], wv[4];
      #pragma unroll
      for (int i = 0; i < 4; ++i) av[i] = As[kk][ty*4+i];
      #pragma unroll
      for (int j = 0; j < 4; ++j) wv[j] = Ws[kk][tx*4+j];
      #pragma unroll
      for (int i = 0; i < 4; ++i)
        #pragma unroll
        for (int j = 0; j < 4; ++j) acc[i][j] = fmaf(av[i], wv[j], acc[i][j]);
    }
    __syncthreads();
  }
  #pragma unroll
  for (int i = 0; i < 4; ++i){
    int gm = bm + ty*4 + i;
    if (gm >= M) continue;
    #pragma unroll
    for (int j = 0; j < 4; ++j){
      int gn = bn + tx*4 + j;
      if (gn >= N) continue;
      float v = acc[i][j] + bias[gn];
      if (ACT == 1) v = fmaxf(v, 0.f);
      if (ACT == 2) v = selu_f(v);
      C[(size_t)gm * N + gn] = v;
    }
  }
}

// ---------------------------------------------------------------------------
// Split-K GEMM: partial[z][M][N] = A[:, z*kchunk:(z+1)*kchunk] @ W^T slice.
// ---------------------------------------------------------------------------
__global__ __launch_bounds__(256) void k_gemm_sk(const float* __restrict__ A,
    const float* __restrict__ W, float* __restrict__ part,
    int M, int N, int K, int kchunk)
{
  __shared__ float As[16][68];
  __shared__ float Ws[16][68];
  const int tid = threadIdx.x;
  const int bm = blockIdx.y * 64, bn = blockIdx.x * 64;
  const int kbeg = blockIdx.z * kchunk;
  const int tx = tid & 15, ty = tid >> 4;
  float acc[4][4] = {};
  for (int k0 = kbeg; k0 < kbeg + kchunk; k0 += 16){
    #pragma unroll
    for (int i = 0; i < 4; ++i){
      int el = tid + (i << 8);
      int kk = el & 15, r = el >> 4;
      int gk = k0 + kk;
      int gm = bm + r;
      As[kk][r] = (gm < M && gk < K) ? A[(size_t)gm * K + gk] : 0.f;
      int gn = bn + r;
      Ws[kk][r] = (gn < N && gk < K) ? W[(size_t)gn * K + gk] : 0.f;
    }
    __syncthreads();
    #pragma unroll
    for (int kk = 0; kk < 16; ++kk){
      float av[4], wv[4];
      #pragma unroll
      for (int i = 0; i < 4; ++i) av[i] = As[kk][ty*4+i];
      #pragma unroll
      for (int j = 0; j < 4; ++j) wv[j] = Ws[kk][tx*4+j];
      #pragma unroll
      for (int i = 0; i < 4; ++i)
        #pragma unroll
        for (int j = 0; j < 4; ++j) acc[i][j] = fmaf(av[i], wv[j], acc[i][j]);
    }
    __syncthreads();
  }
  float* pz = part + (size_t)blockIdx.z * M * N;
  #pragma unroll
  for (int i = 0; i < 4; ++i){
    int gm = bm + ty*4 + i;
    if (gm >= M) continue;
    #pragma unroll
    for (int j = 0; j < 4; ++j){
      int gn = bn + tx*4 + j;
      if (gn >= N) continue;
      pz[(size_t)gm * N + gn] = acc[i][j];
    }
  }
}

// combine KS partials + bias + activation
template<int ACT>
__global__ void k_comb(const float* __restrict__ part, const float* __restrict__ bias,
                       float* __restrict__ C, int M, int N, int KS)
{
  int i = blockIdx.x * blockDim.x + threadIdx.x;
  if (i >= M * N) return;
  int n = i - N * (i / N);
  float v = bias[n];
  for (int z = 0; z < KS; ++z) v += part[(size_t)z * M * N + i];
  if (ACT == 1) v = fmaxf(v, 0.f);
  if (ACT == 2) v = selu_f(v);
  C[i] = v;
}

// ---------------------------------------------------------------------------
// weight fp32 [3072][514] -> single bf16 (RN) [3072][K1]
// ---------------------------------------------------------------------------
__global__ void k_cvt_w(const float* __restrict__ W, short* __restrict__ Wbf)
{
  int i = blockIdx.x * blockDim.x + threadIdx.x;
  if (i >= GOUT * K1) return;
  int n = i / K1, k = i - K1 * n;
  float v = (k < GIND) ? W[(size_t)n * GIND + k] : 0.f;
  Wbf[i] = (short)f2bf_rn(v);
}

// A = [coord | hidden] fp32 -> bf16 split [MPAD][K2] = [hi(576) | lo(576)]
__global__ void k_cvt_a(const float* __restrict__ coord,
                        const float* __restrict__ hidden,
                        short* __restrict__ Abf)
{
  int i = blockIdx.x * blockDim.x + threadIdx.x;
  if (i >= MPAD * K1) return;
  int n = i / K1, k = i - K1 * n;
  float v = 0.f;
  if (n < NN && k < GIND)
    v = (k < 2) ? coord[(size_t)n*2 + k] : hidden[(size_t)n*HIDD + k - 2];
  unsigned short h = f2bf_rn(v);
  unsigned short l = f2bf_rn(v - bf2f(h));
  Abf[(size_t)n * K2 + k]      = (short)h;
  Abf[(size_t)n * K2 + K1 + k] = (short)l;
}

// ---------------------------------------------------------------------------
// GAT GEMM via MFMA bf16, 2-pass hi/lo split on A (18 K-tiles of 64):
//  tiles 0-8: a_hi*b ; 9-17: a_lo*b   (b = single RN bf16)
// Output bf16. LDS XOR swizzle both-sides; bijective XCD swizzle (1512=8*189).
// ---------------------------------------------------------------------------
__global__ __launch_bounds__(256) void k_gat_mfma(
    const short* __restrict__ Abf, const short* __restrict__ Wbf,
    const float* __restrict__ bias, unsigned short* __restrict__ Cb)
{
  __shared__ short As[128 * 64];
  __shared__ short Bs[128 * 64];
  const int tid  = threadIdx.x;
  int lin = blockIdx.y * 24 + blockIdx.x;          // 24*63 = 1512 = 8*189
  int wg  = (lin & 7) * 189 + (lin >> 3);          // bijective XCD chunking
  const int bm = (wg / 24) * 128, bn = (wg % 24) * 128;
  const int w    = tid >> 6, lane = tid & 63;
  const int wr   = w >> 1, wc = w & 1;
  const int lrow = lane & 15;

  f32x4 acc[4][4];
  #pragma unroll
  for (int i = 0; i < 4; ++i)
    #pragma unroll
    for (int j = 0; j < 4; ++j) acc[i][j] = (f32x4){0.f, 0.f, 0.f, 0.f};

  for (int kt = 0; kt < 18; ++kt){
    int aoff = (kt < 9) ? kt * 64 : K1 + (kt - 9) * 64;
    int boff = ((kt < 9) ? kt : kt - 9) * 64;
    __syncthreads();                 // previous tile fully consumed
    #pragma unroll
    for (int i = 0; i < 4; ++i){
      int l  = i * 256 + tid;        // 16B-chunk index 0..1023
      int r  = l >> 3, j = l & 7;
      int js = j ^ (r & 7);          // source pre-swizzle (write side)
      const short* ga = Abf + (size_t)(bm + r) * K2 + aoff + js * 8;
      const short* gb = Wbf + (size_t)(bn + r) * K1 + boff + js * 8;
      short* la = As + ((i * 256 + w * 64) << 3);   // wave-uniform base
      short* lb = Bs + ((i * 256 + w * 64) << 3);
      __builtin_amdgcn_global_load_lds(
          (const __attribute__((address_space(1))) unsigned*)ga,
          (__attribute__((address_space(3))) unsigned*)la, 16, 0, 0);
      __builtin_amdgcn_global_load_lds(
          (const __attribute__((address_space(1))) unsigned*)gb,
          (__attribute__((address_space(3))) unsigned*)lb, 16, 0, 0);
    }
    __syncthreads();                 // drains vmcnt, tile ready
    #pragma unroll
    for (int ks = 0; ks < 2; ++ks){
      // read-side swizzle: chunk c = ks*4 + (lane>>4), row&7 == lrow&7
      const int co = ((ks * 4 + (lane >> 4)) ^ (lrow & 7)) * 8;
      bf16x8 fa[4], fb[4];
      #pragma unroll
      for (int mi = 0; mi < 4; ++mi)
        fa[mi] = *(const bf16x8*)&As[(wr*64 + mi*16 + lrow) * 64 + co];
      #pragma unroll
      for (int ni = 0; ni < 4; ++ni)
        fb[ni] = *(const bf16x8*)&Bs[(wc*64 + ni*16 + lrow) * 64 + co];
      #pragma unroll
      for (int mi = 0; mi < 4; ++mi)
        #pragma unroll
        for (int ni = 0; ni < 4; ++ni)
          acc[mi][ni] = __builtin_amdgcn_mfma_f32_16x16x32_bf16(
              fa[mi], fb[ni], acc[mi][ni], 0, 0, 0);
    }
  }
  // epilogue: bf16 output. col = lane&15, row = (lane>>4)*4 + j
  #pragma unroll
  for (int mi = 0; mi < 4; ++mi){
    #pragma unroll
    for (int ni = 0; ni < 4; ++ni){
      int gn = bn + wc*64 + ni*16 + lrow;
      float bv = bias[gn];
      #pragma unroll
      for (int j = 0; j < 4; ++j){
        int gm = bm + wr*64 + mi*16 + (lane >> 4) * 4 + j;
        if (gm < NN)
          Cb[(size_t)gm * GOUT + gn] = f2bf_rn(acc[mi][ni][j] + bv);
      }
    }
  }
}

// ---------------------------------------------------------------------------
__global__ void k_embed(const float* __restrict__ mesh,
                        const float* __restrict__ w, const float* __restrict__ b,
                        float* __restrict__ h)
{
  int i = blockIdx.x * blockDim.x + threadIdx.x;
  if (i >= NN * DTR) return;
  int n = i >> 6, d = i & 63;
  const float* mr = mesh + n * 4;
  const float* wr = w + d * 4;
  h[i] = fmaf(mr[0], wr[0], fmaf(mr[1], wr[1], fmaf(mr[2], wr[2], mr[3]*wr[3]))) + b[d];
}

// ---------------------------------------------------------------------------
// split-K flash attention, stage 1. 2-way interleaved online-softmax chains
// (even/odd keys) to halve the serial fmax->exp->rescale dependency depth;
// exact merge at the end (pure reassociation, no extra error).
// ---------------------------------------------------------------------------
__global__ __launch_bounds__(128) void k_attn_part(const float* __restrict__ qkv,
    float* __restrict__ Pm, float* __restrict__ Pl, float* __restrict__ Pacc)
{
  __shared__ float Ks[128][DHD];
  __shared__ float Vs[128][DHD];
  const int q  = blockIdx.x * 128 + threadIdx.x;
  const int bh = blockIdx.y;
  const int b  = bh >> 2, h = bh & 3;
  const int ks = blockIdx.z;
  const bool valid = q < SEQ;
  float qv[DHD];
  if (valid){
    const float4* qr = (const float4*)(qkv + ((size_t)(b*SEQ + q))*192 + h*DHD);
    #pragma unroll
    for (int j = 0; j < 4; ++j){
      float4 t = qr[j];
      qv[j*4+0] = t.x; qv[j*4+1] = t.y; qv[j*4+2] = t.z; qv[j*4+3] = t.w;
    }
  }
  float m0 = -1e30f, l0 = 0.f, a0[DHD] = {};
  float m1 = -1e30f, l1 = 0.f, a1[DHD] = {};
  const int kbeg = ks * KCH, kend = kbeg + KCH;
  for (int kt = kbeg; kt < kend; kt += 128){
    int cnt = min(128, kend - kt);
    __syncthreads();
    for (int el = threadIdx.x; el < cnt * 4; el += 128){
      int r = el >> 2, d4 = el & 3;
      const float4* base = (const float4*)(qkv + ((size_t)(b*SEQ + kt + r))*192 + h*DHD);
      ((float4*)Ks[r])[d4] = base[16 + d4];      // +64 floats  = K block
      ((float4*)Vs[r])[d4] = base[32 + d4];      // +128 floats = V block
    }
    __syncthreads();
    if (valid){
      int r = 0;
      for (; r + 1 < cnt; r += 2){
        float s0 = 0.f, s1 = 0.f;
        #pragma unroll
        for (int d = 0; d < DHD; ++d){
          s0 = fmaf(qv[d], Ks[r][d],     s0);
          s1 = fmaf(qv[d], Ks[r+1][d],   s1);
        }
        s0 *= 0.25f; s1 *= 0.25f;
        float mn0 = fmaxf(m0, s0), mn1 = fmaxf(m1, s1);
        float c0 = __expf(m0 - mn0), p0 = __expf(s0 - mn0);
        float c1 = __expf(m1 - mn1), p1 = __expf(s1 - mn1);
        l0 = l0 * c0 + p0;  l1 = l1 * c1 + p1;
        #pragma unroll
        for (int d = 0; d < DHD; ++d){
          a0[d] = fmaf(a0[d], c0, p0 * Vs[r][d]);
          a1[d] = fmaf(a1[d], c1, p1 * Vs[r+1][d]);
        }
        m0 = mn0; m1 = mn1;
      }
      if (r < cnt){                               // odd tail (chain 0)
        float s0 = 0.f;
        #pragma unroll
        for (int d = 0; d < DHD; ++d) s0 = fmaf(qv[d], Ks[r][d], s0);
        s0 *= 0.25f;
        float mn0 = fmaxf(m0, s0);
        float c0 = __expf(m0 - mn0), p0 = __expf(s0 - mn0);
        l0 = l0 * c0 + p0;
        #pragma unroll
        for (int d = 0; d < DHD; ++d) a0[d] = fmaf(a0[d], c0, p0 * Vs[r][d]);
        m0 = mn0;
      }
    }
  }
  if (valid){
    float mn = fmaxf(m0, m1);
    float c0 = __expf(m0 - mn), c1 = __expf(m1 - mn);
    size_t qi = ((size_t)bh * SEQ + q) * KSPLIT + ks;
    Pm[qi] = mn;
    Pl[qi] = l0 * c0 + l1 * c1;
    #pragma unroll
    for (int d = 0; d < DHD; ++d)
      Pacc[qi*DHD + d] = a0[d] * c0 + a1[d] * c1;
  }
}

// stage 2: merge KSPLIT partials per query -> o[N][64]
__global__ void k_attn_comb(const float* __restrict__ Pm, const float* __restrict__ Pl,
                            const float* __restrict__ Pacc, float* __restrict__ o)
{
  int qi = blockIdx.x * blockDim.x + threadIdx.x;
  if (qi >= BATCH * NHTR * SEQ) return;
  float m = -1e30f;
  #pragma unroll
  for (int ks = 0; ks < KSPLIT; ++ks) m = fmaxf(m, Pm[(size_t)qi*KSPLIT + ks]);
  float l = 0.f, acc[DHD] = {};
  #pragma unroll
  for (int ks = 0; ks < KSPLIT; ++ks){
    size_t p = (size_t)qi*KSPLIT + ks;
    float sc = __expf(Pm[p] - m);
    l += Pl[p] * sc;
    #pragma unroll
    for (int d = 0; d < DHD; ++d) acc[d] = fmaf(Pacc[p*DHD + d], sc, acc[d]);
  }
  int bh = qi / SEQ, q = qi - bh * SEQ;
  int b = bh >> 2, h = bh & 3;
  float inv = 1.f / l;
  #pragma unroll
  for (int d = 0; d < DHD; ++d)
    o[((size_t)(b*SEQ + q))*64 + h*DHD + d] = acc[d] * inv;
}

// ---------------------------------------------------------------------------
__global__ __launch_bounds__(256) void k_addln(const float* __restrict__ x,
    const float* __restrict__ y, const float* __restrict__ g,
    const float* __restrict__ b, float* __restrict__ out)
{
  int row = blockIdx.x * 4 + (threadIdx.x >> 6);
  int lane = threadIdx.x & 63;
  if (row >= NN) return;
  float v = x[(size_t)row*64 + lane] + y[(size_t)row*64 + lane];
  float s1 = v, s2 = v * v;
  #pragma unroll
  for (int o = 32; o; o >>= 1){ s1 += __shfl_xor(s1, o); s2 += __shfl_xor(s2, o); }
  float mean = s1 * (1.f/64.f);
  float var  = s2 * (1.f/64.f) - mean * mean;
  float r = rsqrtf(var + 1e-5f);
  out[(size_t)row*64 + lane] = (v - mean) * r * g[lane] + b[lane];
}

__global__ void k_concat_feats(const float* __restrict__ x,
                               const float* __restrict__ tout,
                               float* __restrict__ feats)
{
  int i = blockIdx.x * blockDim.x + threadIdx.x;
  if (i >= NN * 21) return;
  int n = i / 21, c = i - 21*n;
  feats[i] = (c < 5) ? x[(size_t)n*7 + 2 + c] : tout[(size_t)n*16 + c - 5];
}

__global__ void k_initcoord(const float* __restrict__ x, float* __restrict__ coord)
{
  int i = blockIdx.x * blockDim.x + threadIdx.x;
  if (i >= NN * 2) return;
  coord[i] = x[(size_t)(i >> 1)*7 + (i & 1)];
}

// ---------------------------------------------------------------------------
// CSR build (by dst). dst for e>=NEDGE is the self-loop e-NEDGE.
// ---------------------------------------------------------------------------
__global__ void k_count(const int* __restrict__ dst, int* __restrict__ cnt)
{
  int e = blockIdx.x * blockDim.x + threadIdx.x;
  if (e >= ELOOP) return;
  int d = (e < NEDGE) ? dst[e] : e - NEDGE;
  atomicAdd(&cnt[d], 1);
}

__global__ __launch_bounds__(1024) void k_scan(const int* __restrict__ cnt,
                                               int* __restrict__ ptr)
{
  __shared__ int part[1024];
  int tid = threadIdx.x;
  const int per = 8;
  int loc[per]; int s = 0;
  int base = tid * per;
  #pragma unroll
  for (int i = 0; i < per; ++i){
    int v = (base + i < NN) ? cnt[base + i] : 0;
    loc[i] = s; s += v;
  }
  part[tid] = s;
  __syncthreads();
  for (int off = 1; off < 1024; off <<= 1){
    int v = 0;
    if (tid >= off) v = part[tid - off];
    __syncthreads();
    if (tid >= off) part[tid] += v;
    __syncthreads();
  }
  int pre = tid ? part[tid - 1] : 0;
  #pragma unroll
  for (int i = 0; i < per; ++i)
    if (base + i < NN) ptr[base + i] = pre + loc[i];
  if (tid == 1023) ptr[NN] = part[1023];
}

__global__ void k_fill(const int* __restrict__ dst, const int* __restrict__ ptr,
                       int* __restrict__ fil, int* __restrict__ eid)
{
  int e = blockIdx.x * blockDim.x + threadIdx.x;
  if (e >= ELOOP) return;
  int d = (e < NEDGE) ? dst[e] : e - NEDGE;
  int pos = ptr[d] + atomicAdd(&fil[d], 1);
  eid[pos] = e;
}

// ---------------------------------------------------------------------------
// logits2[pos*6+h] over CSR (dst-sorted) positions. One WAVE per edge,
// looping over the 6 heads (eid/src/dst loaded once). bf16 xl/xr, uint4.
// XCD-chunked block swizzle (10000 blocks = 8 * 1250).
// ---------------------------------------------------------------------------
__global__ __launch_bounds__(256) void k_logits(const unsigned short* __restrict__ xlb,
    const unsigned short* __restrict__ xrb, const int* __restrict__ src_a,
    const int* __restrict__ dst_a, const int* __restrict__ eid,
    const float* __restrict__ att, float* __restrict__ logits2)
{
  int bid = blockIdx.x;                         // 10000 = 8 * 1250
  int wgs = (bid & 7) * 1250 + (bid >> 3);      // bijective XCD chunking
  int pos = wgs * 4 + (threadIdx.x >> 6);
  if (pos >= ELOOP) return;
  int lane = threadIdx.x & 63;
  int e = eid[pos];
  int s = (e < NEDGE) ? src_a[e] : e - NEDGE;
  int d = (e < NEDGE) ? dst_a[e] : e - NEDGE;
  const uint4* pl = (const uint4*)(xlb + (size_t)s * GOUT);
  const uint4* pr = (const uint4*)(xrb + (size_t)d * GOUT);
  const float4* pa = (const float4*)att;
  #pragma unroll 2
  for (int h = 0; h < NHEADS; ++h){
    uint4 ua = pl[h*64 + lane];
    uint4 ub = pr[h*64 + lane];
    float4 w0 = pa[h*128 + lane*2], w1 = pa[h*128 + lane*2 + 1];
    float acc = 0.f;
    auto pair = [&](unsigned a, unsigned b, float wl, float wh){
      float vl = __uint_as_float(a << 16)        + __uint_as_float(b << 16);
      float vh = __uint_as_float(a & 0xffff0000u)+ __uint_as_float(b & 0xffff0000u);
      vl = vl > 0.f ? vl : 0.2f * vl;
      vh = vh > 0.f ? vh : 0.2f * vh;
      acc = fmaf(vl, wl, acc);
      acc = fmaf(vh, wh, acc);
    };
    pair(ua.x, ub.x, w0.x, w0.y);
    pair(ua.y, ub.y, w0.z, w0.w);
    pair(ua.z, ub.z, w1.x, w1.y);
    pair(ua.w, ub.w, w1.z, w1.w);
    #pragma unroll
    for (int o2 = 32; o2; o2 >>= 1) acc += __shfl_xor(acc, o2);
    if (lane == 0) logits2[pos*NHEADS + h] = acc;
  }
}

// mx / inv(sum) per (node, head); logits2 is pos-ordered -> sequential reads
__global__ void k_stats(const float* __restrict__ logits2, const int* __restrict__ ptr,
                        float* __restrict__ mx, float* __restrict__ inv)
{
  int i = blockIdx.x * blockDim.x + threadIdx.x;
  if (i >= NN * NHEADS) return;
  int n = i / NHEADS, h = i - NHEADS * n;
  int s0 = ptr[n], s1 = ptr[n + 1];
  float m = -1e30f;
  for (int t = s0; t < s1; ++t) m = fmaxf(m, logits2[t*NHEADS + h]);
  float s = 0.f;
  for (int t = s0; t < s1; ++t) s += __expf(logits2[t*NHEADS + h] - m);
  mx[i] = m; inv[i] = 1.f / s;
}

// ---------------------------------------------------------------------------
// hidden[n,c] = selu(mean_h sum_{e in(n)} a[e,h]*xl[src,h,c] + gbias[c])
// bf16 xl; thread t owns channel pairs (512k + 2t, 512k + 2t+1), head = k.
// ---------------------------------------------------------------------------
__global__ __launch_bounds__(256) void k_agg(const unsigned short* __restrict__ xlb,
    const float* __restrict__ logits2, const float* __restrict__ mx,
    const float* __restrict__ inv, const int* __restrict__ ptr,
    const int* __restrict__ eid, const int* __restrict__ src_a,
    const float* __restrict__ gbias, float* __restrict__ hidden)
{
  const int n = blockIdx.x;
  const int tid = threadIdx.x;
  __shared__ float a_sh[64 * NHEADS];
  __shared__ int src_sh[64];
  const int s0 = ptr[n];
  const int deg = ptr[n + 1] - s0;
  float acc[12] = {};
  for (int base = 0; base < deg; base += 64){
    int cnt = min(64, deg - base);
    __syncthreads();
    for (int t = tid; t < cnt * NHEADS; t += 256){
      int ei = t / NHEADS, h = t - NHEADS * ei;
      a_sh[t] = __expf(logits2[(s0 + base + ei)*NHEADS + h] - mx[n*NHEADS + h])
                * inv[n*NHEADS + h];
      if (h == 0){
        int e = eid[s0 + base + ei];
        src_sh[ei] = (e < NEDGE) ? src_a[e] : e - NEDGE;
      }
    }
    __syncthreads();
    for (int i2 = 0; i2 < cnt; ++i2){
      const unsigned* row = (const unsigned*)(xlb + (size_t)src_sh[i2] * GOUT);
      #pragma unroll
      for (int k = 0; k < NHEADS; ++k){
        unsigned u = row[tid + (k << 8)];
        float wgt = a_sh[i2*NHEADS + k];
        acc[2*k]   = fmaf(__uint_as_float(u << 16),         wgt, acc[2*k]);
        acc[2*k+1] = fmaf(__uint_as_float(u & 0xffff0000u), wgt, acc[2*k+1]);
      }
    }
  }
  float m0 = (acc[0]+acc[2]+acc[4]+acc[6]+acc[8]+acc[10]) * (1.f/6.f);
  float m1 = (acc[1]+acc[3]+acc[5]+acc[7]+acc[9]+acc[11]) * (1.f/6.f);
  float2 out;
  out.x = selu_f(m0 + gbias[2*tid]);
  out.y = selu_f(m1 + gbias[2*tid + 1]);
  *(float2*)&hidden[(size_t)n*HIDD + 2*tid] = out;
}

// ---------------------------------------------------------------------------
extern "C" void kernel_launch(void* const* d_in, const int* in_sizes, int n_in,
                              void* d_out, int out_size, void* d_ws, size_t ws_size,
                              hipStream_t stream)
{
  const float* mesh     = (const float*)d_in[1];
  const float* xin      = (const float*)d_in[2];
  const int*   ei       = (const int*)d_in[3];
  const float* embed_w  = (const float*)d_in[4];
  const float* embed_b  = (const float*)d_in[5];
  const float* in_proj_w= (const float*)d_in[6];
  const float* in_proj_b= (const float*)d_in[7];
  const float* out_proj_w=(const float*)d_in[8];
  const float* out_proj_b=(const float*)d_in[9];
  const float* ln1_g    = (const float*)d_in[10];
  const float* ln1_b    = (const float*)d_in[11];
  const float* ln2_g    = (const float*)d_in[12];
  const float* ln2_b    = (const float*)d_in[13];
  const float* ff1_w    = (const float*)d_in[14];
  const float* ff1_b    = (const float*)d_in[15];
  const float* ff2_w    = (const float*)d_in[16];
  const float* ff2_b    = (const float*)d_in[17];
  const float* tout_w   = (const float*)d_in[18];
  const float* tout_b   = (const float*)d_in[19];
  const float* lin_w    = (const float*)d_in[20];
  const float* lin_b    = (const float*)d_in[21];
  const float* gat_wl   = (const float*)d_in[22];
  const float* gat_bl   = (const float*)d_in[23];
  const float* gat_wr   = (const float*)d_in[24];
  const float* gat_br   = (const float*)d_in[25];
  const float* gat_att  = (const float*)d_in[26];
  const float* gat_bias = (const float*)d_in[27];
  const float* coord1_w = (const float*)d_in[28];
  const float* coord1_b = (const float*)d_in[29];
  const float* coord2_w = (const float*)d_in[30];
  const float* coord2_b = (const float*)d_in[31];

  const int* esrc = ei;
  const int* edst = ei + NEDGE;

  char* ws = (char*)d_ws;
  size_t off = 0;
  auto alloc = [&](size_t nbytes){
    size_t o = off; off += (nbytes + 255) & ~(size_t)255; return o;
  };
  float* hidden = (float*)(ws + alloc((size_t)NN * HIDD * 4));
  float* coord  = (float*)(ws + alloc((size_t)NN * 2 * 4));
  unsigned short* xlb = (unsigned short*)(ws + alloc((size_t)NN * GOUT * 2));
  unsigned short* xrb = (unsigned short*)(ws + alloc((size_t)NN * GOUT * 2));
  float* logits = (float*)(ws + alloc((size_t)ELOOP * NHEADS * 4));
  float* mxb    = (float*)(ws + alloc((size_t)NN * NHEADS * 4));
  float* invb   = (float*)(ws + alloc((size_t)NN * NHEADS * 4));
  float* c1     = (float*)(ws + alloc((size_t)NN * 256 * 4));
  int*   ptr    = (int*)(ws + alloc((size_t)(NN + 1) * 4));
  int*   eid    = (int*)(ws + alloc((size_t)ELOOP * 4));
  int*   cnt    = (int*)(ws + alloc((size_t)NN * 4));
  int*   fil    = (int*)(ws + alloc((size_t)NN * 4));
  short* abf    = (short*)(ws + alloc((size_t)MPAD * K2 * 2));
  short* wlbf   = (short*)(ws + alloc((size_t)GOUT * K1 * 2));
  short* wrbf   = (short*)(ws + alloc((size_t)GOUT * K1 * 2));
  float* part_c1= (float*)(ws + alloc((size_t)4 * NN * 256 * 4));  // 31.25 MiB

  // Transformer-phase temporaries ALIASED inside xlb+xrb (93.75 MiB, all
  // dead before the first k_gat_mfma writes xlb). MiB offsets within region:
  char* arena = (char*)xlb;
  float* h       = (float*)(arena + ((size_t)0  << 20));  // 0-2   (live to ln2)
  float* o       = (float*)(arena + ((size_t)2  << 20));  // 2-4
  float* tmp     = (float*)(arena + ((size_t)4  << 20));  // 4-6
  float* feats   = (float*)(arena + ((size_t)6  << 20));  // 6-6.7
  float* toutb   = (float*)(arena + ((size_t)7  << 20));  // 7-7.6
  float* qkv     = (float*)(arena + ((size_t)8  << 20));  // 8-14.2  (dead after attn)
  float* Pm      = (float*)(arena + ((size_t)16 << 20));  // 16-17   (dead after comb)
  float* Pl      = (float*)(arena + ((size_t)17 << 20));  // 17-18
  float* Pacc    = (float*)(arena + ((size_t)18 << 20));  // 18-33.7 (dead after comb)
  float* part_f2 = (float*)(arena + ((size_t)8  << 20));  // 8-23.7  (after attn dead)
  float* ffmid   = (float*)(arena + ((size_t)28 << 20));  // 28-90.5 (< 93.75 OK)

  // ---- transformer ----
  k_embed<<<CDIV(NN*DTR, 256), 256, 0, stream>>>(mesh, embed_w, embed_b, h);
  k_gemm<0><<<dim3(CDIV(192,64), CDIV(NN,64)), 256, 0, stream>>>(h, in_proj_w, in_proj_b, qkv, NN, 192, DTR);
  k_attn_part<<<dim3(CDIV(SEQ,128), BATCH*NHTR, KSPLIT), 128, 0, stream>>>(qkv, Pm, Pl, Pacc);
  k_attn_comb<<<CDIV(BATCH*NHTR*SEQ, 256), 256, 0, stream>>>(Pm, Pl, Pacc, o);
  k_gemm<0><<<dim3(1, CDIV(NN,64)), 256, 0, stream>>>(o, out_proj_w, out_proj_b, tmp, NN, DTR, DTR);
  k_addln<<<CDIV(NN,4), 256, 0, stream>>>(h, tmp, ln1_g, ln1_b, h);
  k_gemm<1><<<dim3(CDIV(FFD,64), CDIV(NN,64)), 256, 0, stream>>>(h, ff1_w, ff1_b, ffmid, NN, FFD, DTR);
  k_gemm_sk<<<dim3(1, CDIV(NN,64), 8), 256, 0, stream>>>(ffmid, ff2_w, part_f2, NN, DTR, FFD, 256);
  k_comb<0><<<CDIV(NN*DTR, 256), 256, 0, stream>>>(part_f2, ff2_b, tmp, NN, DTR, 8);
  k_addln<<<CDIV(NN,4), 256, 0, stream>>>(h, tmp, ln2_g, ln2_b, h);
  k_gemm<0><<<dim3(1, CDIV(NN,64)), 256, 0, stream>>>(h, tout_w, tout_b, toutb, NN, TOUTD, DTR);
  k_concat_feats<<<CDIV(NN*21, 256), 256, 0, stream>>>(xin, toutb, feats);
  k_gemm<2><<<dim3(CDIV(HIDD,64), CDIV(NN,64)), 256, 0, stream>>>(feats, lin_w, lin_b, hidden, NN, HIDD, 21);
  k_initcoord<<<CDIV(NN*2, 256), 256, 0, stream>>>(xin, coord);

  // ---- CSR by dst + weight conversion (once) ----
  hipMemsetAsync(cnt, 0, (size_t)NN * 4, stream);
  hipMemsetAsync(fil, 0, (size_t)NN * 4, stream);
  k_count<<<CDIV(ELOOP, 256), 256, 0, stream>>>(edst, cnt);
  k_scan<<<1, 1024, 0, stream>>>(cnt, ptr);
  k_fill<<<CDIV(ELOOP, 256), 256, 0, stream>>>(edst, ptr, fil, eid);
  k_cvt_w<<<CDIV(GOUT*K1, 256), 256, 0, stream>>>(gat_wl, wlbf);
  k_cvt_w<<<CDIV(GOUT*K1, 256), 256, 0, stream>>>(gat_wr, wrbf);

  // ---- GAT loops ----
  for (int it = 0; it < 3; ++it){
    k_cvt_a<<<CDIV(MPAD*K1, 256), 256, 0, stream>>>(coord, hidden, abf);
    k_gat_mfma<<<dim3(GOUT/128, MPAD/128), 256, 0, stream>>>(abf, wlbf, gat_bl, xlb);
    k_gat_mfma<<<dim3(GOUT/128, MPAD/128), 256, 0, stream>>>(abf, wrbf, gat_br, xrb);
    k_logits<<<ELOOP/4, 256, 0, stream>>>(xlb, xrb, esrc, edst, eid, gat_att, logits);
    k_stats<<<CDIV(NN*NHEADS, 256), 256, 0, stream>>>(logits, ptr, mxb, invb);
    k_agg<<<NN, 256, 0, stream>>>(xlb, logits, mxb, invb, ptr, eid, esrc, gat_bias, hidden);
    k_gemm_sk<<<dim3(CDIV(256,64), CDIV(NN,64), 4), 256, 0, stream>>>(hidden, coord1_w, part_c1, NN, 256, HIDD, 128);
    k_comb<2><<<CDIV(NN*256, 256), 256, 0, stream>>>(part_c1, coord1_b, c1, NN, 256, 4);
    float* cdst = (it == 2) ? (float*)d_out : coord;
    k_gemm<0><<<dim3(1, CDIV(NN,64)), 256, 0, stream>>>(c1, coord2_w, coord2_b, cdst, NN, 2, 256);
  }
}

// Round 11
// 1267.405 us; speedup vs baseline: 1.7549x; 1.0689x over previous
//
#include <hip/hip_runtime.h>
#include <hip/hip_bf16.h>
#include <math.h>

#define NN     8000
#define MPAD   8064    /* NN padded to 128 */
#define BATCH  4
#define SEQ    2000
#define DTR    64
#define NHTR   4
#define DHD    16
#define FFD    2048
#define TOUTD  16
#define HIDD   512
#define NHEADS 6
#define HCD    512
#define GIND   514
#define GOUT   3072
#define NEDGE  32000
#define ELOOP  40000   /* NEDGE + NN */

#define K1     576     /* GIND padded to 64-multiple */
#define K2     1152    /* hi + lo halves (A only) */

#define KSPLIT 16
#define KCH    125     /* SEQ / KSPLIT */

#define CDIV(a,b) (((a)+(b)-1)/(b))

using bf16x8 = __attribute__((__ext_vector_type__(8))) __bf16;
using f32x4  = __attribute__((__ext_vector_type__(4))) float;

__device__ __forceinline__ float selu_f(float x){
  const float a = 1.6732632423543772848f;
  const float s = 1.0507009873554805f;
  return x > 0.f ? s * x : s * a * (__expf(x) - 1.f);
}

__device__ __forceinline__ unsigned short f2bf_rn(float x){
  unsigned u = __float_as_uint(x);
  unsigned r = (u + 0x7fffu + ((u >> 16) & 1u)) >> 16;
  return (unsigned short)r;
}
__device__ __forceinline__ float bf2f(unsigned short h){
  return __uint_as_float((unsigned)h << 16);
}

// ---------------------------------------------------------------------------
// Generic C[M,N] = act(A[M,K] @ W[N,K]^T + bias). fp32, 64x64 tile, BK=16.
// ---------------------------------------------------------------------------
template<int ACT>  // 0=none 1=relu 2=selu
__global__ __launch_bounds__(256) void k_gemm(const float* __restrict__ A,
    const float* __restrict__ W, const float* __restrict__ bias,
    float* __restrict__ C, int M, int N, int K)
{
  __shared__ float As[16][68];
  __shared__ float Ws[16][68];
  const int tid = threadIdx.x;
  const int bm = blockIdx.y * 64, bn = blockIdx.x * 64;
  const int tx = tid & 15, ty = tid >> 4;
  float acc[4][4] = {};
  for (int k0 = 0; k0 < K; k0 += 16){
    #pragma unroll
    for (int i = 0; i < 4; ++i){
      int el = tid + (i << 8);
      int kk = el & 15, r = el >> 4;
      int gk = k0 + kk;
      int gm = bm + r;
      As[kk][r] = (gm < M && gk < K) ? A[(size_t)gm * K + gk] : 0.f;
      int gn = bn + r;
      Ws[kk][r] = (gn < N && gk < K) ? W[(size_t)gn * K + gk] : 0.f;
    }
    __syncthreads();
    #pragma unroll
    for (int kk = 0; kk < 16; ++kk){
      float av[4], wv[4];
      #pragma unroll
      for (int i = 0; i < 4; ++i) av[i] = As[kk][ty*4+i];
      #pragma unroll
      for (int j = 0; j < 4; ++j) wv[j] = Ws[kk][tx*4+j];
      #pragma unroll
      for (int i = 0; i < 4; ++i)
        #pragma unroll
        for (int j = 0; j < 4; ++j) acc[i][j] = fmaf(av[i], wv[j], acc[i][j]);
    }
    __syncthreads();
  }
  #pragma unroll
  for (int i = 0; i < 4; ++i){
    int gm = bm + ty*4 + i;
    if (gm >= M) continue;
    #pragma unroll
    for (int j = 0; j < 4; ++j){
      int gn = bn + tx*4 + j;
      if (gn >= N) continue;
      float v = acc[i][j] + bias[gn];
      if (ACT == 1) v = fmaxf(v, 0.f);
      if (ACT == 2) v = selu_f(v);
      C[(size_t)gm * N + gn] = v;
    }
  }
}

// ---------------------------------------------------------------------------
// Split-K GEMM: partial[z][M][N] = A[:, z*kchunk:(z+1)*kchunk] @ W^T slice.
// ---------------------------------------------------------------------------
__global__ __launch_bounds__(256) void k_gemm_sk(const float* __restrict__ A,
    const float* __restrict__ W, float* __restrict__ part,
    int M, int N, int K, int kchunk)
{
  __shared__ float As[16][68];
  __shared__ float Ws[16][68];
  const int tid = threadIdx.x;
  const int bm = blockIdx.y * 64, bn = blockIdx.x * 64;
  const int kbeg = blockIdx.z * kchunk;
  const int tx = tid & 15, ty = tid >> 4;
  float acc[4][4] = {};
  for (int k0 = kbeg; k0 < kbeg + kchunk; k0 += 16){
    #pragma unroll
    for (int i = 0; i < 4; ++i){
      int el = tid + (i << 8);
      int kk = el & 15, r = el >> 4;
      int gk = k0 + kk;
      int gm = bm + r;
      As[kk][r] = (gm < M && gk < K) ? A[(size_t)gm * K + gk] : 0.f;
      int gn = bn + r;
      Ws[kk][r] = (gn < N && gk < K) ? W[(size_t)gn * K + gk] : 0.f;
    }
    __syncthreads();
    #pragma unroll
    for (int kk = 0; kk < 16; ++kk){
      float av[4], wv[4];
      #pragma unroll
      for (int i = 0; i < 4; ++i) av[i] = As[kk][ty*4+i];
      #pragma unroll
      for (int j = 0; j < 4; ++j) wv[j] = Ws[kk][tx*4+j];
      #pragma unroll
      for (int i = 0; i < 4; ++i)
        #pragma unroll
        for (int j = 0; j < 4; ++j) acc[i][j] = fmaf(av[i], wv[j], acc[i][j]);
    }
    __syncthreads();
  }
  float* pz = part + (size_t)blockIdx.z * M * N;
  #pragma unroll
  for (int i = 0; i < 4; ++i){
    int gm = bm + ty*4 + i;
    if (gm >= M) continue;
    #pragma unroll
    for (int j = 0; j < 4; ++j){
      int gn = bn + tx*4 + j;
      if (gn >= N) continue;
      pz[(size_t)gm * N + gn] = acc[i][j];
    }
  }
}

// combine KS partials + bias + activation
template<int ACT>
__global__ void k_comb(const float* __restrict__ part, const float* __restrict__ bias,
                       float* __restrict__ C, int M, int N, int KS)
{
  int i = blockIdx.x * blockDim.x + threadIdx.x;
  if (i >= M * N) return;
  int n = i - N * (i / N);
  float v = bias[n];
  for (int z = 0; z < KS; ++z) v += part[(size_t)z * M * N + i];
  if (ACT == 1) v = fmaxf(v, 0.f);
  if (ACT == 2) v = selu_f(v);
  C[i] = v;
}

// ---------------------------------------------------------------------------
// fused coord tail: c1 = selu(sum_z part + bias) per row, then
// coord[n][j] = c1 . coord2_w[j] + coord2_b[j]. block per row, 256 threads.
// ---------------------------------------------------------------------------
__global__ __launch_bounds__(256) void k_coord(const float* __restrict__ part,
    const float* __restrict__ c1b, const float* __restrict__ w2,
    const float* __restrict__ b2, float* __restrict__ out)
{
  int n = blockIdx.x, t = threadIdx.x;
  float v = c1b[t];
  #pragma unroll
  for (int z = 0; z < 4; ++z) v += part[(size_t)z*NN*256 + (size_t)n*256 + t];
  v = selu_f(v);
  float d0 = v * w2[t], d1 = v * w2[256 + t];
  #pragma unroll
  for (int o = 32; o; o >>= 1){ d0 += __shfl_xor(d0, o); d1 += __shfl_xor(d1, o); }
  __shared__ float red[8];
  int wv = t >> 6;
  if ((t & 63) == 0){ red[wv] = d0; red[4 + wv] = d1; }
  __syncthreads();
  if (t == 0) out[(size_t)n*2]     = red[0]+red[1]+red[2]+red[3] + b2[0];
  if (t == 1) out[(size_t)n*2 + 1] = red[4]+red[5]+red[6]+red[7] + b2[1];
}

// ---------------------------------------------------------------------------
// weight fp32 [3072][514] -> single bf16 (RN) [3072][K1]
// ---------------------------------------------------------------------------
__global__ void k_cvt_w(const float* __restrict__ W, short* __restrict__ Wbf)
{
  int i = blockIdx.x * blockDim.x + threadIdx.x;
  if (i >= GOUT * K1) return;
  int n = i / K1, k = i - K1 * n;
  float v = (k < GIND) ? W[(size_t)n * GIND + k] : 0.f;
  Wbf[i] = (short)f2bf_rn(v);
}

// A = [coord | hidden] fp32 -> bf16 split [MPAD][K2] = [hi(576) | lo(576)]
__global__ void k_cvt_a(const float* __restrict__ coord,
                        const float* __restrict__ hidden,
                        short* __restrict__ Abf)
{
  int i = blockIdx.x * blockDim.x + threadIdx.x;
  if (i >= MPAD * K1) return;
  int n = i / K1, k = i - K1 * n;
  float v = 0.f;
  if (n < NN && k < GIND)
    v = (k < 2) ? coord[(size_t)n*2 + k] : hidden[(size_t)n*HIDD + k - 2];
  unsigned short h = f2bf_rn(v);
  unsigned short l = f2bf_rn(v - bf2f(h));
  Abf[(size_t)n * K2 + k]      = (short)h;
  Abf[(size_t)n * K2 + K1 + k] = (short)l;
}

// ---------------------------------------------------------------------------
// GAT GEMM via MFMA bf16, 2-pass hi/lo split on A (18 K-tiles of 64):
//  tiles 0-8: a_hi*b ; 9-17: a_lo*b   (b = single RN bf16)
// Output bf16. LDS XOR swizzle both-sides; bijective XCD swizzle (1512=8*189).
// ---------------------------------------------------------------------------
__global__ __launch_bounds__(256) void k_gat_mfma(
    const short* __restrict__ Abf, const short* __restrict__ Wbf,
    const float* __restrict__ bias, unsigned short* __restrict__ Cb)
{
  __shared__ short As[128 * 64];
  __shared__ short Bs[128 * 64];
  const int tid  = threadIdx.x;
  int lin = blockIdx.y * 24 + blockIdx.x;          // 24*63 = 1512 = 8*189
  int wg  = (lin & 7) * 189 + (lin >> 3);          // bijective XCD chunking
  const int bm = (wg / 24) * 128, bn = (wg % 24) * 128;
  const int w    = tid >> 6, lane = tid & 63;
  const int wr   = w >> 1, wc = w & 1;
  const int lrow = lane & 15;

  f32x4 acc[4][4];
  #pragma unroll
  for (int i = 0; i < 4; ++i)
    #pragma unroll
    for (int j = 0; j < 4; ++j) acc[i][j] = (f32x4){0.f, 0.f, 0.f, 0.f};

  for (int kt = 0; kt < 18; ++kt){
    int aoff = (kt < 9) ? kt * 64 : K1 + (kt - 9) * 64;
    int boff = ((kt < 9) ? kt : kt - 9) * 64;
    __syncthreads();                 // previous tile fully consumed
    #pragma unroll
    for (int i = 0; i < 4; ++i){
      int l  = i * 256 + tid;        // 16B-chunk index 0..1023
      int r  = l >> 3, j = l & 7;
      int js = j ^ (r & 7);          // source pre-swizzle (write side)
      const short* ga = Abf + (size_t)(bm + r) * K2 + aoff + js * 8;
      const short* gb = Wbf + (size_t)(bn + r) * K1 + boff + js * 8;
      short* la = As + ((i * 256 + w * 64) << 3);   // wave-uniform base
      short* lb = Bs + ((i * 256 + w * 64) << 3);
      __builtin_amdgcn_global_load_lds(
          (const __attribute__((address_space(1))) unsigned*)ga,
          (__attribute__((address_space(3))) unsigned*)la, 16, 0, 0);
      __builtin_amdgcn_global_load_lds(
          (const __attribute__((address_space(1))) unsigned*)gb,
          (__attribute__((address_space(3))) unsigned*)lb, 16, 0, 0);
    }
    __syncthreads();                 // drains vmcnt, tile ready
    #pragma unroll
    for (int ks = 0; ks < 2; ++ks){
      // read-side swizzle: chunk c = ks*4 + (lane>>4), row&7 == lrow&7
      const int co = ((ks * 4 + (lane >> 4)) ^ (lrow & 7)) * 8;
      bf16x8 fa[4], fb[4];
      #pragma unroll
      for (int mi = 0; mi < 4; ++mi)
        fa[mi] = *(const bf16x8*)&As[(wr*64 + mi*16 + lrow) * 64 + co];
      #pragma unroll
      for (int ni = 0; ni < 4; ++ni)
        fb[ni] = *(const bf16x8*)&Bs[(wc*64 + ni*16 + lrow) * 64 + co];
      #pragma unroll
      for (int mi = 0; mi < 4; ++mi)
        #pragma unroll
        for (int ni = 0; ni < 4; ++ni)
          acc[mi][ni] = __builtin_amdgcn_mfma_f32_16x16x32_bf16(
              fa[mi], fb[ni], acc[mi][ni], 0, 0, 0);
    }
  }
  // epilogue: bf16 output. col = lane&15, row = (lane>>4)*4 + j
  #pragma unroll
  for (int mi = 0; mi < 4; ++mi){
    #pragma unroll
    for (int ni = 0; ni < 4; ++ni){
      int gn = bn + wc*64 + ni*16 + lrow;
      float bv = bias[gn];
      #pragma unroll
      for (int j = 0; j < 4; ++j){
        int gm = bm + wr*64 + mi*16 + (lane >> 4) * 4 + j;
        if (gm < NN)
          Cb[(size_t)gm * GOUT + gn] = f2bf_rn(acc[mi][ni][j] + bv);
      }
    }
  }
}

// ---------------------------------------------------------------------------
__global__ void k_embed(const float* __restrict__ mesh,
                        const float* __restrict__ w, const float* __restrict__ b,
                        float* __restrict__ h)
{
  int i = blockIdx.x * blockDim.x + threadIdx.x;
  if (i >= NN * DTR) return;
  int n = i >> 6, d = i & 63;
  const float* mr = mesh + n * 4;
  const float* wr = w + d * 4;
  h[i] = fmaf(mr[0], wr[0], fmaf(mr[1], wr[1], fmaf(mr[2], wr[2], mr[3]*wr[3]))) + b[d];
}

// ---------------------------------------------------------------------------
// split-K flash attention, stage 1. Defer-max (T13): work in log2 domain,
// rescale only when __any(s > m + 8) — p bounded by 2^8, exact normalization.
// KSPLIT=16 (KCH=125, single LDS tile per block) for occupancy.
// ---------------------------------------------------------------------------
__global__ __launch_bounds__(128) void k_attn_part(const float* __restrict__ qkv,
    float* __restrict__ Pm, float* __restrict__ Pl, float* __restrict__ Pacc)
{
  __shared__ float Ks[128][DHD];
  __shared__ float Vs[128][DHD];
  const int q  = blockIdx.x * 128 + threadIdx.x;
  const int bh = blockIdx.y;
  const int b  = bh >> 2, h = bh & 3;
  const int ks = blockIdx.z;
  const bool valid = q < SEQ;
  const float SC = 0.25f * 1.4426950408889634f;   // scale * log2(e)
  float qv[DHD];
  if (valid){
    const float4* qr = (const float4*)(qkv + ((size_t)(b*SEQ + q))*192 + h*DHD);
    #pragma unroll
    for (int j = 0; j < 4; ++j){
      float4 t = qr[j];
      qv[j*4+0] = t.x; qv[j*4+1] = t.y; qv[j*4+2] = t.z; qv[j*4+3] = t.w;
    }
  }
  const int kbeg = ks * KCH;
  // stage 125 K/V rows
  for (int el = threadIdx.x; el < KCH * 4; el += 128){
    int r = el >> 2, d4 = el & 3;
    const float4* base = (const float4*)(qkv + ((size_t)(b*SEQ + kbeg + r))*192 + h*DHD);
    ((float4*)Ks[r])[d4] = base[16 + d4];      // +64 floats  = K block
    ((float4*)Vs[r])[d4] = base[32 + d4];      // +128 floats = V block
  }
  __syncthreads();
  float m = -1e30f, l = 0.f, acc[DHD] = {};
  if (valid){
    for (int r = 0; r < KCH; ++r){
      float s = 0.f;
      #pragma unroll
      for (int d = 0; d < DHD; ++d) s = fmaf(qv[d], Ks[r][d], s);
      s *= SC;                                   // log2-domain logit
      if (__any(s > m + 8.f)){                   // rare: true rescale
        float mn = fmaxf(m, s);
        float cc = exp2f(m - mn);
        l *= cc;
        #pragma unroll
        for (int d = 0; d < DHD; ++d) acc[d] *= cc;
        m = mn;
      }
      float p = exp2f(s - m);                    // bounded by 2^8
      l += p;
      #pragma unroll
      for (int d = 0; d < DHD; ++d) acc[d] = fmaf(p, Vs[r][d], acc[d]);
    }
    size_t qi = ((size_t)bh * SEQ + q) * KSPLIT + ks;
    Pm[qi] = m; Pl[qi] = l;
    #pragma unroll
    for (int d = 0; d < DHD; ++d) Pacc[qi*DHD + d] = acc[d];
  }
}

// stage 2: merge KSPLIT partials per query -> o[N][64] (log2 domain)
__global__ void k_attn_comb(const float* __restrict__ Pm, const float* __restrict__ Pl,
                            const float* __restrict__ Pacc, float* __restrict__ o)
{
  int qi = blockIdx.x * blockDim.x + threadIdx.x;
  if (qi >= BATCH * NHTR * SEQ) return;
  float m = -1e30f;
  #pragma unroll
  for (int ks = 0; ks < KSPLIT; ++ks) m = fmaxf(m, Pm[(size_t)qi*KSPLIT + ks]);
  float l = 0.f, acc[DHD] = {};
  #pragma unroll
  for (int ks = 0; ks < KSPLIT; ++ks){
    size_t p = (size_t)qi*KSPLIT + ks;
    float sc = exp2f(Pm[p] - m);
    l += Pl[p] * sc;
    #pragma unroll
    for (int d = 0; d < DHD; ++d) acc[d] = fmaf(Pacc[p*DHD + d], sc, acc[d]);
  }
  int bh = qi / SEQ, q = qi - bh * SEQ;
  int b = bh >> 2, h = bh & 3;
  float inv = 1.f / l;
  #pragma unroll
  for (int d = 0; d < DHD; ++d)
    o[((size_t)(b*SEQ + q))*64 + h*DHD + d] = acc[d] * inv;
}

// ---------------------------------------------------------------------------
__global__ __launch_bounds__(256) void k_addln(const float* __restrict__ x,
    const float* __restrict__ y, const float* __restrict__ g,
    const float* __restrict__ b, float* __restrict__ out)
{
  int row = blockIdx.x * 4 + (threadIdx.x >> 6);
  int lane = threadIdx.x & 63;
  if (row >= NN) return;
  float v = x[(size_t)row*64 + lane] + y[(size_t)row*64 + lane];
  float s1 = v, s2 = v * v;
  #pragma unroll
  for (int o = 32; o; o >>= 1){ s1 += __shfl_xor(s1, o); s2 += __shfl_xor(s2, o); }
  float mean = s1 * (1.f/64.f);
  float var  = s2 * (1.f/64.f) - mean * mean;
  float r = rsqrtf(var + 1e-5f);
  out[(size_t)row*64 + lane] = (v - mean) * r * g[lane] + b[lane];
}

__global__ void k_concat_feats(const float* __restrict__ x,
                               const float* __restrict__ tout,
                               float* __restrict__ feats)
{
  int i = blockIdx.x * blockDim.x + threadIdx.x;
  if (i >= NN * 21) return;
  int n = i / 21, c = i - 21*n;
  feats[i] = (c < 5) ? x[(size_t)n*7 + 2 + c] : tout[(size_t)n*16 + c - 5];
}

__global__ void k_initcoord(const float* __restrict__ x, float* __restrict__ coord)
{
  int i = blockIdx.x * blockDim.x + threadIdx.x;
  if (i >= NN * 2) return;
  coord[i] = x[(size_t)(i >> 1)*7 + (i & 1)];
}

// ---------------------------------------------------------------------------
// CSR build (by dst). dst for e>=NEDGE is the self-loop e-NEDGE.
// ---------------------------------------------------------------------------
__global__ void k_count(const int* __restrict__ dst, int* __restrict__ cnt)
{
  int e = blockIdx.x * blockDim.x + threadIdx.x;
  if (e >= ELOOP) return;
  int d = (e < NEDGE) ? dst[e] : e - NEDGE;
  atomicAdd(&cnt[d], 1);
}

__global__ __launch_bounds__(1024) void k_scan(const int* __restrict__ cnt,
                                               int* __restrict__ ptr)
{
  __shared__ int part[1024];
  int tid = threadIdx.x;
  const int per = 8;
  int loc[per]; int s = 0;
  int base = tid * per;
  #pragma unroll
  for (int i = 0; i < per; ++i){
    int v = (base + i < NN) ? cnt[base + i] : 0;
    loc[i] = s; s += v;
  }
  part[tid] = s;
  __syncthreads();
  for (int off = 1; off < 1024; off <<= 1){
    int v = 0;
    if (tid >= off) v = part[tid - off];
    __syncthreads();
    if (tid >= off) part[tid] += v;
    __syncthreads();
  }
  int pre = tid ? part[tid - 1] : 0;
  #pragma unroll
  for (int i = 0; i < per; ++i)
    if (base + i < NN) ptr[base + i] = pre + loc[i];
  if (tid == 1023) ptr[NN] = part[1023];
}

__global__ void k_fill(const int* __restrict__ dst, const int* __restrict__ ptr,
                       int* __restrict__ fil, int* __restrict__ eid)
{
  int e = blockIdx.x * blockDim.x + threadIdx.x;
  if (e >= ELOOP) return;
  int d = (e < NEDGE) ? dst[e] : e - NEDGE;
  int pos = ptr[d] + atomicAdd(&fil[d], 1);
  eid[pos] = e;
}

// ---------------------------------------------------------------------------
// logits2[pos*6+h] over CSR (dst-sorted) positions. One WAVE per edge,
// looping over the 6 heads. bf16 xl/xr, uint4. XCD swizzle (10000 = 8*1250).
// ---------------------------------------------------------------------------
__global__ __launch_bounds__(256) void k_logits(const unsigned short* __restrict__ xlb,
    const unsigned short* __restrict__ xrb, const int* __restrict__ src_a,
    const int* __restrict__ dst_a, const int* __restrict__ eid,
    const float* __restrict__ att, float* __restrict__ logits2)
{
  int bid = blockIdx.x;                         // 10000 = 8 * 1250
  int wgs = (bid & 7) * 1250 + (bid >> 3);      // bijective XCD chunking
  int pos = wgs * 4 + (threadIdx.x >> 6);
  if (pos >= ELOOP) return;
  int lane = threadIdx.x & 63;
  int e = eid[pos];
  int s = (e < NEDGE) ? src_a[e] : e - NEDGE;
  int d = (e < NEDGE) ? dst_a[e] : e - NEDGE;
  const uint4* pl = (const uint4*)(xlb + (size_t)s * GOUT);
  const uint4* pr = (const uint4*)(xrb + (size_t)d * GOUT);
  const float4* pa = (const float4*)att;
  #pragma unroll 2
  for (int h = 0; h < NHEADS; ++h){
    uint4 ua = pl[h*64 + lane];
    uint4 ub = pr[h*64 + lane];
    float4 w0 = pa[h*128 + lane*2], w1 = pa[h*128 + lane*2 + 1];
    float acc = 0.f;
    auto pair = [&](unsigned a, unsigned b, float wl, float wh){
      float vl = __uint_as_float(a << 16)        + __uint_as_float(b << 16);
      float vh = __uint_as_float(a & 0xffff0000u)+ __uint_as_float(b & 0xffff0000u);
      vl = vl > 0.f ? vl : 0.2f * vl;
      vh = vh > 0.f ? vh : 0.2f * vh;
      acc = fmaf(vl, wl, acc);
      acc = fmaf(vh, wh, acc);
    };
    pair(ua.x, ub.x, w0.x, w0.y);
    pair(ua.y, ub.y, w0.z, w0.w);
    pair(ua.z, ub.z, w1.x, w1.y);
    pair(ua.w, ub.w, w1.z, w1.w);
    #pragma unroll
    for (int o2 = 32; o2; o2 >>= 1) acc += __shfl_xor(acc, o2);
    if (lane == 0) logits2[pos*NHEADS + h] = acc;
  }
}

// mx / inv(sum) per (node, head); logits2 is pos-ordered -> sequential reads
__global__ void k_stats(const float* __restrict__ logits2, const int* __restrict__ ptr,
                        float* __restrict__ mx, float* __restrict__ inv)
{
  int i = blockIdx.x * blockDim.x + threadIdx.x;
  if (i >= NN * NHEADS) return;
  int n = i / NHEADS, h = i - NHEADS * n;
  int s0 = ptr[n], s1 = ptr[n + 1];
  float m = -1e30f;
  for (int t = s0; t < s1; ++t) m = fmaxf(m, logits2[t*NHEADS + h]);
  float s = 0.f;
  for (int t = s0; t < s1; ++t) s += __expf(logits2[t*NHEADS + h] - m);
  mx[i] = m; inv[i] = 1.f / s;
}

// ---------------------------------------------------------------------------
// hidden[n,c] = selu(mean_h sum_{e in(n)} a[e,h]*xl[src,h,c] + gbias[c])
// ---------------------------------------------------------------------------
__global__ __launch_bounds__(256) void k_agg(const unsigned short* __restrict__ xlb,
    const float* __restrict__ logits2, const float* __restrict__ mx,
    const float* __restrict__ inv, const int* __restrict__ ptr,
    const int* __restrict__ eid, const int* __restrict__ src_a,
    const float* __restrict__ gbias, float* __restrict__ hidden)
{
  const int n = blockIdx.x;
  const int tid = threadIdx.x;
  __shared__ float a_sh[64 * NHEADS];
  __shared__ int src_sh[64];
  const int s0 = ptr[n];
  const int deg = ptr[n + 1] - s0;
  float acc[12] = {};
  for (int base = 0; base < deg; base += 64){
    int cnt = min(64, deg - base);
    __syncthreads();
    for (int t = tid; t < cnt * NHEADS; t += 256){
      int ei = t / NHEADS, h = t - NHEADS * ei;
      a_sh[t] = __expf(logits2[(s0 + base + ei)*NHEADS + h] - mx[n*NHEADS + h])
                * inv[n*NHEADS + h];
      if (h == 0){
        int e = eid[s0 + base + ei];
        src_sh[ei] = (e < NEDGE) ? src_a[e] : e - NEDGE;
      }
    }
    __syncthreads();
    for (int i2 = 0; i2 < cnt; ++i2){
      const unsigned* row = (const unsigned*)(xlb + (size_t)src_sh[i2] * GOUT);
      #pragma unroll
      for (int k = 0; k < NHEADS; ++k){
        unsigned u = row[tid + (k << 8)];
        float wgt = a_sh[i2*NHEADS + k];
        acc[2*k]   = fmaf(__uint_as_float(u << 16),         wgt, acc[2*k]);
        acc[2*k+1] = fmaf(__uint_as_float(u & 0xffff0000u), wgt, acc[2*k+1]);
      }
    }
  }
  float m0 = (acc[0]+acc[2]+acc[4]+acc[6]+acc[8]+acc[10]) * (1.f/6.f);
  float m1 = (acc[1]+acc[3]+acc[5]+acc[7]+acc[9]+acc[11]) * (1.f/6.f);
  float2 out;
  out.x = selu_f(m0 + gbias[2*tid]);
  out.y = selu_f(m1 + gbias[2*tid + 1]);
  *(float2*)&hidden[(size_t)n*HIDD + 2*tid] = out;
}

// ---------------------------------------------------------------------------
extern "C" void kernel_launch(void* const* d_in, const int* in_sizes, int n_in,
                              void* d_out, int out_size, void* d_ws, size_t ws_size,
                              hipStream_t stream)
{
  const float* mesh     = (const float*)d_in[1];
  const float* xin      = (const float*)d_in[2];
  const int*   ei       = (const int*)d_in[3];
  const float* embed_w  = (const float*)d_in[4];
  const float* embed_b  = (const float*)d_in[5];
  const float* in_proj_w= (const float*)d_in[6];
  const float* in_proj_b= (const float*)d_in[7];
  const float* out_proj_w=(const float*)d_in[8];
  const float* out_proj_b=(const float*)d_in[9];
  const float* ln1_g    = (const float*)d_in[10];
  const float* ln1_b    = (const float*)d_in[11];
  const float* ln2_g    = (const float*)d_in[12];
  const float* ln2_b    = (const float*)d_in[13];
  const float* ff1_w    = (const float*)d_in[14];
  const float* ff1_b    = (const float*)d_in[15];
  const float* ff2_w    = (const float*)d_in[16];
  const float* ff2_b    = (const float*)d_in[17];
  const float* tout_w   = (const float*)d_in[18];
  const float* tout_b   = (const float*)d_in[19];
  const float* lin_w    = (const float*)d_in[20];
  const float* lin_b    = (const float*)d_in[21];
  const float* gat_wl   = (const float*)d_in[22];
  const float* gat_bl   = (const float*)d_in[23];
  const float* gat_wr   = (const float*)d_in[24];
  const float* gat_br   = (const float*)d_in[25];
  const float* gat_att  = (const float*)d_in[26];
  const float* gat_bias = (const float*)d_in[27];
  const float* coord1_w = (const float*)d_in[28];
  const float* coord1_b = (const float*)d_in[29];
  const float* coord2_w = (const float*)d_in[30];
  const float* coord2_b = (const float*)d_in[31];

  const int* esrc = ei;
  const int* edst = ei + NEDGE;

  char* ws = (char*)d_ws;
  size_t off = 0;
  auto alloc = [&](size_t nbytes){
    size_t o = off; off += (nbytes + 255) & ~(size_t)255; return o;
  };
  float* hidden = (float*)(ws + alloc((size_t)NN * HIDD * 4));
  float* coord  = (float*)(ws + alloc((size_t)NN * 2 * 4));
  unsigned short* xlb = (unsigned short*)(ws + alloc((size_t)NN * GOUT * 2));
  unsigned short* xrb = (unsigned short*)(ws + alloc((size_t)NN * GOUT * 2));
  float* logits = (float*)(ws + alloc((size_t)ELOOP * NHEADS * 4));
  float* mxb    = (float*)(ws + alloc((size_t)NN * NHEADS * 4));
  float* invb   = (float*)(ws + alloc((size_t)NN * NHEADS * 4));
  int*   ptr    = (int*)(ws + alloc((size_t)(NN + 1) * 4));
  int*   eid    = (int*)(ws + alloc((size_t)ELOOP * 4));
  int*   cnt    = (int*)(ws + alloc((size_t)NN * 4));
  int*   fil    = (int*)(ws + alloc((size_t)NN * 4));
  short* abf    = (short*)(ws + alloc((size_t)MPAD * K2 * 2));
  short* wlbf   = (short*)(ws + alloc((size_t)GOUT * K1 * 2));
  short* wrbf   = (short*)(ws + alloc((size_t)GOUT * K1 * 2));
  float* part_c1= (float*)(ws + alloc((size_t)4 * NN * 256 * 4));  // 31.25 MiB

  // Transformer-phase temporaries ALIASED inside xlb+xrb (93.75 MiB, all
  // dead before the first k_gat_mfma writes xlb). MiB offsets within region:
  char* arena = (char*)xlb;
  float* h       = (float*)(arena + ((size_t)0  << 20));  // 0-2     (live to ln2)
  float* o       = (float*)(arena + ((size_t)2  << 20));  // 2-4
  float* tmp     = (float*)(arena + ((size_t)4  << 20));  // 4-6
  float* feats   = (float*)(arena + ((size_t)6  << 20));  // 6-6.7
  float* toutb   = (float*)(arena + ((size_t)7  << 20));  // 7-7.6
  float* qkv     = (float*)(arena + ((size_t)8  << 20));  // 8-14.2  (dead after attn)
  float* Pm      = (float*)(arena + ((size_t)15 << 20));  // 15-17   (2 MB, KSPLIT=16)
  float* Pl      = (float*)(arena + ((size_t)17 << 20));  // 17-19
  float* Pacc    = (float*)(arena + ((size_t)19 << 20));  // 19-50.3 (dead after comb)
  float* part_f2 = (float*)(arena + ((size_t)8  << 20));  // 8-23.7  (attn dead by ff2)
  float* ffmid   = (float*)(arena + ((size_t)28 << 20));  // 28-90.5 (Pacc dead by ff1)

  // ---- transformer ----
  k_embed<<<CDIV(NN*DTR, 256), 256, 0, stream>>>(mesh, embed_w, embed_b, h);
  k_gemm<0><<<dim3(CDIV(192,64), CDIV(NN,64)), 256, 0, stream>>>(h, in_proj_w, in_proj_b, qkv, NN, 192, DTR);
  k_attn_part<<<dim3(CDIV(SEQ,128), BATCH*NHTR, KSPLIT), 128, 0, stream>>>(qkv, Pm, Pl, Pacc);
  k_attn_comb<<<CDIV(BATCH*NHTR*SEQ, 256), 256, 0, stream>>>(Pm, Pl, Pacc, o);
  k_gemm<0><<<dim3(1, CDIV(NN,64)), 256, 0, stream>>>(o, out_proj_w, out_proj_b, tmp, NN, DTR, DTR);
  k_addln<<<CDIV(NN,4), 256, 0, stream>>>(h, tmp, ln1_g, ln1_b, h);
  k_gemm<1><<<dim3(CDIV(FFD,64), CDIV(NN,64)), 256, 0, stream>>>(h, ff1_w, ff1_b, ffmid, NN, FFD, DTR);
  k_gemm_sk<<<dim3(1, CDIV(NN,64), 8), 256, 0, stream>>>(ffmid, ff2_w, part_f2, NN, DTR, FFD, 256);
  k_comb<0><<<CDIV(NN*DTR, 256), 256, 0, stream>>>(part_f2, ff2_b, tmp, NN, DTR, 8);
  k_addln<<<CDIV(NN,4), 256, 0, stream>>>(h, tmp, ln2_g, ln2_b, h);
  k_gemm<0><<<dim3(1, CDIV(NN,64)), 256, 0, stream>>>(h, tout_w, tout_b, toutb, NN, TOUTD, DTR);
  k_concat_feats<<<CDIV(NN*21, 256), 256, 0, stream>>>(xin, toutb, feats);
  k_gemm<2><<<dim3(CDIV(HIDD,64), CDIV(NN,64)), 256, 0, stream>>>(feats, lin_w, lin_b, hidden, NN, HIDD, 21);
  k_initcoord<<<CDIV(NN*2, 256), 256, 0, stream>>>(xin, coord);

  // ---- CSR by dst + weight conversion (once) ----
  hipMemsetAsync(cnt, 0, (size_t)NN * 4, stream);
  hipMemsetAsync(fil, 0, (size_t)NN * 4, stream);
  k_count<<<CDIV(ELOOP, 256), 256, 0, stream>>>(edst, cnt);
  k_scan<<<1, 1024, 0, stream>>>(cnt, ptr);
  k_fill<<<CDIV(ELOOP, 256), 256, 0, stream>>>(edst, ptr, fil, eid);
  k_cvt_w<<<CDIV(GOUT*K1, 256), 256, 0, stream>>>(gat_wl, wlbf);
  k_cvt_w<<<CDIV(GOUT*K1, 256), 256, 0, stream>>>(gat_wr, wrbf);

  // ---- GAT loops ----
  for (int it = 0; it < 3; ++it){
    k_cvt_a<<<CDIV(MPAD*K1, 256), 256, 0, stream>>>(coord, hidden, abf);
    k_gat_mfma<<<dim3(GOUT/128, MPAD/128), 256, 0, stream>>>(abf, wlbf, gat_bl, xlb);
    k_gat_mfma<<<dim3(GOUT/128, MPAD/128), 256, 0, stream>>>(abf, wrbf, gat_br, xrb);
    k_logits<<<ELOOP/4, 256, 0, stream>>>(xlb, xrb, esrc, edst, eid, gat_att, logits);
    k_stats<<<CDIV(NN*NHEADS, 256), 256, 0, stream>>>(logits, ptr, mxb, invb);
    k_agg<<<NN, 256, 0, stream>>>(xlb, logits, mxb, invb, ptr, eid, esrc, gat_bias, hidden);
    k_gemm_sk<<<dim3(CDIV(256,64), CDIV(NN,64), 4), 256, 0, stream>>>(hidden, coord1_w, part_c1, NN, 256, HIDD, 128);
    float* cdst = (it == 2) ? (float*)d_out : coord;
    k_coord<<<NN, 256, 0, stream>>>(part_c1, coord1_b, coord2_w, coord2_b, cdst);
  }
}

// Round 12
// 1246.765 us; speedup vs baseline: 1.7839x; 1.0166x over previous
//
#include <hip/hip_runtime.h>
#include <hip/hip_bf16.h>
#include <math.h>

#define NN     8000
#define MPAD   8064    /* NN padded to 128 */
#define BATCH  4
#define SEQ    2000
#define DTR    64
#define NHTR   4
#define DHD    16
#define FFD    2048
#define TOUTD  16
#define HIDD   512
#define NHEADS 6
#define HCD    512
#define GIND   514
#define GOUT   3072
#define NEDGE  32000
#define ELOOP  40000   /* NEDGE + NN */

#define K1     576     /* GIND padded to 64-multiple */
#define K2     1152    /* hi + lo halves (A only) */

#define KSPLIT 16
#define KCH    125     /* SEQ / KSPLIT */

#define CDIV(a,b) (((a)+(b)-1)/(b))

using bf16x8 = __attribute__((__ext_vector_type__(8))) __bf16;
using f32x4  = __attribute__((__ext_vector_type__(4))) float;

__device__ __forceinline__ float selu_f(float x){
  const float a = 1.6732632423543772848f;
  const float s = 1.0507009873554805f;
  return x > 0.f ? s * x : s * a * (__expf(x) - 1.f);
}

__device__ __forceinline__ unsigned short f2bf_rn(float x){
  unsigned u = __float_as_uint(x);
  unsigned r = (u + 0x7fffu + ((u >> 16) & 1u)) >> 16;
  return (unsigned short)r;
}
__device__ __forceinline__ float bf2f(unsigned short h){
  return __uint_as_float((unsigned)h << 16);
}

// ---------------------------------------------------------------------------
// Generic C[M,N] = act(A[M,K] @ W[N,K]^T + bias). fp32, 64x64 tile, BK=16.
// ---------------------------------------------------------------------------
template<int ACT>  // 0=none 1=relu 2=selu
__global__ __launch_bounds__(256) void k_gemm(const float* __restrict__ A,
    const float* __restrict__ W, const float* __restrict__ bias,
    float* __restrict__ C, int M, int N, int K)
{
  __shared__ float As[16][68];
  __shared__ float Ws[16][68];
  const int tid = threadIdx.x;
  const int bm = blockIdx.y * 64, bn = blockIdx.x * 64;
  const int tx = tid & 15, ty = tid >> 4;
  float acc[4][4] = {};
  for (int k0 = 0; k0 < K; k0 += 16){
    #pragma unroll
    for (int i = 0; i < 4; ++i){
      int el = tid + (i << 8);
      int kk = el & 15, r = el >> 4;
      int gk = k0 + kk;
      int gm = bm + r;
      As[kk][r] = (gm < M && gk < K) ? A[(size_t)gm * K + gk] : 0.f;
      int gn = bn + r;
      Ws[kk][r] = (gn < N && gk < K) ? W[(size_t)gn * K + gk] : 0.f;
    }
    __syncthreads();
    #pragma unroll
    for (int kk = 0; kk < 16; ++kk){
      float av[4], wv[4];
      #pragma unroll
      for (int i = 0; i < 4; ++i) av[i] = As[kk][ty*4+i];
      #pragma unroll
      for (int j = 0; j < 4; ++j) wv[j] = Ws[kk][tx*4+j];
      #pragma unroll
      for (int i = 0; i < 4; ++i)
        #pragma unroll
        for (int j = 0; j < 4; ++j) acc[i][j] = fmaf(av[i], wv[j], acc[i][j]);
    }
    __syncthreads();
  }
  #pragma unroll
  for (int i = 0; i < 4; ++i){
    int gm = bm + ty*4 + i;
    if (gm >= M) continue;
    #pragma unroll
    for (int j = 0; j < 4; ++j){
      int gn = bn + tx*4 + j;
      if (gn >= N) continue;
      float v = acc[i][j] + bias[gn];
      if (ACT == 1) v = fmaxf(v, 0.f);
      if (ACT == 2) v = selu_f(v);
      C[(size_t)gm * N + gn] = v;
    }
  }
}

// ---------------------------------------------------------------------------
// Split-K GEMM: partial[z][M][N] = A[:, z*kchunk:(z+1)*kchunk] @ W^T slice.
// ---------------------------------------------------------------------------
__global__ __launch_bounds__(256) void k_gemm_sk(const float* __restrict__ A,
    const float* __restrict__ W, float* __restrict__ part,
    int M, int N, int K, int kchunk)
{
  __shared__ float As[16][68];
  __shared__ float Ws[16][68];
  const int tid = threadIdx.x;
  const int bm = blockIdx.y * 64, bn = blockIdx.x * 64;
  const int kbeg = blockIdx.z * kchunk;
  const int tx = tid & 15, ty = tid >> 4;
  float acc[4][4] = {};
  for (int k0 = kbeg; k0 < kbeg + kchunk; k0 += 16){
    #pragma unroll
    for (int i = 0; i < 4; ++i){
      int el = tid + (i << 8);
      int kk = el & 15, r = el >> 4;
      int gk = k0 + kk;
      int gm = bm + r;
      As[kk][r] = (gm < M && gk < K) ? A[(size_t)gm * K + gk] : 0.f;
      int gn = bn + r;
      Ws[kk][r] = (gn < N && gk < K) ? W[(size_t)gn * K + gk] : 0.f;
    }
    __syncthreads();
    #pragma unroll
    for (int kk = 0; kk < 16; ++kk){
      float av[4], wv[4];
      #pragma unroll
      for (int i = 0; i < 4; ++i) av[i] = As[kk][ty*4+i];
      #pragma unroll
      for (int j = 0; j < 4; ++j) wv[j] = Ws[kk][tx*4+j];
      #pragma unroll
      for (int i = 0; i < 4; ++i)
        #pragma unroll
        for (int j = 0; j < 4; ++j) acc[i][j] = fmaf(av[i], wv[j], acc[i][j]);
    }
    __syncthreads();
  }
  float* pz = part + (size_t)blockIdx.z * M * N;
  #pragma unroll
  for (int i = 0; i < 4; ++i){
    int gm = bm + ty*4 + i;
    if (gm >= M) continue;
    #pragma unroll
    for (int j = 0; j < 4; ++j){
      int gn = bn + tx*4 + j;
      if (gn >= N) continue;
      pz[(size_t)gm * N + gn] = acc[i][j];
    }
  }
}

// combine KS partials + bias + activation
template<int ACT>
__global__ void k_comb(const float* __restrict__ part, const float* __restrict__ bias,
                       float* __restrict__ C, int M, int N, int KS)
{
  int i = blockIdx.x * blockDim.x + threadIdx.x;
  if (i >= M * N) return;
  int n = i - N * (i / N);
  float v = bias[n];
  for (int z = 0; z < KS; ++z) v += part[(size_t)z * M * N + i];
  if (ACT == 1) v = fmaxf(v, 0.f);
  if (ACT == 2) v = selu_f(v);
  C[i] = v;
}

// ---------------------------------------------------------------------------
// fused coord tail: c1 = selu(sum_z part + bias), coord = c1 @ w2^T + b2.
// Also refreshes abf coord columns (0,1) hi/lo for the next GAT loop.
// ---------------------------------------------------------------------------
__global__ __launch_bounds__(256) void k_coord(const float* __restrict__ part,
    const float* __restrict__ c1b, const float* __restrict__ w2,
    const float* __restrict__ b2, float* __restrict__ out,
    short* __restrict__ abf)
{
  int n = blockIdx.x, t = threadIdx.x;
  float v = c1b[t];
  #pragma unroll
  for (int z = 0; z < 4; ++z) v += part[(size_t)z*NN*256 + (size_t)n*256 + t];
  v = selu_f(v);
  float d0 = v * w2[t], d1 = v * w2[256 + t];
  #pragma unroll
  for (int o = 32; o; o >>= 1){ d0 += __shfl_xor(d0, o); d1 += __shfl_xor(d1, o); }
  __shared__ float red[8];
  int wv = t >> 6;
  if ((t & 63) == 0){ red[wv] = d0; red[4 + wv] = d1; }
  __syncthreads();
  if (t < 2){
    float c = (t == 0 ? red[0]+red[1]+red[2]+red[3] + b2[0]
                      : red[4]+red[5]+red[6]+red[7] + b2[1]);
    out[(size_t)n*2 + t] = c;
    unsigned short hi = f2bf_rn(c);
    unsigned short lo = f2bf_rn(c - bf2f(hi));
    abf[(size_t)n*K2 + t]      = (short)hi;
    abf[(size_t)n*K2 + K1 + t] = (short)lo;
  }
}

// ---------------------------------------------------------------------------
// weight fp32 [3072][514] -> single bf16 (RN) [3072][K1]
// ---------------------------------------------------------------------------
__global__ void k_cvt_w(const float* __restrict__ W, short* __restrict__ Wbf)
{
  int i = blockIdx.x * blockDim.x + threadIdx.x;
  if (i >= GOUT * K1) return;
  int n = i / K1, k = i - K1 * n;
  float v = (k < GIND) ? W[(size_t)n * GIND + k] : 0.f;
  Wbf[i] = (short)f2bf_rn(v);
}

// A = [coord | hidden] fp32 -> bf16 split [MPAD][K2] = [hi(576) | lo(576)]
// Run ONCE before the GAT loop; later loops refresh via k_agg / k_coord.
__global__ void k_cvt_a(const float* __restrict__ coord,
                        const float* __restrict__ hidden,
                        short* __restrict__ Abf)
{
  int i = blockIdx.x * blockDim.x + threadIdx.x;
  if (i >= MPAD * K1) return;
  int n = i / K1, k = i - K1 * n;
  float v = 0.f;
  if (n < NN && k < GIND)
    v = (k < 2) ? coord[(size_t)n*2 + k] : hidden[(size_t)n*HIDD + k - 2];
  unsigned short h = f2bf_rn(v);
  unsigned short l = f2bf_rn(v - bf2f(h));
  Abf[(size_t)n * K2 + k]      = (short)h;
  Abf[(size_t)n * K2 + K1 + k] = (short)l;
}

// ---------------------------------------------------------------------------
// GAT GEMM via MFMA bf16, 2-pass hi/lo split on A (18 K-tiles of 64):
//  tiles 0-8: a_hi*b ; 9-17: a_lo*b   (b = single RN bf16)
// Output bf16. LDS XOR swizzle both-sides; bijective XCD swizzle (1512=8*189).
// ---------------------------------------------------------------------------
__global__ __launch_bounds__(256) void k_gat_mfma(
    const short* __restrict__ Abf, const short* __restrict__ Wbf,
    const float* __restrict__ bias, unsigned short* __restrict__ Cb)
{
  __shared__ short As[128 * 64];
  __shared__ short Bs[128 * 64];
  const int tid  = threadIdx.x;
  int lin = blockIdx.y * 24 + blockIdx.x;          // 24*63 = 1512 = 8*189
  int wg  = (lin & 7) * 189 + (lin >> 3);          // bijective XCD chunking
  const int bm = (wg / 24) * 128, bn = (wg % 24) * 128;
  const int w    = tid >> 6, lane = tid & 63;
  const int wr   = w >> 1, wc = w & 1;
  const int lrow = lane & 15;

  f32x4 acc[4][4];
  #pragma unroll
  for (int i = 0; i < 4; ++i)
    #pragma unroll
    for (int j = 0; j < 4; ++j) acc[i][j] = (f32x4){0.f, 0.f, 0.f, 0.f};

  for (int kt = 0; kt < 18; ++kt){
    int aoff = (kt < 9) ? kt * 64 : K1 + (kt - 9) * 64;
    int boff = ((kt < 9) ? kt : kt - 9) * 64;
    __syncthreads();                 // previous tile fully consumed
    #pragma unroll
    for (int i = 0; i < 4; ++i){
      int l  = i * 256 + tid;        // 16B-chunk index 0..1023
      int r  = l >> 3, j = l & 7;
      int js = j ^ (r & 7);          // source pre-swizzle (write side)
      const short* ga = Abf + (size_t)(bm + r) * K2 + aoff + js * 8;
      const short* gb = Wbf + (size_t)(bn + r) * K1 + boff + js * 8;
      short* la = As + ((i * 256 + w * 64) << 3);   // wave-uniform base
      short* lb = Bs + ((i * 256 + w * 64) << 3);
      __builtin_amdgcn_global_load_lds(
          (const __attribute__((address_space(1))) unsigned*)ga,
          (__attribute__((address_space(3))) unsigned*)la, 16, 0, 0);
      __builtin_amdgcn_global_load_lds(
          (const __attribute__((address_space(1))) unsigned*)gb,
          (__attribute__((address_space(3))) unsigned*)lb, 16, 0, 0);
    }
    __syncthreads();                 // drains vmcnt, tile ready
    #pragma unroll
    for (int ks = 0; ks < 2; ++ks){
      // read-side swizzle: chunk c = ks*4 + (lane>>4), row&7 == lrow&7
      const int co = ((ks * 4 + (lane >> 4)) ^ (lrow & 7)) * 8;
      bf16x8 fa[4], fb[4];
      #pragma unroll
      for (int mi = 0; mi < 4; ++mi)
        fa[mi] = *(const bf16x8*)&As[(wr*64 + mi*16 + lrow) * 64 + co];
      #pragma unroll
      for (int ni = 0; ni < 4; ++ni)
        fb[ni] = *(const bf16x8*)&Bs[(wc*64 + ni*16 + lrow) * 64 + co];
      #pragma unroll
      for (int mi = 0; mi < 4; ++mi)
        #pragma unroll
        for (int ni = 0; ni < 4; ++ni)
          acc[mi][ni] = __builtin_amdgcn_mfma_f32_16x16x32_bf16(
              fa[mi], fb[ni], acc[mi][ni], 0, 0, 0);
    }
  }
  // epilogue: bf16 output. col = lane&15, row = (lane>>4)*4 + j
  #pragma unroll
  for (int mi = 0; mi < 4; ++mi){
    #pragma unroll
    for (int ni = 0; ni < 4; ++ni){
      int gn = bn + wc*64 + ni*16 + lrow;
      float bv = bias[gn];
      #pragma unroll
      for (int j = 0; j < 4; ++j){
        int gm = bm + wr*64 + mi*16 + (lane >> 4) * 4 + j;
        if (gm < NN)
          Cb[(size_t)gm * GOUT + gn] = f2bf_rn(acc[mi][ni][j] + bv);
      }
    }
  }
}

// ---------------------------------------------------------------------------
__global__ void k_embed(const float* __restrict__ mesh,
                        const float* __restrict__ w, const float* __restrict__ b,
                        float* __restrict__ h)
{
  int i = blockIdx.x * blockDim.x + threadIdx.x;
  if (i >= NN * DTR) return;
  int n = i >> 6, d = i & 63;
  const float* mr = mesh + n * 4;
  const float* wr = w + d * 4;
  h[i] = fmaf(mr[0], wr[0], fmaf(mr[1], wr[1], fmaf(mr[2], wr[2], mr[3]*wr[3]))) + b[d];
}

// ---------------------------------------------------------------------------
// split-K flash attention, stage 1. Defer-max (T13) in log2 domain.
// TWO queries per thread (q, q+1024): the 8 broadcast ds_read_b128 per key
// now feed 64 FMA-instrs instead of 32 -> VALU-dominant, not LDS-bound.
// ---------------------------------------------------------------------------
__global__ __launch_bounds__(128) void k_attn_part(const float* __restrict__ qkv,
    float* __restrict__ Pm, float* __restrict__ Pl, float* __restrict__ Pacc)
{
  __shared__ float Ks[128][DHD];
  __shared__ float Vs[128][DHD];
  const int q1 = blockIdx.x * 128 + threadIdx.x;   // 0..1023
  const int q2 = q1 + 1024;                        // 1024..2047
  const int bh = blockIdx.y;
  const int b  = bh >> 2, h = bh & 3;
  const int ks = blockIdx.z;
  const bool v2 = q2 < SEQ;
  const float SC = 0.25f * 1.4426950408889634f;    // scale * log2(e)
  float qv1[DHD], qv2[DHD];
  {
    const float4* qr = (const float4*)(qkv + ((size_t)(b*SEQ + q1))*192 + h*DHD);
    #pragma unroll
    for (int j = 0; j < 4; ++j){
      float4 t = qr[j];
      qv1[j*4+0] = t.x; qv1[j*4+1] = t.y; qv1[j*4+2] = t.z; qv1[j*4+3] = t.w;
    }
  }
  if (v2){
    const float4* qr = (const float4*)(qkv + ((size_t)(b*SEQ + q2))*192 + h*DHD);
    #pragma unroll
    for (int j = 0; j < 4; ++j){
      float4 t = qr[j];
      qv2[j*4+0] = t.x; qv2[j*4+1] = t.y; qv2[j*4+2] = t.z; qv2[j*4+3] = t.w;
    }
  } else {
    #pragma unroll
    for (int j = 0; j < DHD; ++j) qv2[j] = 0.f;
  }
  const int kbeg = ks * KCH;
  for (int el = threadIdx.x; el < KCH * 4; el += 128){
    int r = el >> 2, d4 = el & 3;
    const float4* base = (const float4*)(qkv + ((size_t)(b*SEQ + kbeg + r))*192 + h*DHD);
    ((float4*)Ks[r])[d4] = base[16 + d4];      // +64 floats  = K block
    ((float4*)Vs[r])[d4] = base[32 + d4];      // +128 floats = V block
  }
  __syncthreads();
  float m1 = -1e30f, l1 = 0.f, a1[DHD] = {};
  float m2 = -1e30f, l2 = 0.f, a2[DHD] = {};
  for (int r = 0; r < KCH; ++r){
    float s1 = 0.f, s2 = 0.f;
    #pragma unroll
    for (int d = 0; d < DHD; ++d){
      float kd = Ks[r][d];
      s1 = fmaf(qv1[d], kd, s1);
      s2 = fmaf(qv2[d], kd, s2);
    }
    s1 *= SC; s2 *= SC;
    if (__any((s1 > m1 + 8.f) || (s2 > m2 + 8.f))){
      float mn1 = fmaxf(m1, s1), mn2 = fmaxf(m2, s2);
      float c1 = exp2f(m1 - mn1), c2 = exp2f(m2 - mn2);
      l1 *= c1; l2 *= c2;
      #pragma unroll
      for (int d = 0; d < DHD; ++d){ a1[d] *= c1; a2[d] *= c2; }
      m1 = mn1; m2 = mn2;
    }
    float p1 = exp2f(s1 - m1), p2 = exp2f(s2 - m2);
    l1 += p1; l2 += p2;
    #pragma unroll
    for (int d = 0; d < DHD; ++d){
      float vd = Vs[r][d];
      a1[d] = fmaf(p1, vd, a1[d]);
      a2[d] = fmaf(p2, vd, a2[d]);
    }
  }
  {
    size_t qi = ((size_t)bh * SEQ + q1) * KSPLIT + ks;
    Pm[qi] = m1; Pl[qi] = l1;
    #pragma unroll
    for (int d = 0; d < DHD; ++d) Pacc[qi*DHD + d] = a1[d];
  }
  if (v2){
    size_t qi = ((size_t)bh * SEQ + q2) * KSPLIT + ks;
    Pm[qi] = m2; Pl[qi] = l2;
    #pragma unroll
    for (int d = 0; d < DHD; ++d) Pacc[qi*DHD + d] = a2[d];
  }
}

// stage 2: merge KSPLIT partials per query -> o[N][64] (log2 domain)
__global__ void k_attn_comb(const float* __restrict__ Pm, const float* __restrict__ Pl,
                            const float* __restrict__ Pacc, float* __restrict__ o)
{
  int qi = blockIdx.x * blockDim.x + threadIdx.x;
  if (qi >= BATCH * NHTR * SEQ) return;
  float m = -1e30f;
  #pragma unroll
  for (int ks = 0; ks < KSPLIT; ++ks) m = fmaxf(m, Pm[(size_t)qi*KSPLIT + ks]);
  float l = 0.f, acc[DHD] = {};
  #pragma unroll
  for (int ks = 0; ks < KSPLIT; ++ks){
    size_t p = (size_t)qi*KSPLIT + ks;
    float sc = exp2f(Pm[p] - m);
    l += Pl[p] * sc;
    #pragma unroll
    for (int d = 0; d < DHD; ++d) acc[d] = fmaf(Pacc[p*DHD + d], sc, acc[d]);
  }
  int bh = qi / SEQ, q = qi - bh * SEQ;
  int b = bh >> 2, h = bh & 3;
  float inv = 1.f / l;
  #pragma unroll
  for (int d = 0; d < DHD; ++d)
    o[((size_t)(b*SEQ + q))*64 + h*DHD + d] = acc[d] * inv;
}

// ---------------------------------------------------------------------------
__global__ __launch_bounds__(256) void k_addln(const float* __restrict__ x,
    const float* __restrict__ y, const float* __restrict__ g,
    const float* __restrict__ b, float* __restrict__ out)
{
  int row = blockIdx.x * 4 + (threadIdx.x >> 6);
  int lane = threadIdx.x & 63;
  if (row >= NN) return;
  float v = x[(size_t)row*64 + lane] + y[(size_t)row*64 + lane];
  float s1 = v, s2 = v * v;
  #pragma unroll
  for (int o = 32; o; o >>= 1){ s1 += __shfl_xor(s1, o); s2 += __shfl_xor(s2, o); }
  float mean = s1 * (1.f/64.f);
  float var  = s2 * (1.f/64.f) - mean * mean;
  float r = rsqrtf(var + 1e-5f);
  out[(size_t)row*64 + lane] = (v - mean) * r * g[lane] + b[lane];
}

__global__ void k_concat_feats(const float* __restrict__ x,
                               const float* __restrict__ tout,
                               float* __restrict__ feats)
{
  int i = blockIdx.x * blockDim.x + threadIdx.x;
  if (i >= NN * 21) return;
  int n = i / 21, c = i - 21*n;
  feats[i] = (c < 5) ? x[(size_t)n*7 + 2 + c] : tout[(size_t)n*16 + c - 5];
}

__global__ void k_initcoord(const float* __restrict__ x, float* __restrict__ coord)
{
  int i = blockIdx.x * blockDim.x + threadIdx.x;
  if (i >= NN * 2) return;
  coord[i] = x[(size_t)(i >> 1)*7 + (i & 1)];
}

// ---------------------------------------------------------------------------
// CSR build (by dst). dst for e>=NEDGE is the self-loop e-NEDGE.
// ---------------------------------------------------------------------------
__global__ void k_count(const int* __restrict__ dst, int* __restrict__ cnt)
{
  int e = blockIdx.x * blockDim.x + threadIdx.x;
  if (e >= ELOOP) return;
  int d = (e < NEDGE) ? dst[e] : e - NEDGE;
  atomicAdd(&cnt[d], 1);
}

__global__ __launch_bounds__(1024) void k_scan(const int* __restrict__ cnt,
                                               int* __restrict__ ptr)
{
  __shared__ int part[1024];
  int tid = threadIdx.x;
  const int per = 8;
  int loc[per]; int s = 0;
  int base = tid * per;
  #pragma unroll
  for (int i = 0; i < per; ++i){
    int v = (base + i < NN) ? cnt[base + i] : 0;
    loc[i] = s; s += v;
  }
  part[tid] = s;
  __syncthreads();
  for (int off = 1; off < 1024; off <<= 1){
    int v = 0;
    if (tid >= off) v = part[tid - off];
    __syncthreads();
    if (tid >= off) part[tid] += v;
    __syncthreads();
  }
  int pre = tid ? part[tid - 1] : 0;
  #pragma unroll
  for (int i = 0; i < per; ++i)
    if (base + i < NN) ptr[base + i] = pre + loc[i];
  if (tid == 1023) ptr[NN] = part[1023];
}

__global__ void k_fill(const int* __restrict__ dst, const int* __restrict__ ptr,
                       int* __restrict__ fil, int* __restrict__ eid)
{
  int e = blockIdx.x * blockDim.x + threadIdx.x;
  if (e >= ELOOP) return;
  int d = (e < NEDGE) ? dst[e] : e - NEDGE;
  int pos = ptr[d] + atomicAdd(&fil[d], 1);
  eid[pos] = e;
}

// ---------------------------------------------------------------------------
// logits2[pos*6+h] over CSR (dst-sorted) positions. One WAVE per edge,
// looping over the 6 heads. bf16 xl/xr, uint4. XCD swizzle (10000 = 8*1250).
// ---------------------------------------------------------------------------
__global__ __launch_bounds__(256) void k_logits(const unsigned short* __restrict__ xlb,
    const unsigned short* __restrict__ xrb, const int* __restrict__ src_a,
    const int* __restrict__ dst_a, const int* __restrict__ eid,
    const float* __restrict__ att, float* __restrict__ logits2)
{
  int bid = blockIdx.x;                         // 10000 = 8 * 1250
  int wgs = (bid & 7) * 1250 + (bid >> 3);      // bijective XCD chunking
  int pos = wgs * 4 + (threadIdx.x >> 6);
  if (pos >= ELOOP) return;
  int lane = threadIdx.x & 63;
  int e = eid[pos];
  int s = (e < NEDGE) ? src_a[e] : e - NEDGE;
  int d = (e < NEDGE) ? dst_a[e] : e - NEDGE;
  const uint4* pl = (const uint4*)(xlb + (size_t)s * GOUT);
  const uint4* pr = (const uint4*)(xrb + (size_t)d * GOUT);
  const float4* pa = (const float4*)att;
  #pragma unroll 2
  for (int h = 0; h < NHEADS; ++h){
    uint4 ua = pl[h*64 + lane];
    uint4 ub = pr[h*64 + lane];
    float4 w0 = pa[h*128 + lane*2], w1 = pa[h*128 + lane*2 + 1];
    float acc = 0.f;
    auto pair = [&](unsigned a, unsigned b, float wl, float wh){
      float vl = __uint_as_float(a << 16)        + __uint_as_float(b << 16);
      float vh = __uint_as_float(a & 0xffff0000u)+ __uint_as_float(b & 0xffff0000u);
      vl = vl > 0.f ? vl : 0.2f * vl;
      vh = vh > 0.f ? vh : 0.2f * vh;
      acc = fmaf(vl, wl, acc);
      acc = fmaf(vh, wh, acc);
    };
    pair(ua.x, ub.x, w0.x, w0.y);
    pair(ua.y, ub.y, w0.z, w0.w);
    pair(ua.z, ub.z, w1.x, w1.y);
    pair(ua.w, ub.w, w1.z, w1.w);
    #pragma unroll
    for (int o2 = 32; o2; o2 >>= 1) acc += __shfl_xor(acc, o2);
    if (lane == 0) logits2[pos*NHEADS + h] = acc;
  }
}

// mx / inv(sum) per (node, head); logits2 is pos-ordered -> sequential reads
__global__ void k_stats(const float* __restrict__ logits2, const int* __restrict__ ptr,
                        float* __restrict__ mx, float* __restrict__ inv)
{
  int i = blockIdx.x * blockDim.x + threadIdx.x;
  if (i >= NN * NHEADS) return;
  int n = i / NHEADS, h = i - NHEADS * n;
  int s0 = ptr[n], s1 = ptr[n + 1];
  float m = -1e30f;
  for (int t = s0; t < s1; ++t) m = fmaxf(m, logits2[t*NHEADS + h]);
  float s = 0.f;
  for (int t = s0; t < s1; ++t) s += __expf(logits2[t*NHEADS + h] - m);
  mx[i] = m; inv[i] = 1.f / s;
}

// ---------------------------------------------------------------------------
// hidden[n,c] = selu(mean_h sum a[e,h]*xl[src,h,c] + gbias[c]); also writes
// the bf16 hi/lo columns of abf (cols 2+2t, 3+2t) for the next GAT loop.
// ---------------------------------------------------------------------------
__global__ __launch_bounds__(256) void k_agg(const unsigned short* __restrict__ xlb,
    const float* __restrict__ logits2, const float* __restrict__ mx,
    const float* __restrict__ inv, const int* __restrict__ ptr,
    const int* __restrict__ eid, const int* __restrict__ src_a,
    const float* __restrict__ gbias, float* __restrict__ hidden,
    short* __restrict__ abf)
{
  const int n = blockIdx.x;
  const int tid = threadIdx.x;
  __shared__ float a_sh[64 * NHEADS];
  __shared__ int src_sh[64];
  const int s0 = ptr[n];
  const int deg = ptr[n + 1] - s0;
  float acc[12] = {};
  for (int base = 0; base < deg; base += 64){
    int cnt = min(64, deg - base);
    __syncthreads();
    for (int t = tid; t < cnt * NHEADS; t += 256){
      int ei = t / NHEADS, h = t - NHEADS * ei;
      a_sh[t] = __expf(logits2[(s0 + base + ei)*NHEADS + h] - mx[n*NHEADS + h])
                * inv[n*NHEADS + h];
      if (h == 0){
        int e = eid[s0 + base + ei];
        src_sh[ei] = (e < NEDGE) ? src_a[e] : e - NEDGE;
      }
    }
    __syncthreads();
    for (int i2 = 0; i2 < cnt; ++i2){
      const unsigned* row = (const unsigned*)(xlb + (size_t)src_sh[i2] * GOUT);
      #pragma unroll
      for (int k = 0; k < NHEADS; ++k){
        unsigned u = row[tid + (k << 8)];
        float wgt = a_sh[i2*NHEADS + k];
        acc[2*k]   = fmaf(__uint_as_float(u << 16),         wgt, acc[2*k]);
        acc[2*k+1] = fmaf(__uint_as_float(u & 0xffff0000u), wgt, acc[2*k+1]);
      }
    }
  }
  float m0 = (acc[0]+acc[2]+acc[4]+acc[6]+acc[8]+acc[10]) * (1.f/6.f);
  float m1 = (acc[1]+acc[3]+acc[5]+acc[7]+acc[9]+acc[11]) * (1.f/6.f);
  float2 out;
  out.x = selu_f(m0 + gbias[2*tid]);
  out.y = selu_f(m1 + gbias[2*tid + 1]);
  *(float2*)&hidden[(size_t)n*HIDD + 2*tid] = out;
  // abf refresh: hi/lo bf16 for channels (2+2t, 3+2t), packed uint stores
  unsigned short h0 = f2bf_rn(out.x), h1 = f2bf_rn(out.y);
  unsigned short l0 = f2bf_rn(out.x - bf2f(h0)), l1 = f2bf_rn(out.y - bf2f(h1));
  *(unsigned*)&abf[(size_t)n*K2 + 2 + 2*tid]      = (unsigned)h0 | ((unsigned)h1 << 16);
  *(unsigned*)&abf[(size_t)n*K2 + K1 + 2 + 2*tid] = (unsigned)l0 | ((unsigned)l1 << 16);
}

// ---------------------------------------------------------------------------
extern "C" void kernel_launch(void* const* d_in, const int* in_sizes, int n_in,
                              void* d_out, int out_size, void* d_ws, size_t ws_size,
                              hipStream_t stream)
{
  const float* mesh     = (const float*)d_in[1];
  const float* xin      = (const float*)d_in[2];
  const int*   ei       = (const int*)d_in[3];
  const float* embed_w  = (const float*)d_in[4];
  const float* embed_b  = (const float*)d_in[5];
  const float* in_proj_w= (const float*)d_in[6];
  const float* in_proj_b= (const float*)d_in[7];
  const float* out_proj_w=(const float*)d_in[8];
  const float* out_proj_b=(const float*)d_in[9];
  const float* ln1_g    = (const float*)d_in[10];
  const float* ln1_b    = (const float*)d_in[11];
  const float* ln2_g    = (const float*)d_in[12];
  const float* ln2_b    = (const float*)d_in[13];
  const float* ff1_w    = (const float*)d_in[14];
  const float* ff1_b    = (const float*)d_in[15];
  const float* ff2_w    = (const float*)d_in[16];
  const float* ff2_b    = (const float*)d_in[17];
  const float* tout_w   = (const float*)d_in[18];
  const float* tout_b   = (const float*)d_in[19];
  const float* lin_w    = (const float*)d_in[20];
  const float* lin_b    = (const float*)d_in[21];
  const float* gat_wl   = (const float*)d_in[22];
  const float* gat_bl   = (const float*)d_in[23];
  const float* gat_wr   = (const float*)d_in[24];
  const float* gat_br   = (const float*)d_in[25];
  const float* gat_att  = (const float*)d_in[26];
  const float* gat_bias = (const float*)d_in[27];
  const float* coord1_w = (const float*)d_in[28];
  const float* coord1_b = (const float*)d_in[29];
  const float* coord2_w = (const float*)d_in[30];
  const float* coord2_b = (const float*)d_in[31];

  const int* esrc = ei;
  const int* edst = ei + NEDGE;

  char* ws = (char*)d_ws;
  size_t off = 0;
  auto alloc = [&](size_t nbytes){
    size_t o = off; off += (nbytes + 255) & ~(size_t)255; return o;
  };
  float* hidden = (float*)(ws + alloc((size_t)NN * HIDD * 4));
  float* coord  = (float*)(ws + alloc((size_t)NN * 2 * 4));
  unsigned short* xlb = (unsigned short*)(ws + alloc((size_t)NN * GOUT * 2));
  unsigned short* xrb = (unsigned short*)(ws + alloc((size_t)NN * GOUT * 2));
  float* logits = (float*)(ws + alloc((size_t)ELOOP * NHEADS * 4));
  float* mxb    = (float*)(ws + alloc((size_t)NN * NHEADS * 4));
  float* invb   = (float*)(ws + alloc((size_t)NN * NHEADS * 4));
  int*   ptr    = (int*)(ws + alloc((size_t)(NN + 1) * 4));
  int*   eid    = (int*)(ws + alloc((size_t)ELOOP * 4));
  int*   cnt    = (int*)(ws + alloc((size_t)NN * 4));
  int*   fil    = (int*)(ws + alloc((size_t)NN * 4));
  short* abf    = (short*)(ws + alloc((size_t)MPAD * K2 * 2));
  short* wlbf   = (short*)(ws + alloc((size_t)GOUT * K1 * 2));
  short* wrbf   = (short*)(ws + alloc((size_t)GOUT * K1 * 2));
  float* part_c1= (float*)(ws + alloc((size_t)4 * NN * 256 * 4));  // 31.25 MiB

  // Transformer-phase temporaries ALIASED inside xlb+xrb (93.75 MiB, all
  // dead before the first k_gat_mfma writes xlb). MiB offsets within region:
  char* arena = (char*)xlb;
  float* h       = (float*)(arena + ((size_t)0  << 20));  // 0-2     (live to ln2)
  float* o       = (float*)(arena + ((size_t)2  << 20));  // 2-4
  float* tmp     = (float*)(arena + ((size_t)4  << 20));  // 4-6
  float* feats   = (float*)(arena + ((size_t)6  << 20));  // 6-6.7
  float* toutb   = (float*)(arena + ((size_t)7  << 20));  // 7-7.6
  float* qkv     = (float*)(arena + ((size_t)8  << 20));  // 8-14.2  (dead after attn)
  float* Pm      = (float*)(arena + ((size_t)15 << 20));  // 15-17   (2 MB, KSPLIT=16)
  float* Pl      = (float*)(arena + ((size_t)17 << 20));  // 17-19
  float* Pacc    = (float*)(arena + ((size_t)19 << 20));  // 19-50.3 (dead after comb)
  float* part_f2 = (float*)(arena + ((size_t)8  << 20));  // 8-23.7  (attn dead by ff2)
  float* ffmid   = (float*)(arena + ((size_t)28 << 20));  // 28-90.5 (Pacc dead by ff1)

  // ---- transformer ----
  k_embed<<<CDIV(NN*DTR, 256), 256, 0, stream>>>(mesh, embed_w, embed_b, h);
  k_gemm<0><<<dim3(CDIV(192,64), CDIV(NN,64)), 256, 0, stream>>>(h, in_proj_w, in_proj_b, qkv, NN, 192, DTR);
  k_attn_part<<<dim3(CDIV(SEQ,256), BATCH*NHTR, KSPLIT), 128, 0, stream>>>(qkv, Pm, Pl, Pacc);
  k_attn_comb<<<CDIV(BATCH*NHTR*SEQ, 256), 256, 0, stream>>>(Pm, Pl, Pacc, o);
  k_gemm<0><<<dim3(1, CDIV(NN,64)), 256, 0, stream>>>(o, out_proj_w, out_proj_b, tmp, NN, DTR, DTR);
  k_addln<<<CDIV(NN,4), 256, 0, stream>>>(h, tmp, ln1_g, ln1_b, h);
  k_gemm<1><<<dim3(CDIV(FFD,64), CDIV(NN,64)), 256, 0, stream>>>(h, ff1_w, ff1_b, ffmid, NN, FFD, DTR);
  k_gemm_sk<<<dim3(1, CDIV(NN,64), 8), 256, 0, stream>>>(ffmid, ff2_w, part_f2, NN, DTR, FFD, 256);
  k_comb<0><<<CDIV(NN*DTR, 256), 256, 0, stream>>>(part_f2, ff2_b, tmp, NN, DTR, 8);
  k_addln<<<CDIV(NN,4), 256, 0, stream>>>(h, tmp, ln2_g, ln2_b, h);
  k_gemm<0><<<dim3(1, CDIV(NN,64)), 256, 0, stream>>>(h, tout_w, tout_b, toutb, NN, TOUTD, DTR);
  k_concat_feats<<<CDIV(NN*21, 256), 256, 0, stream>>>(xin, toutb, feats);
  k_gemm<2><<<dim3(CDIV(HIDD,64), CDIV(NN,64)), 256, 0, stream>>>(feats, lin_w, lin_b, hidden, NN, HIDD, 21);
  k_initcoord<<<CDIV(NN*2, 256), 256, 0, stream>>>(xin, coord);

  // ---- CSR by dst + weight conversion (once) ----
  hipMemsetAsync(cnt, 0, (size_t)NN * 4, stream);
  hipMemsetAsync(fil, 0, (size_t)NN * 4, stream);
  k_count<<<CDIV(ELOOP, 256), 256, 0, stream>>>(edst, cnt);
  k_scan<<<1, 1024, 0, stream>>>(cnt, ptr);
  k_fill<<<CDIV(ELOOP, 256), 256, 0, stream>>>(edst, ptr, fil, eid);
  k_cvt_w<<<CDIV(GOUT*K1, 256), 256, 0, stream>>>(gat_wl, wlbf);
  k_cvt_w<<<CDIV(GOUT*K1, 256), 256, 0, stream>>>(gat_wr, wrbf);
  k_cvt_a<<<CDIV(MPAD*K1, 256), 256, 0, stream>>>(coord, hidden, abf);  // once

  // ---- GAT loops (abf refreshed in-place by k_agg / k_coord) ----
  for (int it = 0; it < 3; ++it){
    k_gat_mfma<<<dim3(GOUT/128, MPAD/128), 256, 0, stream>>>(abf, wlbf, gat_bl, xlb);
    k_gat_mfma<<<dim3(GOUT/128, MPAD/128), 256, 0, stream>>>(abf, wrbf, gat_br, xrb);
    k_logits<<<ELOOP/4, 256, 0, stream>>>(xlb, xrb, esrc, edst, eid, gat_att, logits);
    k_stats<<<CDIV(NN*NHEADS, 256), 256, 0, stream>>>(logits, ptr, mxb, invb);
    k_agg<<<NN, 256, 0, stream>>>(xlb, logits, mxb, invb, ptr, eid, esrc, gat_bias, hidden, abf);
    k_gemm_sk<<<dim3(CDIV(256,64), CDIV(NN,64), 4), 256, 0, stream>>>(hidden, coord1_w, part_c1, NN, 256, HIDD, 128);
    float* cdst = (it == 2) ? (float*)d_out : coord;
    k_coord<<<NN, 256, 0, stream>>>(part_c1, coord1_b, coord2_w, coord2_b, cdst, abf);
  }
}

// Round 13
// 1068.333 us; speedup vs baseline: 2.0819x; 1.1670x over previous
//
#include <hip/hip_runtime.h>
#include <hip/hip_bf16.h>
#include <math.h>

#define NN     8000
#define MPAD   8064    /* NN padded to 128 */
#define BATCH  4
#define SEQ    2000
#define DTR    64
#define NHTR   4
#define DHD    16
#define FFD    2048
#define TOUTD  16
#define HIDD   512
#define NHEADS 6
#define HCD    512
#define GIND   514
#define GOUT   3072
#define NEDGE  32000
#define ELOOP  40000   /* NEDGE + NN */

#define K1     576     /* GIND padded to 64-multiple */
#define K2     1152    /* abf row stride (hi | lo; lo unused by GEMM now) */

#define KSPLIT 20
#define KCH    100     /* SEQ / KSPLIT */

#define CDIV(a,b) (((a)+(b)-1)/(b))

using bf16x8 = __attribute__((__ext_vector_type__(8))) __bf16;
using f32x4  = __attribute__((__ext_vector_type__(4))) float;

__device__ __forceinline__ float selu_f(float x){
  const float a = 1.6732632423543772848f;
  const float s = 1.0507009873554805f;
  return x > 0.f ? s * x : s * a * (__expf(x) - 1.f);
}

__device__ __forceinline__ unsigned short f2bf_rn(float x){
  unsigned u = __float_as_uint(x);
  unsigned r = (u + 0x7fffu + ((u >> 16) & 1u)) >> 16;
  return (unsigned short)r;
}
__device__ __forceinline__ float bf2f(unsigned short h){
  return __uint_as_float((unsigned)h << 16);
}

// ---------------------------------------------------------------------------
// Generic C[M,N] = act(A[M,K] @ W[N,K]^T + bias). fp32, 64x64 tile, BK=16.
// ---------------------------------------------------------------------------
template<int ACT>  // 0=none 1=relu 2=selu
__global__ __launch_bounds__(256) void k_gemm(const float* __restrict__ A,
    const float* __restrict__ W, const float* __restrict__ bias,
    float* __restrict__ C, int M, int N, int K)
{
  __shared__ float As[16][68];
  __shared__ float Ws[16][68];
  const int tid = threadIdx.x;
  const int bm = blockIdx.y * 64, bn = blockIdx.x * 64;
  const int tx = tid & 15, ty = tid >> 4;
  float acc[4][4] = {};
  for (int k0 = 0; k0 < K; k0 += 16){
    #pragma unroll
    for (int i = 0; i < 4; ++i){
      int el = tid + (i << 8);
      int kk = el & 15, r = el >> 4;
      int gk = k0 + kk;
      int gm = bm + r;
      As[kk][r] = (gm < M && gk < K) ? A[(size_t)gm * K + gk] : 0.f;
      int gn = bn + r;
      Ws[kk][r] = (gn < N && gk < K) ? W[(size_t)gn * K + gk] : 0.f;
    }
    __syncthreads();
    #pragma unroll
    for (int kk = 0; kk < 16; ++kk){
      float av[4], wv[4];
      #pragma unroll
      for (int i = 0; i < 4; ++i) av[i] = As[kk][ty*4+i];
      #pragma unroll
      for (int j = 0; j < 4; ++j) wv[j] = Ws[kk][tx*4+j];
      #pragma unroll
      for (int i = 0; i < 4; ++i)
        #pragma unroll
        for (int j = 0; j < 4; ++j) acc[i][j] = fmaf(av[i], wv[j], acc[i][j]);
    }
    __syncthreads();
  }
  #pragma unroll
  for (int i = 0; i < 4; ++i){
    int gm = bm + ty*4 + i;
    if (gm >= M) continue;
    #pragma unroll
    for (int j = 0; j < 4; ++j){
      int gn = bn + tx*4 + j;
      if (gn >= N) continue;
      float v = acc[i][j] + bias[gn];
      if (ACT == 1) v = fmaxf(v, 0.f);
      if (ACT == 2) v = selu_f(v);
      C[(size_t)gm * N + gn] = v;
    }
  }
}

// ---------------------------------------------------------------------------
// Split-K GEMM: partial[z][M][N] = A[:, z*kchunk:(z+1)*kchunk] @ W^T slice.
// ---------------------------------------------------------------------------
__global__ __launch_bounds__(256) void k_gemm_sk(const float* __restrict__ A,
    const float* __restrict__ W, float* __restrict__ part,
    int M, int N, int K, int kchunk)
{
  __shared__ float As[16][68];
  __shared__ float Ws[16][68];
  const int tid = threadIdx.x;
  const int bm = blockIdx.y * 64, bn = blockIdx.x * 64;
  const int kbeg = blockIdx.z * kchunk;
  const int tx = tid & 15, ty = tid >> 4;
  float acc[4][4] = {};
  for (int k0 = kbeg; k0 < kbeg + kchunk; k0 += 16){
    #pragma unroll
    for (int i = 0; i < 4; ++i){
      int el = tid + (i << 8);
      int kk = el & 15, r = el >> 4;
      int gk = k0 + kk;
      int gm = bm + r;
      As[kk][r] = (gm < M && gk < K) ? A[(size_t)gm * K + gk] : 0.f;
      int gn = bn + r;
      Ws[kk][r] = (gn < N && gk < K) ? W[(size_t)gn * K + gk] : 0.f;
    }
    __syncthreads();
    #pragma unroll
    for (int kk = 0; kk < 16; ++kk){
      float av[4], wv[4];
      #pragma unroll
      for (int i = 0; i < 4; ++i) av[i] = As[kk][ty*4+i];
      #pragma unroll
      for (int j = 0; j < 4; ++j) wv[j] = Ws[kk][tx*4+j];
      #pragma unroll
      for (int i = 0; i < 4; ++i)
        #pragma unroll
        for (int j = 0; j < 4; ++j) acc[i][j] = fmaf(av[i], wv[j], acc[i][j]);
    }
    __syncthreads();
  }
  float* pz = part + (size_t)blockIdx.z * M * N;
  #pragma unroll
  for (int i = 0; i < 4; ++i){
    int gm = bm + ty*4 + i;
    if (gm >= M) continue;
    #pragma unroll
    for (int j = 0; j < 4; ++j){
      int gn = bn + tx*4 + j;
      if (gn >= N) continue;
      pz[(size_t)gm * N + gn] = acc[i][j];
    }
  }
}

// combine KS partials + bias + activation
template<int ACT>
__global__ void k_comb(const float* __restrict__ part, const float* __restrict__ bias,
                       float* __restrict__ C, int M, int N, int KS)
{
  int i = blockIdx.x * blockDim.x + threadIdx.x;
  if (i >= M * N) return;
  int n = i - N * (i / N);
  float v = bias[n];
  for (int z = 0; z < KS; ++z) v += part[(size_t)z * M * N + i];
  if (ACT == 1) v = fmaxf(v, 0.f);
  if (ACT == 2) v = selu_f(v);
  C[i] = v;
}

// ---------------------------------------------------------------------------
// fused coord tail: c1 = selu(sum_z part + bias), coord = c1 @ w2^T + b2.
// Also refreshes abf coord columns (0,1) hi/lo for the next GAT loop.
// ---------------------------------------------------------------------------
__global__ __launch_bounds__(256) void k_coord(const float* __restrict__ part,
    const float* __restrict__ c1b, const float* __restrict__ w2,
    const float* __restrict__ b2, float* __restrict__ out,
    short* __restrict__ abf)
{
  int n = blockIdx.x, t = threadIdx.x;
  float v = c1b[t];
  #pragma unroll
  for (int z = 0; z < 4; ++z) v += part[(size_t)z*NN*256 + (size_t)n*256 + t];
  v = selu_f(v);
  float d0 = v * w2[t], d1 = v * w2[256 + t];
  #pragma unroll
  for (int o = 32; o; o >>= 1){ d0 += __shfl_xor(d0, o); d1 += __shfl_xor(d1, o); }
  __shared__ float red[8];
  int wv = t >> 6;
  if ((t & 63) == 0){ red[wv] = d0; red[4 + wv] = d1; }
  __syncthreads();
  if (t < 2){
    float c = (t == 0 ? red[0]+red[1]+red[2]+red[3] + b2[0]
                      : red[4]+red[5]+red[6]+red[7] + b2[1]);
    out[(size_t)n*2 + t] = c;
    abf[(size_t)n*K2 + t] = (short)f2bf_rn(c);
  }
}

// ---------------------------------------------------------------------------
// weight fp32 [3072][514] -> single bf16 (RN) [3072][K1]
// ---------------------------------------------------------------------------
__global__ void k_cvt_w(const float* __restrict__ W, short* __restrict__ Wbf)
{
  int i = blockIdx.x * blockDim.x + threadIdx.x;
  if (i >= GOUT * K1) return;
  int n = i / K1, k = i - K1 * n;
  float v = (k < GIND) ? W[(size_t)n * GIND + k] : 0.f;
  Wbf[i] = (short)f2bf_rn(v);
}

// A = [coord | hidden] fp32 -> bf16 (RN) [MPAD][K2] (cols 0..K1-1 used).
// Run ONCE before the GAT loop; later loops refresh via k_agg / k_coord.
__global__ void k_cvt_a(const float* __restrict__ coord,
                        const float* __restrict__ hidden,
                        short* __restrict__ Abf)
{
  int i = blockIdx.x * blockDim.x + threadIdx.x;
  if (i >= MPAD * K1) return;
  int n = i / K1, k = i - K1 * n;
  float v = 0.f;
  if (n < NN && k < GIND)
    v = (k < 2) ? coord[(size_t)n*2 + k] : hidden[(size_t)n*HIDD + k - 2];
  Abf[(size_t)n * K2 + k] = (short)f2bf_rn(v);
}

// ---------------------------------------------------------------------------
// GAT GEMM via MFMA bf16, single-pass (9 K-tiles of 64): a_bf16 * b_bf16.
// Output bf16. LDS XOR swizzle both-sides; bijective XCD swizzle (1512=8*189).
// ---------------------------------------------------------------------------
__global__ __launch_bounds__(256) void k_gat_mfma(
    const short* __restrict__ Abf, const short* __restrict__ Wbf,
    const float* __restrict__ bias, unsigned short* __restrict__ Cb)
{
  __shared__ short As[128 * 64];
  __shared__ short Bs[128 * 64];
  const int tid  = threadIdx.x;
  int lin = blockIdx.y * 24 + blockIdx.x;          // 24*63 = 1512 = 8*189
  int wg  = (lin & 7) * 189 + (lin >> 3);          // bijective XCD chunking
  const int bm = (wg / 24) * 128, bn = (wg % 24) * 128;
  const int w    = tid >> 6, lane = tid & 63;
  const int wr   = w >> 1, wc = w & 1;
  const int lrow = lane & 15;

  f32x4 acc[4][4];
  #pragma unroll
  for (int i = 0; i < 4; ++i)
    #pragma unroll
    for (int j = 0; j < 4; ++j) acc[i][j] = (f32x4){0.f, 0.f, 0.f, 0.f};

  for (int kt = 0; kt < 9; ++kt){
    int koff = kt * 64;
    __syncthreads();                 // previous tile fully consumed
    #pragma unroll
    for (int i = 0; i < 4; ++i){
      int l  = i * 256 + tid;        // 16B-chunk index 0..1023
      int r  = l >> 3, j = l & 7;
      int js = j ^ (r & 7);          // source pre-swizzle (write side)
      const short* ga = Abf + (size_t)(bm + r) * K2 + koff + js * 8;
      const short* gb = Wbf + (size_t)(bn + r) * K1 + koff + js * 8;
      short* la = As + ((i * 256 + w * 64) << 3);   // wave-uniform base
      short* lb = Bs + ((i * 256 + w * 64) << 3);
      __builtin_amdgcn_global_load_lds(
          (const __attribute__((address_space(1))) unsigned*)ga,
          (__attribute__((address_space(3))) unsigned*)la, 16, 0, 0);
      __builtin_amdgcn_global_load_lds(
          (const __attribute__((address_space(1))) unsigned*)gb,
          (__attribute__((address_space(3))) unsigned*)lb, 16, 0, 0);
    }
    __syncthreads();                 // drains vmcnt, tile ready
    #pragma unroll
    for (int ks = 0; ks < 2; ++ks){
      // read-side swizzle: chunk c = ks*4 + (lane>>4), row&7 == lrow&7
      const int co = ((ks * 4 + (lane >> 4)) ^ (lrow & 7)) * 8;
      bf16x8 fa[4], fb[4];
      #pragma unroll
      for (int mi = 0; mi < 4; ++mi)
        fa[mi] = *(const bf16x8*)&As[(wr*64 + mi*16 + lrow) * 64 + co];
      #pragma unroll
      for (int ni = 0; ni < 4; ++ni)
        fb[ni] = *(const bf16x8*)&Bs[(wc*64 + ni*16 + lrow) * 64 + co];
      #pragma unroll
      for (int mi = 0; mi < 4; ++mi)
        #pragma unroll
        for (int ni = 0; ni < 4; ++ni)
          acc[mi][ni] = __builtin_amdgcn_mfma_f32_16x16x32_bf16(
              fa[mi], fb[ni], acc[mi][ni], 0, 0, 0);
    }
  }
  // epilogue: bf16 output. col = lane&15, row = (lane>>4)*4 + j
  #pragma unroll
  for (int mi = 0; mi < 4; ++mi){
    #pragma unroll
    for (int ni = 0; ni < 4; ++ni){
      int gn = bn + wc*64 + ni*16 + lrow;
      float bv = bias[gn];
      #pragma unroll
      for (int j = 0; j < 4; ++j){
        int gm = bm + wr*64 + mi*16 + (lane >> 4) * 4 + j;
        if (gm < NN)
          Cb[(size_t)gm * GOUT + gn] = f2bf_rn(acc[mi][ni][j] + bv);
      }
    }
  }
}

// ---------------------------------------------------------------------------
__global__ void k_embed(const float* __restrict__ mesh,
                        const float* __restrict__ w, const float* __restrict__ b,
                        float* __restrict__ h)
{
  int i = blockIdx.x * blockDim.x + threadIdx.x;
  if (i >= NN * DTR) return;
  int n = i >> 6, d = i & 63;
  const float* mr = mesh + n * 4;
  const float* wr = w + d * 4;
  h[i] = fmaf(mr[0], wr[0], fmaf(mr[1], wr[1], fmaf(mr[2], wr[2], mr[3]*wr[3]))) + b[d];
}

// ---------------------------------------------------------------------------
// split-K flash attention, stage 1. Defer-max (T13) in log2 domain.
// TWO queries per thread (q, q+1024); KSPLIT=20 (KCH=100).
// ---------------------------------------------------------------------------
__global__ __launch_bounds__(128) void k_attn_part(const float* __restrict__ qkv,
    float* __restrict__ Pm, float* __restrict__ Pl, float* __restrict__ Pacc)
{
  __shared__ float Ks[KCH][DHD];
  __shared__ float Vs[KCH][DHD];
  const int q1 = blockIdx.x * 128 + threadIdx.x;   // 0..1023
  const int q2 = q1 + 1024;                        // 1024..2047
  const int bh = blockIdx.y;
  const int b  = bh >> 2, h = bh & 3;
  const int ks = blockIdx.z;
  const bool v2 = q2 < SEQ;
  const float SC = 0.25f * 1.4426950408889634f;    // scale * log2(e)
  float qv1[DHD], qv2[DHD];
  {
    const float4* qr = (const float4*)(qkv + ((size_t)(b*SEQ + q1))*192 + h*DHD);
    #pragma unroll
    for (int j = 0; j < 4; ++j){
      float4 t = qr[j];
      qv1[j*4+0] = t.x; qv1[j*4+1] = t.y; qv1[j*4+2] = t.z; qv1[j*4+3] = t.w;
    }
  }
  if (v2){
    const float4* qr = (const float4*)(qkv + ((size_t)(b*SEQ + q2))*192 + h*DHD);
    #pragma unroll
    for (int j = 0; j < 4; ++j){
      float4 t = qr[j];
      qv2[j*4+0] = t.x; qv2[j*4+1] = t.y; qv2[j*4+2] = t.z; qv2[j*4+3] = t.w;
    }
  } else {
    #pragma unroll
    for (int j = 0; j < DHD; ++j) qv2[j] = 0.f;
  }
  const int kbeg = ks * KCH;
  for (int el = threadIdx.x; el < KCH * 4; el += 128){
    int r = el >> 2, d4 = el & 3;
    const float4* base = (const float4*)(qkv + ((size_t)(b*SEQ + kbeg + r))*192 + h*DHD);
    ((float4*)Ks[r])[d4] = base[16 + d4];      // +64 floats  = K block
    ((float4*)Vs[r])[d4] = base[32 + d4];      // +128 floats = V block
  }
  __syncthreads();
  float m1 = -1e30f, l1 = 0.f, a1[DHD] = {};
  float m2 = -1e30f, l2 = 0.f, a2[DHD] = {};
  for (int r = 0; r < KCH; ++r){
    float s1 = 0.f, s2 = 0.f;
    #pragma unroll
    for (int d = 0; d < DHD; ++d){
      float kd = Ks[r][d];
      s1 = fmaf(qv1[d], kd, s1);
      s2 = fmaf(qv2[d], kd, s2);
    }
    s1 *= SC; s2 *= SC;
    if (__any((s1 > m1 + 8.f) || (s2 > m2 + 8.f))){
      float mn1 = fmaxf(m1, s1), mn2 = fmaxf(m2, s2);
      float c1 = exp2f(m1 - mn1), c2 = exp2f(m2 - mn2);
      l1 *= c1; l2 *= c2;
      #pragma unroll
      for (int d = 0; d < DHD; ++d){ a1[d] *= c1; a2[d] *= c2; }
      m1 = mn1; m2 = mn2;
    }
    float p1 = exp2f(s1 - m1), p2 = exp2f(s2 - m2);
    l1 += p1; l2 += p2;
    #pragma unroll
    for (int d = 0; d < DHD; ++d){
      float vd = Vs[r][d];
      a1[d] = fmaf(p1, vd, a1[d]);
      a2[d] = fmaf(p2, vd, a2[d]);
    }
  }
  {
    size_t qi = ((size_t)bh * SEQ + q1) * KSPLIT + ks;
    Pm[qi] = m1; Pl[qi] = l1;
    #pragma unroll
    for (int d = 0; d < DHD; ++d) Pacc[qi*DHD + d] = a1[d];
  }
  if (v2){
    size_t qi = ((size_t)bh * SEQ + q2) * KSPLIT + ks;
    Pm[qi] = m2; Pl[qi] = l2;
    #pragma unroll
    for (int d = 0; d < DHD; ++d) Pacc[qi*DHD + d] = a2[d];
  }
}

// stage 2: merge KSPLIT partials per query -> o[N][64] (log2 domain)
__global__ void k_attn_comb(const float* __restrict__ Pm, const float* __restrict__ Pl,
                            const float* __restrict__ Pacc, float* __restrict__ o)
{
  int qi = blockIdx.x * blockDim.x + threadIdx.x;
  if (qi >= BATCH * NHTR * SEQ) return;
  float m = -1e30f;
  #pragma unroll
  for (int ks = 0; ks < KSPLIT; ++ks) m = fmaxf(m, Pm[(size_t)qi*KSPLIT + ks]);
  float l = 0.f, acc[DHD] = {};
  #pragma unroll
  for (int ks = 0; ks < KSPLIT; ++ks){
    size_t p = (size_t)qi*KSPLIT + ks;
    float sc = exp2f(Pm[p] - m);
    l += Pl[p] * sc;
    #pragma unroll
    for (int d = 0; d < DHD; ++d) acc[d] = fmaf(Pacc[p*DHD + d], sc, acc[d]);
  }
  int bh = qi / SEQ, q = qi - bh * SEQ;
  int b = bh >> 2, h = bh & 3;
  float inv = 1.f / l;
  #pragma unroll
  for (int d = 0; d < DHD; ++d)
    o[((size_t)(b*SEQ + q))*64 + h*DHD + d] = acc[d] * inv;
}

// ---------------------------------------------------------------------------
__global__ __launch_bounds__(256) void k_addln(const float* __restrict__ x,
    const float* __restrict__ y, const float* __restrict__ g,
    const float* __restrict__ b, float* __restrict__ out)
{
  int row = blockIdx.x * 4 + (threadIdx.x >> 6);
  int lane = threadIdx.x & 63;
  if (row >= NN) return;
  float v = x[(size_t)row*64 + lane] + y[(size_t)row*64 + lane];
  float s1 = v, s2 = v * v;
  #pragma unroll
  for (int o = 32; o; o >>= 1){ s1 += __shfl_xor(s1, o); s2 += __shfl_xor(s2, o); }
  float mean = s1 * (1.f/64.f);
  float var  = s2 * (1.f/64.f) - mean * mean;
  float r = rsqrtf(var + 1e-5f);
  out[(size_t)row*64 + lane] = (v - mean) * r * g[lane] + b[lane];
}

__global__ void k_concat_feats(const float* __restrict__ x,
                               const float* __restrict__ tout,
                               float* __restrict__ feats)
{
  int i = blockIdx.x * blockDim.x + threadIdx.x;
  if (i >= NN * 21) return;
  int n = i / 21, c = i - 21*n;
  feats[i] = (c < 5) ? x[(size_t)n*7 + 2 + c] : tout[(size_t)n*16 + c - 5];
}

__global__ void k_initcoord(const float* __restrict__ x, float* __restrict__ coord)
{
  int i = blockIdx.x * blockDim.x + threadIdx.x;
  if (i >= NN * 2) return;
  coord[i] = x[(size_t)(i >> 1)*7 + (i & 1)];
}

// ---------------------------------------------------------------------------
// CSR build (by dst). dst for e>=NEDGE is the self-loop e-NEDGE.
// ---------------------------------------------------------------------------
__global__ void k_count(const int* __restrict__ dst, int* __restrict__ cnt)
{
  int e = blockIdx.x * blockDim.x + threadIdx.x;
  if (e >= ELOOP) return;
  int d = (e < NEDGE) ? dst[e] : e - NEDGE;
  atomicAdd(&cnt[d], 1);
}

__global__ __launch_bounds__(1024) void k_scan(const int* __restrict__ cnt,
                                               int* __restrict__ ptr)
{
  __shared__ int part[1024];
  int tid = threadIdx.x;
  const int per = 8;
  int loc[per]; int s = 0;
  int base = tid * per;
  #pragma unroll
  for (int i = 0; i < per; ++i){
    int v = (base + i < NN) ? cnt[base + i] : 0;
    loc[i] = s; s += v;
  }
  part[tid] = s;
  __syncthreads();
  for (int off = 1; off < 1024; off <<= 1){
    int v = 0;
    if (tid >= off) v = part[tid - off];
    __syncthreads();
    if (tid >= off) part[tid] += v;
    __syncthreads();
  }
  int pre = tid ? part[tid - 1] : 0;
  #pragma unroll
  for (int i = 0; i < per; ++i)
    if (base + i < NN) ptr[base + i] = pre + loc[i];
  if (tid == 1023) ptr[NN] = part[1023];
}

__global__ void k_fill(const int* __restrict__ dst, const int* __restrict__ ptr,
                       int* __restrict__ fil, int* __restrict__ eid)
{
  int e = blockIdx.x * blockDim.x + threadIdx.x;
  if (e >= ELOOP) return;
  int d = (e < NEDGE) ? dst[e] : e - NEDGE;
  int pos = ptr[d] + atomicAdd(&fil[d], 1);
  eid[pos] = e;
}

// ---------------------------------------------------------------------------
// logits2[pos*6+h] over CSR (dst-sorted) positions. One WAVE per edge,
// looping over the 6 heads. bf16 xl/xr, uint4. XCD swizzle (10000 = 8*1250).
// ---------------------------------------------------------------------------
__global__ __launch_bounds__(256) void k_logits(const unsigned short* __restrict__ xlb,
    const unsigned short* __restrict__ xrb, const int* __restrict__ src_a,
    const int* __restrict__ dst_a, const int* __restrict__ eid,
    const float* __restrict__ att, float* __restrict__ logits2)
{
  int bid = blockIdx.x;                         // 10000 = 8 * 1250
  int wgs = (bid & 7) * 1250 + (bid >> 3);      // bijective XCD chunking
  int pos = wgs * 4 + (threadIdx.x >> 6);
  if (pos >= ELOOP) return;
  int lane = threadIdx.x & 63;
  int e = eid[pos];
  int s = (e < NEDGE) ? src_a[e] : e - NEDGE;
  int d = (e < NEDGE) ? dst_a[e] : e - NEDGE;
  const uint4* pl = (const uint4*)(xlb + (size_t)s * GOUT);
  const uint4* pr = (const uint4*)(xrb + (size_t)d * GOUT);
  const float4* pa = (const float4*)att;
  #pragma unroll 2
  for (int h = 0; h < NHEADS; ++h){
    uint4 ua = pl[h*64 + lane];
    uint4 ub = pr[h*64 + lane];
    float4 w0 = pa[h*128 + lane*2], w1 = pa[h*128 + lane*2 + 1];
    float acc = 0.f;
    auto pair = [&](unsigned a, unsigned b, float wl, float wh){
      float vl = __uint_as_float(a << 16)        + __uint_as_float(b << 16);
      float vh = __uint_as_float(a & 0xffff0000u)+ __uint_as_float(b & 0xffff0000u);
      vl = vl > 0.f ? vl : 0.2f * vl;
      vh = vh > 0.f ? vh : 0.2f * vh;
      acc = fmaf(vl, wl, acc);
      acc = fmaf(vh, wh, acc);
    };
    pair(ua.x, ub.x, w0.x, w0.y);
    pair(ua.y, ub.y, w0.z, w0.w);
    pair(ua.z, ub.z, w1.x, w1.y);
    pair(ua.w, ub.w, w1.z, w1.w);
    #pragma unroll
    for (int o2 = 32; o2; o2 >>= 1) acc += __shfl_xor(acc, o2);
    if (lane == 0) logits2[pos*NHEADS + h] = acc;
  }
}

// mx / inv(sum) per (node, head); logits2 is pos-ordered -> sequential reads
__global__ void k_stats(const float* __restrict__ logits2, const int* __restrict__ ptr,
                        float* __restrict__ mx, float* __restrict__ inv)
{
  int i = blockIdx.x * blockDim.x + threadIdx.x;
  if (i >= NN * NHEADS) return;
  int n = i / NHEADS, h = i - NHEADS * n;
  int s0 = ptr[n], s1 = ptr[n + 1];
  float m = -1e30f;
  for (int t = s0; t < s1; ++t) m = fmaxf(m, logits2[t*NHEADS + h]);
  float s = 0.f;
  for (int t = s0; t < s1; ++t) s += __expf(logits2[t*NHEADS + h] - m);
  mx[i] = m; inv[i] = 1.f / s;
}

// ---------------------------------------------------------------------------
// hidden[n,c] = selu(mean_h sum a[e,h]*xl[src,h,c] + gbias[c]); also writes
// the bf16 columns of abf (cols 2+2t, 3+2t) for the next GAT loop.
// ---------------------------------------------------------------------------
__global__ __launch_bounds__(256) void k_agg(const unsigned short* __restrict__ xlb,
    const float* __restrict__ logits2, const float* __restrict__ mx,
    const float* __restrict__ inv, const int* __restrict__ ptr,
    const int* __restrict__ eid, const int* __restrict__ src_a,
    const float* __restrict__ gbias, float* __restrict__ hidden,
    short* __restrict__ abf)
{
  const int n = blockIdx.x;
  const int tid = threadIdx.x;
  __shared__ float a_sh[64 * NHEADS];
  __shared__ int src_sh[64];
  const int s0 = ptr[n];
  const int deg = ptr[n + 1] - s0;
  float acc[12] = {};
  for (int base = 0; base < deg; base += 64){
    int cnt = min(64, deg - base);
    __syncthreads();
    for (int t = tid; t < cnt * NHEADS; t += 256){
      int ei = t / NHEADS, h = t - NHEADS * ei;
      a_sh[t] = __expf(logits2[(s0 + base + ei)*NHEADS + h] - mx[n*NHEADS + h])
                * inv[n*NHEADS + h];
      if (h == 0){
        int e = eid[s0 + base + ei];
        src_sh[ei] = (e < NEDGE) ? src_a[e] : e - NEDGE;
      }
    }
    __syncthreads();
    for (int i2 = 0; i2 < cnt; ++i2){
      const unsigned* row = (const unsigned*)(xlb + (size_t)src_sh[i2] * GOUT);
      #pragma unroll
      for (int k = 0; k < NHEADS; ++k){
        unsigned u = row[tid + (k << 8)];
        float wgt = a_sh[i2*NHEADS + k];
        acc[2*k]   = fmaf(__uint_as_float(u << 16),         wgt, acc[2*k]);
        acc[2*k+1] = fmaf(__uint_as_float(u & 0xffff0000u), wgt, acc[2*k+1]);
      }
    }
  }
  float m0 = (acc[0]+acc[2]+acc[4]+acc[6]+acc[8]+acc[10]) * (1.f/6.f);
  float m1 = (acc[1]+acc[3]+acc[5]+acc[7]+acc[9]+acc[11]) * (1.f/6.f);
  float2 out;
  out.x = selu_f(m0 + gbias[2*tid]);
  out.y = selu_f(m1 + gbias[2*tid + 1]);
  *(float2*)&hidden[(size_t)n*HIDD + 2*tid] = out;
  // abf refresh: bf16 for channels (2+2t, 3+2t), packed uint store
  unsigned short h0 = f2bf_rn(out.x), h1 = f2bf_rn(out.y);
  *(unsigned*)&abf[(size_t)n*K2 + 2 + 2*tid] = (unsigned)h0 | ((unsigned)h1 << 16);
}

// ---------------------------------------------------------------------------
extern "C" void kernel_launch(void* const* d_in, const int* in_sizes, int n_in,
                              void* d_out, int out_size, void* d_ws, size_t ws_size,
                              hipStream_t stream)
{
  const float* mesh     = (const float*)d_in[1];
  const float* xin      = (const float*)d_in[2];
  const int*   ei       = (const int*)d_in[3];
  const float* embed_w  = (const float*)d_in[4];
  const float* embed_b  = (const float*)d_in[5];
  const float* in_proj_w= (const float*)d_in[6];
  const float* in_proj_b= (const float*)d_in[7];
  const float* out_proj_w=(const float*)d_in[8];
  const float* out_proj_b=(const float*)d_in[9];
  const float* ln1_g    = (const float*)d_in[10];
  const float* ln1_b    = (const float*)d_in[11];
  const float* ln2_g    = (const float*)d_in[12];
  const float* ln2_b    = (const float*)d_in[13];
  const float* ff1_w    = (const float*)d_in[14];
  const float* ff1_b    = (const float*)d_in[15];
  const float* ff2_w    = (const float*)d_in[16];
  const float* ff2_b    = (const float*)d_in[17];
  const float* tout_w   = (const float*)d_in[18];
  const float* tout_b   = (const float*)d_in[19];
  const float* lin_w    = (const float*)d_in[20];
  const float* lin_b    = (const float*)d_in[21];
  const float* gat_wl   = (const float*)d_in[22];
  const float* gat_bl   = (const float*)d_in[23];
  const float* gat_wr   = (const float*)d_in[24];
  const float* gat_br   = (const float*)d_in[25];
  const float* gat_att  = (const float*)d_in[26];
  const float* gat_bias = (const float*)d_in[27];
  const float* coord1_w = (const float*)d_in[28];
  const float* coord1_b = (const float*)d_in[29];
  const float* coord2_w = (const float*)d_in[30];
  const float* coord2_b = (const float*)d_in[31];

  const int* esrc = ei;
  const int* edst = ei + NEDGE;

  char* ws = (char*)d_ws;
  size_t off = 0;
  auto alloc = [&](size_t nbytes){
    size_t o = off; off += (nbytes + 255) & ~(size_t)255; return o;
  };
  float* hidden = (float*)(ws + alloc((size_t)NN * HIDD * 4));
  float* coord  = (float*)(ws + alloc((size_t)NN * 2 * 4));
  unsigned short* xlb = (unsigned short*)(ws + alloc((size_t)NN * GOUT * 2));
  unsigned short* xrb = (unsigned short*)(ws + alloc((size_t)NN * GOUT * 2));
  float* logits = (float*)(ws + alloc((size_t)ELOOP * NHEADS * 4));
  float* mxb    = (float*)(ws + alloc((size_t)NN * NHEADS * 4));
  float* invb   = (float*)(ws + alloc((size_t)NN * NHEADS * 4));
  int*   ptr    = (int*)(ws + alloc((size_t)(NN + 1) * 4));
  int*   eid    = (int*)(ws + alloc((size_t)ELOOP * 4));
  int*   cnt    = (int*)(ws + alloc((size_t)NN * 4));
  int*   fil    = (int*)(ws + alloc((size_t)NN * 4));
  short* abf    = (short*)(ws + alloc((size_t)MPAD * K2 * 2));
  short* wlbf   = (short*)(ws + alloc((size_t)GOUT * K1 * 2));
  short* wrbf   = (short*)(ws + alloc((size_t)GOUT * K1 * 2));
  float* part_c1= (float*)(ws + alloc((size_t)4 * NN * 256 * 4));  // 31.25 MiB

  // Transformer-phase temporaries ALIASED inside xlb+xrb (93.75 MiB, all
  // dead before the first k_gat_mfma writes xlb). MiB offsets within region:
  char* arena = (char*)xlb;
  float* h       = (float*)(arena + ((size_t)0  << 20));  // 0-2     (live to ln2)
  float* o       = (float*)(arena + ((size_t)2  << 20));  // 2-4
  float* tmp     = (float*)(arena + ((size_t)4  << 20));  // 4-6
  float* feats   = (float*)(arena + ((size_t)6  << 20));  // 6-6.7
  float* toutb   = (float*)(arena + ((size_t)7  << 20));  // 7-7.6
  float* qkv     = (float*)(arena + ((size_t)8  << 20));  // 8-14.2  (dead after attn)
  float* Pm      = (float*)(arena + ((size_t)15 << 20));  // 15-17.5 (KSPLIT=20)
  float* Pl      = (float*)(arena + ((size_t)18 << 20));  // 18-20.5
  float* Pacc    = (float*)(arena + ((size_t)21 << 20));  // 21-62   (dead after comb)
  float* part_f2 = (float*)(arena + ((size_t)8  << 20));  // 8-23.7  (attn dead by ff2)
  float* ffmid   = (float*)(arena + ((size_t)28 << 20));  // 28-90.5 (Pacc dead by ff1)

  // ---- transformer ----
  k_embed<<<CDIV(NN*DTR, 256), 256, 0, stream>>>(mesh, embed_w, embed_b, h);
  k_gemm<0><<<dim3(CDIV(192,64), CDIV(NN,64)), 256, 0, stream>>>(h, in_proj_w, in_proj_b, qkv, NN, 192, DTR);
  k_attn_part<<<dim3(CDIV(SEQ,256), BATCH*NHTR, KSPLIT), 128, 0, stream>>>(qkv, Pm, Pl, Pacc);
  k_attn_comb<<<CDIV(BATCH*NHTR*SEQ, 256), 256, 0, stream>>>(Pm, Pl, Pacc, o);
  k_gemm<0><<<dim3(1, CDIV(NN,64)), 256, 0, stream>>>(o, out_proj_w, out_proj_b, tmp, NN, DTR, DTR);
  k_addln<<<CDIV(NN,4), 256, 0, stream>>>(h, tmp, ln1_g, ln1_b, h);
  k_gemm<1><<<dim3(CDIV(FFD,64), CDIV(NN,64)), 256, 0, stream>>>(h, ff1_w, ff1_b, ffmid, NN, FFD, DTR);
  k_gemm_sk<<<dim3(1, CDIV(NN,64), 8), 256, 0, stream>>>(ffmid, ff2_w, part_f2, NN, DTR, FFD, 256);
  k_comb<0><<<CDIV(NN*DTR, 256), 256, 0, stream>>>(part_f2, ff2_b, tmp, NN, DTR, 8);
  k_addln<<<CDIV(NN,4), 256, 0, stream>>>(h, tmp, ln2_g, ln2_b, h);
  k_gemm<0><<<dim3(1, CDIV(NN,64)), 256, 0, stream>>>(h, tout_w, tout_b, toutb, NN, TOUTD, DTR);
  k_concat_feats<<<CDIV(NN*21, 256), 256, 0, stream>>>(xin, toutb, feats);
  k_gemm<2><<<dim3(CDIV(HIDD,64), CDIV(NN,64)), 256, 0, stream>>>(feats, lin_w, lin_b, hidden, NN, HIDD, 21);
  k_initcoord<<<CDIV(NN*2, 256), 256, 0, stream>>>(xin, coord);

  // ---- CSR by dst + weight conversion (once) ----
  hipMemsetAsync(cnt, 0, (size_t)NN * 4, stream);
  hipMemsetAsync(fil, 0, (size_t)NN * 4, stream);
  k_count<<<CDIV(ELOOP, 256), 256, 0, stream>>>(edst, cnt);
  k_scan<<<1, 1024, 0, stream>>>(cnt, ptr);
  k_fill<<<CDIV(ELOOP, 256), 256, 0, stream>>>(edst, ptr, fil, eid);
  k_cvt_w<<<CDIV(GOUT*K1, 256), 256, 0, stream>>>(gat_wl, wlbf);
  k_cvt_w<<<CDIV(GOUT*K1, 256), 256, 0, stream>>>(gat_wr, wrbf);
  k_cvt_a<<<CDIV(MPAD*K1, 256), 256, 0, stream>>>(coord, hidden, abf);  // once

  // ---- GAT loops (abf refreshed in-place by k_agg / k_coord) ----
  for (int it = 0; it < 3; ++it){
    k_gat_mfma<<<dim3(GOUT/128, MPAD/128), 256, 0, stream>>>(abf, wlbf, gat_bl, xlb);
    k_gat_mfma<<<dim3(GOUT/128, MPAD/128), 256, 0, stream>>>(abf, wrbf, gat_br, xrb);
    k_logits<<<ELOOP/4, 256, 0, stream>>>(xlb, xrb, esrc, edst, eid, gat_att, logits);
    k_stats<<<CDIV(NN*NHEADS, 256), 256, 0, stream>>>(logits, ptr, mxb, invb);
    k_agg<<<NN, 256, 0, stream>>>(xlb, logits, mxb, invb, ptr, eid, esrc, gat_bias, hidden, abf);
    k_gemm_sk<<<dim3(CDIV(256,64), CDIV(NN,64), 4), 256, 0, stream>>>(hidden, coord1_w, part_c1, NN, 256, HIDD, 128);
    float* cdst = (it == 2) ? (float*)d_out : coord;
    k_coord<<<NN, 256, 0, stream>>>(part_c1, coord1_b, coord2_w, coord2_b, cdst, abf);
  }
}